// Round 3
// baseline (372.745 us; speedup 1.0000x reference)
//
#include <hip/hip_runtime.h>
#include <hip/hip_bf16.h>
#include <cstdint>
#include <cstddef>

// Problem constants
#define Bb   2
#define Tt   2048
#define Cc   896
#define Hh   14
#define HKVc 2
#define Dd   64
#define Mm   (Bb * Tt)        // 4096 rows

typedef __attribute__((ext_vector_type(8))) short bfrag8;   // 8 bf16 (4 VGPRs)
typedef __attribute__((ext_vector_type(4))) float facc4;    // 4 f32 acc
typedef unsigned short u16;

__device__ __forceinline__ float bf2f(u16 v) {
    union { unsigned int u; float f; } c; c.u = ((unsigned int)v) << 16; return c.f;
}
__device__ __forceinline__ u16 f2bf(float f) {
    union { float f; unsigned int u; } c; c.f = f;
    unsigned int u = c.u;
    return (u16)((u + 0x7fffu + ((u >> 16) & 1u)) >> 16);  // RNE
}

// ---------------------------------------------------------------------------
// Kernel 1: fused QKV projection GEMM + bias.  Inputs fp32, ws outputs bf16.
// Block: 256 thr (4 waves). Tile 64(M) x 64(N), K-step 32.
// W staged transposed in LDS as [n][k] (stride 40 elems, 16B-aligned rows).
// V output is written TRANSPOSED: v_t[b][kvh][d][t] so attention can load PV
// B-fragments straight from global (contiguous in t).
// ---------------------------------------------------------------------------
__global__ __launch_bounds__(256)
void qkv_kernel(const float* __restrict__ x,
                const float* __restrict__ wq, const float* __restrict__ bq,
                const float* __restrict__ wk, const float* __restrict__ bk,
                const float* __restrict__ wv, const float* __restrict__ bv,
                u16* __restrict__ q_ws, u16* __restrict__ k_ws, u16* __restrict__ v_t)
{
    __shared__ __align__(16) u16 lds_w[64 * 40];

    const int mt = blockIdx.x;        // 0..63
    const int nt = blockIdx.y;        // 0..17: 14 q-tiles, 2 k-tiles, 2 v-tiles
    const float* W; const float* bias; int ldw, col0;
    if (nt < 14)      { W = wq; bias = bq; ldw = 896; col0 = nt * 64; }
    else if (nt < 16) { W = wk; bias = bk; ldw = 128; col0 = (nt - 14) * 64; }
    else              { W = wv; bias = bv; ldw = 128; col0 = (nt - 16) * 64; }

    const int tid  = threadIdx.x;
    const int lane = tid & 63;
    const int wave = tid >> 6;
    const int lr   = lane & 15;       // A-row / B-col / C-col
    const int quad = lane >> 4;       // k-granule selector
    const int row0 = mt * 64 + wave * 16;

    facc4 acc[4];
    #pragma unroll
    for (int i = 0; i < 4; ++i) acc[i] = (facc4){0.f, 0.f, 0.f, 0.f};

    const int sn  = tid & 63;         // staging: LDS row n
    const int skg = (tid >> 6) * 8;   // staging: k-granule base

    for (int k0 = 0; k0 < 896; k0 += 32) {
        __syncthreads();
        {   // coalesced f32 global loads down a W column group, cvt, one b128 LDS write
            union { u16 s[8]; bfrag8 v; } tw;
            #pragma unroll
            for (int j = 0; j < 8; ++j)
                tw.s[j] = f2bf(W[(size_t)(k0 + skg + j) * ldw + col0 + sn]);
            *(bfrag8*)(&lds_w[sn * 40 + skg]) = tw.v;
        }
        __syncthreads();

        // A-frag: 8 consecutive f32 of an x row -> bf16x8
        const float4* ap = (const float4*)(x + (size_t)(row0 + lr) * 896 + k0 + quad * 8);
        const float4 a0 = ap[0], a1 = ap[1];
        union { u16 s[8]; bfrag8 v; } ta;
        ta.s[0] = f2bf(a0.x); ta.s[1] = f2bf(a0.y); ta.s[2] = f2bf(a0.z); ta.s[3] = f2bf(a0.w);
        ta.s[4] = f2bf(a1.x); ta.s[5] = f2bf(a1.y); ta.s[6] = f2bf(a1.z); ta.s[7] = f2bf(a1.w);

        #pragma unroll
        for (int ct = 0; ct < 4; ++ct) {
            const bfrag8 bfr = *(const bfrag8*)(&lds_w[(ct * 16 + lr) * 40 + quad * 8]);
            acc[ct] = __builtin_amdgcn_mfma_f32_16x16x32_bf16(ta.v, bfr, acc[ct], 0, 0, 0);
        }
    }

    // epilogue: bias + store bf16 (C layout: row = quad*4+r, col = lr)
    const bool is_v = (nt >= 16);
    #pragma unroll
    for (int ct = 0; ct < 4; ++ct) {
        const int col = col0 + ct * 16 + lr;
        const float bb = bias[col];
        #pragma unroll
        for (int r = 0; r < 4; ++r) {
            const int row = row0 + quad * 4 + r;
            const u16 val = f2bf(acc[ct][r] + bb);
            if (is_v) {
                // v_t[((b*2 + kvh)*64 + d) * 2048 + t]
                const int bq_ = row >> 11, t = row & 2047;
                const int kvh = col >> 6, d = col & 63;
                v_t[((size_t)(bq_ * 2 + kvh) * 64 + d) * 2048 + t] = val;
            } else if (nt < 14) {
                q_ws[(size_t)row * 896 + col] = val;
            } else {
                k_ws[(size_t)row * 128 + col] = val;
            }
        }
    }
}

// ---------------------------------------------------------------------------
// Kernel 2: RoPE in-place on bf16 q (B,T,H,D) and k (B,T,HKV,D).
// cos/sin tables are fp32. Thread = one (d, d+32) pair.
// ---------------------------------------------------------------------------
__global__ __launch_bounds__(256)
void rope_kernel(u16* __restrict__ q_ws, u16* __restrict__ k_ws,
                 const float* __restrict__ cosT, const float* __restrict__ sinT)
{
    const int NQ = Bb * Tt * Hh * 32;
    const int NK = Bb * Tt * HKVc * 32;
    const int idx = blockIdx.x * 256 + threadIdx.x;

    u16* p; int t, d;
    if (idx < NQ) {
        d = idx & 31;
        const int h = (idx >> 5) % Hh;
        t = (idx / (32 * Hh)) % Tt;
        const int b = idx / (32 * Hh * Tt);
        p = q_ws + ((size_t)(b * Tt + t) * Hh + h) * 64;
    } else if (idx < NQ + NK) {
        const int i = idx - NQ;
        d = i & 31;
        const int h = (i >> 5) % HKVc;
        t = (i / (32 * HKVc)) % Tt;
        const int b = i / (32 * HKVc * Tt);
        p = k_ws + ((size_t)(b * Tt + t) * HKVc + h) * 64;
    } else {
        return;
    }
    const float c1 = cosT[t * 64 + d],      s1 = sinT[t * 64 + d];
    const float c2 = cosT[t * 64 + d + 32], s2 = sinT[t * 64 + d + 32];
    const float a  = bf2f(p[d]);
    const float b2 = bf2f(p[d + 32]);
    p[d]      = f2bf(a * c1 - b2 * s1);   // first half: q*c - q[d+32]*s
    p[d + 32] = f2bf(b2 * c2 + a * s2);   // second half: q*c + q[d-32]*s
}

// ---------------------------------------------------------------------------
// Kernel 3: flash-style causal attention, wave-autonomous.
// Block = 1 wave (64 thr) owning 16 Q rows; grid (128 qi) x (28 bh), qi reversed
// so long blocks dispatch first. No __syncthreads anywhere.
// QK^T: Q + K frags direct from global. PV: V frags direct from global (v_t is
// pre-transposed [b][kvh][d][t]). P relayout C->A via wave-private LDS.
// ---------------------------------------------------------------------------
__global__ __launch_bounds__(64)
void attn_kernel(const u16* __restrict__ q_ws, const u16* __restrict__ k_ws,
                 const u16* __restrict__ v_t, u16* __restrict__ o_ws)
{
    __shared__ __align__(16) u16 lds_p[16 * 72];   // 16x64 P, stride 72

    const int qi = 127 - blockIdx.x;      // reversed: long blocks first
    const int bh = blockIdx.y;            // 0..27
    const int b = bh / Hh, h = bh % Hh;
    const int kvh = h / (Hh / HKVc);      // h / 7

    const int lane = threadIdx.x;         // 0..63
    const int lr   = lane & 15;
    const int quad = lane >> 4;
    const int m0   = qi * 16;             // q-row base for this wave

    const u16* Qbase = q_ws + (size_t)(b * Tt) * 896 + h * 64;
    const u16* Kbase = k_ws + (size_t)(b * Tt) * 128 + kvh * 64;
    const u16* Vbase = v_t + (size_t)(b * 2 + kvh) * 64 * 2048;

    // Q fragments for both 32-wide k-steps of D=64, held in regs all kernel
    bfrag8 qf[2];
    #pragma unroll
    for (int ks = 0; ks < 2; ++ks)
        qf[ks] = *(const bfrag8*)(Qbase + (size_t)(m0 + lr) * 896 + ks * 32 + quad * 8);

    float m_r[4], l_r[4];
    #pragma unroll
    for (int r = 0; r < 4; ++r) { m_r[r] = -3e38f; l_r[r] = 0.f; }
    facc4 o_acc[4];
    #pragma unroll
    for (int ct = 0; ct < 4; ++ct) o_acc[ct] = (facc4){0.f, 0.f, 0.f, 0.f};

    const float scale = 0.125f;           // 1/sqrt(64)
    const int nkv = (m0 + 16 + 63) >> 6;  // KV-64 tiles covering causal range

    for (int jt = 0; jt < nkv; ++jt) {
        const int j0 = jt * 64;

        // S = Q K^T  (B-frag of K^T == contiguous-8 along D of K rows)
        facc4 s[4];
        #pragma unroll
        for (int ct = 0; ct < 4; ++ct) {
            s[ct] = (facc4){0.f, 0.f, 0.f, 0.f};
            #pragma unroll
            for (int ks = 0; ks < 2; ++ks) {
                const bfrag8 kf = *(const bfrag8*)(
                    Kbase + (size_t)(j0 + ct * 16 + lr) * 128 + ks * 32 + quad * 8);
                s[ct] = __builtin_amdgcn_mfma_f32_16x16x32_bf16(qf[ks], kf, s[ct], 0, 0, 0);
            }
        }

        // scale + causal mask (only the last tile crosses the diagonal)
        const bool diag = (jt == nkv - 1);
        #pragma unroll
        for (int ct = 0; ct < 4; ++ct) {
            const int j = j0 + ct * 16 + lr;
            #pragma unroll
            for (int r = 0; r < 4; ++r) {
                float sv = s[ct][r] * scale;
                if (diag && j > (m0 + quad * 4 + r)) sv = -3e38f;
                s[ct][r] = sv;
            }
        }

        // online softmax: row max across the quad's 16 lanes
        float alpha[4];
        #pragma unroll
        for (int r = 0; r < 4; ++r) {
            float v = fmaxf(fmaxf(s[0][r], s[1][r]), fmaxf(s[2][r], s[3][r]));
            v = fmaxf(v, __shfl_xor(v, 1));
            v = fmaxf(v, __shfl_xor(v, 2));
            v = fmaxf(v, __shfl_xor(v, 4));
            v = fmaxf(v, __shfl_xor(v, 8));
            const float mn = fmaxf(m_r[r], v);
            alpha[r] = __expf(m_r[r] - mn);
            m_r[r] = mn;
        }

        // P = exp(s - m); write bf16 P to LDS (C-layout -> [row][col])
        float rsum[4] = {0.f, 0.f, 0.f, 0.f};
        #pragma unroll
        for (int ct = 0; ct < 4; ++ct) {
            #pragma unroll
            for (int r = 0; r < 4; ++r) {
                const float p = __expf(s[ct][r] - m_r[r]);
                rsum[r] += p;
                lds_p[(quad * 4 + r) * 72 + ct * 16 + lr] = f2bf(p);
            }
        }
        #pragma unroll
        for (int r = 0; r < 4; ++r) {
            float v = rsum[r];
            v += __shfl_xor(v, 1);
            v += __shfl_xor(v, 2);
            v += __shfl_xor(v, 4);
            v += __shfl_xor(v, 8);
            l_r[r] = l_r[r] * alpha[r] + v;
        }
        #pragma unroll
        for (int ct = 0; ct < 4; ++ct)
            #pragma unroll
            for (int r = 0; r < 4; ++r) o_acc[ct][r] *= alpha[r];

        // O += P @ V   (V B-frags straight from global: contiguous in t)
        #pragma unroll
        for (int ks = 0; ks < 2; ++ks) {
            const bfrag8 pf = *(const bfrag8*)(&lds_p[lr * 72 + ks * 32 + quad * 8]);
            #pragma unroll
            for (int ct = 0; ct < 4; ++ct) {
                const bfrag8 vf = *(const bfrag8*)(
                    Vbase + (size_t)(ct * 16 + lr) * 2048 + j0 + ks * 32 + quad * 8);
                o_acc[ct] = __builtin_amdgcn_mfma_f32_16x16x32_bf16(pf, vf, o_acc[ct], 0, 0, 0);
            }
        }
    }

    // epilogue: O / l -> o_ws[b][t][h*64+d] (bf16)
    #pragma unroll
    for (int ct = 0; ct < 4; ++ct) {
        const int dcol = ct * 16 + lr;
        #pragma unroll
        for (int r = 0; r < 4; ++r) {
            const int t = m0 + quad * 4 + r;
            o_ws[(size_t)(b * Tt + t) * 896 + h * 64 + dcol] = f2bf(o_acc[ct][r] / l_r[r]);
        }
    }
}

// ---------------------------------------------------------------------------
// Kernel 4: output projection  o_ws(4096x896 bf16) @ wo(896x896 f32) -> d_out f32
// ---------------------------------------------------------------------------
__global__ __launch_bounds__(256)
void oproj_kernel(const u16* __restrict__ a_in, const float* __restrict__ wo,
                  float* __restrict__ outp)
{
    __shared__ __align__(16) u16 lds_w[64 * 40];

    const int mt = blockIdx.x;        // 0..63
    const int col0 = blockIdx.y * 64; // 0..13 tiles

    const int tid  = threadIdx.x;
    const int lane = tid & 63;
    const int wave = tid >> 6;
    const int lr   = lane & 15;
    const int quad = lane >> 4;
    const int row0 = mt * 64 + wave * 16;

    facc4 acc[4];
    #pragma unroll
    for (int i = 0; i < 4; ++i) acc[i] = (facc4){0.f, 0.f, 0.f, 0.f};

    const int sn  = tid & 63;
    const int skg = (tid >> 6) * 8;

    for (int k0 = 0; k0 < 896; k0 += 32) {
        __syncthreads();
        {
            union { u16 s[8]; bfrag8 v; } tw;
            #pragma unroll
            for (int j = 0; j < 8; ++j)
                tw.s[j] = f2bf(wo[(size_t)(k0 + skg + j) * 896 + col0 + sn]);
            *(bfrag8*)(&lds_w[sn * 40 + skg]) = tw.v;
        }
        __syncthreads();

        const bfrag8 a = *(const bfrag8*)(a_in + (size_t)(row0 + lr) * 896 + k0 + quad * 8);
        #pragma unroll
        for (int ct = 0; ct < 4; ++ct) {
            const bfrag8 bfr = *(const bfrag8*)(&lds_w[(ct * 16 + lr) * 40 + quad * 8]);
            acc[ct] = __builtin_amdgcn_mfma_f32_16x16x32_bf16(a, bfr, acc[ct], 0, 0, 0);
        }
    }

    #pragma unroll
    for (int ct = 0; ct < 4; ++ct) {
        const int col = col0 + ct * 16 + lr;
        #pragma unroll
        for (int r = 0; r < 4; ++r) {
            const int row = row0 + quad * 4 + r;
            outp[(size_t)row * 896 + col] = acc[ct][r];
        }
    }
}

// ---------------------------------------------------------------------------
extern "C" void kernel_launch(void* const* d_in, const int* in_sizes, int n_in,
                              void* d_out, int out_size, void* d_ws, size_t ws_size,
                              hipStream_t stream)
{
    const float* x    = (const float*)d_in[0];
    const float* wq   = (const float*)d_in[1];
    const float* bq   = (const float*)d_in[2];
    const float* wk   = (const float*)d_in[3];
    const float* bk   = (const float*)d_in[4];
    const float* wv   = (const float*)d_in[5];
    const float* bv   = (const float*)d_in[6];
    const float* wo   = (const float*)d_in[7];
    const float* cosT = (const float*)d_in[8];
    const float* sinT = (const float*)d_in[9];
    // d_in[10] = mask: exact causal tril(0 / -1e9) — applied inline in attn_kernel.

    // Workspace layout (bf16), ~16.8 MiB total:
    u16* q_ws = (u16*)d_ws;                              // 4096*896
    u16* k_ws = q_ws + (size_t)Mm * 896;                 // 4096*128
    u16* v_t  = k_ws + (size_t)Mm * 128;                 // 2*2*64*2048 (transposed V)
    u16* o_ws = v_t + (size_t)4 * 64 * 2048;             // 4096*896

    qkv_kernel<<<dim3(64, 18), 256, 0, stream>>>(x, wq, bq, wk, bk, wv, bv,
                                                 q_ws, k_ws, v_t);
    rope_kernel<<<dim3(8192), 256, 0, stream>>>(q_ws, k_ws, cosT, sinT);
    attn_kernel<<<dim3(128, 28), 64, 0, stream>>>(q_ws, k_ws, v_t, o_ws);
    oproj_kernel<<<dim3(64, 14), 256, 0, stream>>>(o_ws, wo, (float*)d_out);
}

// Round 4
// 331.241 us; speedup vs baseline: 1.1253x; 1.1253x over previous
//
#include <hip/hip_runtime.h>
#include <hip/hip_bf16.h>
#include <cstdint>
#include <cstddef>

// Problem constants
#define Bb   2
#define Tt   2048
#define Cc   896
#define Hh   14
#define HKVc 2
#define Dd   64
#define Mm   (Bb * Tt)        // 4096 rows

typedef __attribute__((ext_vector_type(8))) short bfrag8;   // 8 bf16 (4 VGPRs)
typedef __attribute__((ext_vector_type(4))) float facc4;    // 4 f32 acc
typedef unsigned short u16;

__device__ __forceinline__ float bf2f(u16 v) {
    union { unsigned int u; float f; } c; c.u = ((unsigned int)v) << 16; return c.f;
}
__device__ __forceinline__ u16 f2bf(float f) {
    union { float f; unsigned int u; } c; c.f = f;
    unsigned int u = c.u;
    return (u16)((u + 0x7fffu + ((u >> 16) & 1u)) >> 16);  // RNE
}

// ---------------------------------------------------------------------------
// Kernel 1: fused QKV projection GEMM + bias.  Inputs fp32, ws outputs bf16.
// Block: 256 thr (4 waves). Tile 64(M) x 64(N), K-step 32.
// W staged transposed in LDS as [n][k] (stride 40 elems, 16B-aligned rows).
// V output is written TRANSPOSED: v_t[b][kvh][d][t] so attention can load PV
// B-fragments straight from global (contiguous in t).
// ---------------------------------------------------------------------------
__global__ __launch_bounds__(256)
void qkv_kernel(const float* __restrict__ x,
                const float* __restrict__ wq, const float* __restrict__ bq,
                const float* __restrict__ wk, const float* __restrict__ bk,
                const float* __restrict__ wv, const float* __restrict__ bv,
                u16* __restrict__ q_ws, u16* __restrict__ k_ws, u16* __restrict__ v_t)
{
    __shared__ __align__(16) u16 lds_w[64 * 40];

    const int mt = blockIdx.x;        // 0..63
    const int nt = blockIdx.y;        // 0..17: 14 q-tiles, 2 k-tiles, 2 v-tiles
    const float* W; const float* bias; int ldw, col0;
    if (nt < 14)      { W = wq; bias = bq; ldw = 896; col0 = nt * 64; }
    else if (nt < 16) { W = wk; bias = bk; ldw = 128; col0 = (nt - 14) * 64; }
    else              { W = wv; bias = bv; ldw = 128; col0 = (nt - 16) * 64; }

    const int tid  = threadIdx.x;
    const int lane = tid & 63;
    const int wave = tid >> 6;
    const int lr   = lane & 15;       // A-row / B-col / C-col
    const int quad = lane >> 4;       // k-granule selector
    const int row0 = mt * 64 + wave * 16;

    facc4 acc[4];
    #pragma unroll
    for (int i = 0; i < 4; ++i) acc[i] = (facc4){0.f, 0.f, 0.f, 0.f};

    const int sn  = tid & 63;         // staging: LDS row n
    const int skg = (tid >> 6) * 8;   // staging: k-granule base

    for (int k0 = 0; k0 < 896; k0 += 32) {
        __syncthreads();
        {   // coalesced f32 global loads down a W column group, cvt, one b128 LDS write
            union { u16 s[8]; bfrag8 v; } tw;
            #pragma unroll
            for (int j = 0; j < 8; ++j)
                tw.s[j] = f2bf(W[(size_t)(k0 + skg + j) * ldw + col0 + sn]);
            *(bfrag8*)(&lds_w[sn * 40 + skg]) = tw.v;
        }
        __syncthreads();

        // A-frag: 8 consecutive f32 of an x row -> bf16x8
        const float4* ap = (const float4*)(x + (size_t)(row0 + lr) * 896 + k0 + quad * 8);
        const float4 a0 = ap[0], a1 = ap[1];
        union { u16 s[8]; bfrag8 v; } ta;
        ta.s[0] = f2bf(a0.x); ta.s[1] = f2bf(a0.y); ta.s[2] = f2bf(a0.z); ta.s[3] = f2bf(a0.w);
        ta.s[4] = f2bf(a1.x); ta.s[5] = f2bf(a1.y); ta.s[6] = f2bf(a1.z); ta.s[7] = f2bf(a1.w);

        #pragma unroll
        for (int ct = 0; ct < 4; ++ct) {
            const bfrag8 bfr = *(const bfrag8*)(&lds_w[(ct * 16 + lr) * 40 + quad * 8]);
            acc[ct] = __builtin_amdgcn_mfma_f32_16x16x32_bf16(ta.v, bfr, acc[ct], 0, 0, 0);
        }
    }

    // epilogue: bias + store bf16 (C layout: row = quad*4+r, col = lr)
    const bool is_v = (nt >= 16);
    #pragma unroll
    for (int ct = 0; ct < 4; ++ct) {
        const int col = col0 + ct * 16 + lr;
        const float bb = bias[col];
        #pragma unroll
        for (int r = 0; r < 4; ++r) {
            const int row = row0 + quad * 4 + r;
            const u16 val = f2bf(acc[ct][r] + bb);
            if (is_v) {
                // v_t[((b*2 + kvh)*64 + d) * 2048 + t]
                const int bq_ = row >> 11, t = row & 2047;
                const int kvh = col >> 6, d = col & 63;
                v_t[((size_t)(bq_ * 2 + kvh) * 64 + d) * 2048 + t] = val;
            } else if (nt < 14) {
                q_ws[(size_t)row * 896 + col] = val;
            } else {
                k_ws[(size_t)row * 128 + col] = val;
            }
        }
    }
}

// ---------------------------------------------------------------------------
// Kernel 2: RoPE in-place on bf16 q (B,T,H,D) and k (B,T,HKV,D).
// cos/sin tables are fp32. Thread = one (d, d+32) pair.
// ---------------------------------------------------------------------------
__global__ __launch_bounds__(256)
void rope_kernel(u16* __restrict__ q_ws, u16* __restrict__ k_ws,
                 const float* __restrict__ cosT, const float* __restrict__ sinT)
{
    const int NQ = Bb * Tt * Hh * 32;
    const int NK = Bb * Tt * HKVc * 32;
    const int idx = blockIdx.x * 256 + threadIdx.x;

    u16* p; int t, d;
    if (idx < NQ) {
        d = idx & 31;
        const int h = (idx >> 5) % Hh;
        t = (idx / (32 * Hh)) % Tt;
        const int b = idx / (32 * Hh * Tt);
        p = q_ws + ((size_t)(b * Tt + t) * Hh + h) * 64;
    } else if (idx < NQ + NK) {
        const int i = idx - NQ;
        d = i & 31;
        const int h = (i >> 5) % HKVc;
        t = (i / (32 * HKVc)) % Tt;
        const int b = i / (32 * HKVc * Tt);
        p = k_ws + ((size_t)(b * Tt + t) * HKVc + h) * 64;
    } else {
        return;
    }
    const float c1 = cosT[t * 64 + d],      s1 = sinT[t * 64 + d];
    const float c2 = cosT[t * 64 + d + 32], s2 = sinT[t * 64 + d + 32];
    const float a  = bf2f(p[d]);
    const float b2 = bf2f(p[d + 32]);
    p[d]      = f2bf(a * c1 - b2 * s1);   // first half: q*c - q[d+32]*s
    p[d + 32] = f2bf(b2 * c2 + a * s2);   // second half: q*c + q[d-32]*s
}

// ---------------------------------------------------------------------------
// Kernel 3: flash-style causal attention, wave-autonomous, software-pipelined.
// Block = 1 wave (64 thr) owning 16 Q rows; grid (128 qi) x (28 bh), qi
// reversed so long blocks dispatch first. No __syncthreads anywhere.
// Pipeline: kf (K frags) prefetched one KV-tile ahead; vf (V frags) batch-
// issued at iteration top so their latency hides behind S-MFMA + softmax.
// Named register arrays force the compiler to keep all loads in flight
// (round-3 compiled at 64 VGPRs and serialized every load -> 15k cyc/iter).
// ---------------------------------------------------------------------------
__global__ __launch_bounds__(64)
void attn_kernel(const u16* __restrict__ q_ws, const u16* __restrict__ k_ws,
                 const u16* __restrict__ v_t, u16* __restrict__ o_ws)
{
    __shared__ __align__(16) u16 lds_p[16 * 72];   // 16x64 P, stride 72

    const int qi = 127 - blockIdx.x;      // reversed: long blocks first
    const int bh = blockIdx.y;            // 0..27
    const int b = bh / Hh, h = bh % Hh;
    const int kvh = h / (Hh / HKVc);      // h / 7

    const int lane = threadIdx.x;         // 0..63
    const int lr   = lane & 15;
    const int quad = lane >> 4;
    const int m0   = qi * 16;             // q-row base for this wave

    const u16* Qbase = q_ws + (size_t)(b * Tt) * 896 + h * 64;
    const u16* Kbase = k_ws + (size_t)(b * Tt) * 128 + kvh * 64;
    const u16* Vbase = v_t + (size_t)(b * 2 + kvh) * 64 * 2048;

    // Q fragments for both 32-wide k-steps of D=64, held in regs all kernel
    bfrag8 qf[2];
    #pragma unroll
    for (int ks = 0; ks < 2; ++ks)
        qf[ks] = *(const bfrag8*)(Qbase + (size_t)(m0 + lr) * 896 + ks * 32 + quad * 8);

    float m_r[4], l_r[4];
    #pragma unroll
    for (int r = 0; r < 4; ++r) { m_r[r] = -3e38f; l_r[r] = 0.f; }
    facc4 o_acc[4];
    #pragma unroll
    for (int ct = 0; ct < 4; ++ct) o_acc[ct] = (facc4){0.f, 0.f, 0.f, 0.f};

    const float scale = 0.125f;           // 1/sqrt(64)
    const int nkv = (m0 + 16 + 63) >> 6;  // KV-64 tiles covering causal range

    // --- prefetch K fragments for tile 0 ---
    bfrag8 kf[8];
    #pragma unroll
    for (int ct = 0; ct < 4; ++ct)
        #pragma unroll
        for (int ks = 0; ks < 2; ++ks)
            kf[ct * 2 + ks] = *(const bfrag8*)(
                Kbase + (size_t)(ct * 16 + lr) * 128 + ks * 32 + quad * 8);

    for (int jt = 0; jt < nkv; ++jt) {
        const int j0 = jt * 64;

        // batch-issue all V fragment loads for this tile (latency hides
        // behind S-MFMA + softmax below)
        bfrag8 vf[8];
        #pragma unroll
        for (int ct = 0; ct < 4; ++ct)
            #pragma unroll
            for (int ks = 0; ks < 2; ++ks)
                vf[ct * 2 + ks] = *(const bfrag8*)(
                    Vbase + (size_t)(ct * 16 + lr) * 2048 + j0 + ks * 32 + quad * 8);

        // S = Q K^T from prefetched kf
        facc4 s[4];
        #pragma unroll
        for (int ct = 0; ct < 4; ++ct) {
            s[ct] = (facc4){0.f, 0.f, 0.f, 0.f};
            #pragma unroll
            for (int ks = 0; ks < 2; ++ks)
                s[ct] = __builtin_amdgcn_mfma_f32_16x16x32_bf16(qf[ks], kf[ct * 2 + ks], s[ct], 0, 0, 0);
        }

        // prefetch K fragments for the NEXT tile (wave-uniform clamp keeps
        // the loads unconditional; last-iter result is unused)
        const int jn0 = (jt + 1 < nkv) ? j0 + 64 : j0;
        bfrag8 kfn[8];
        #pragma unroll
        for (int ct = 0; ct < 4; ++ct)
            #pragma unroll
            for (int ks = 0; ks < 2; ++ks)
                kfn[ct * 2 + ks] = *(const bfrag8*)(
                    Kbase + (size_t)(jn0 + ct * 16 + lr) * 128 + ks * 32 + quad * 8);

        // scale + causal mask (only the last tile crosses the diagonal)
        const bool diag = (jt == nkv - 1);
        #pragma unroll
        for (int ct = 0; ct < 4; ++ct) {
            const int j = j0 + ct * 16 + lr;
            #pragma unroll
            for (int r = 0; r < 4; ++r) {
                float sv = s[ct][r] * scale;
                if (diag && j > (m0 + quad * 4 + r)) sv = -3e38f;
                s[ct][r] = sv;
            }
        }

        // online softmax: row max across the quad's 16 lanes
        float alpha[4];
        #pragma unroll
        for (int r = 0; r < 4; ++r) {
            float v = fmaxf(fmaxf(s[0][r], s[1][r]), fmaxf(s[2][r], s[3][r]));
            v = fmaxf(v, __shfl_xor(v, 1));
            v = fmaxf(v, __shfl_xor(v, 2));
            v = fmaxf(v, __shfl_xor(v, 4));
            v = fmaxf(v, __shfl_xor(v, 8));
            const float mn = fmaxf(m_r[r], v);
            alpha[r] = __expf(m_r[r] - mn);
            m_r[r] = mn;
        }

        // P = exp(s - m); write bf16 P to LDS (C-layout -> [row][col])
        float rsum[4] = {0.f, 0.f, 0.f, 0.f};
        #pragma unroll
        for (int ct = 0; ct < 4; ++ct) {
            #pragma unroll
            for (int r = 0; r < 4; ++r) {
                const float p = __expf(s[ct][r] - m_r[r]);
                rsum[r] += p;
                lds_p[(quad * 4 + r) * 72 + ct * 16 + lr] = f2bf(p);
            }
        }
        #pragma unroll
        for (int r = 0; r < 4; ++r) {
            float v = rsum[r];
            v += __shfl_xor(v, 1);
            v += __shfl_xor(v, 2);
            v += __shfl_xor(v, 4);
            v += __shfl_xor(v, 8);
            l_r[r] = l_r[r] * alpha[r] + v;
        }
        #pragma unroll
        for (int ct = 0; ct < 4; ++ct)
            #pragma unroll
            for (int r = 0; r < 4; ++r) o_acc[ct][r] *= alpha[r];

        // O += P @ V from the batched vf
        #pragma unroll
        for (int ks = 0; ks < 2; ++ks) {
            const bfrag8 pf = *(const bfrag8*)(&lds_p[lr * 72 + ks * 32 + quad * 8]);
            #pragma unroll
            for (int ct = 0; ct < 4; ++ct)
                o_acc[ct] = __builtin_amdgcn_mfma_f32_16x16x32_bf16(pf, vf[ct * 2 + ks], o_acc[ct], 0, 0, 0);
        }

        // rotate the K pipeline
        #pragma unroll
        for (int i = 0; i < 8; ++i) kf[i] = kfn[i];
    }

    // epilogue: O / l -> o_ws[b][t][h*64+d] (bf16)
    #pragma unroll
    for (int ct = 0; ct < 4; ++ct) {
        const int dcol = ct * 16 + lr;
        #pragma unroll
        for (int r = 0; r < 4; ++r) {
            const int t = m0 + quad * 4 + r;
            o_ws[(size_t)(b * Tt + t) * 896 + h * 64 + dcol] = f2bf(o_acc[ct][r] / l_r[r]);
        }
    }
}

// ---------------------------------------------------------------------------
// Kernel 4: output projection  o_ws(4096x896 bf16) @ wo(896x896 f32) -> d_out f32
// ---------------------------------------------------------------------------
__global__ __launch_bounds__(256)
void oproj_kernel(const u16* __restrict__ a_in, const float* __restrict__ wo,
                  float* __restrict__ outp)
{
    __shared__ __align__(16) u16 lds_w[64 * 40];

    const int mt = blockIdx.x;        // 0..63
    const int col0 = blockIdx.y * 64; // 0..13 tiles

    const int tid  = threadIdx.x;
    const int lane = tid & 63;
    const int wave = tid >> 6;
    const int lr   = lane & 15;
    const int quad = lane >> 4;
    const int row0 = mt * 64 + wave * 16;

    facc4 acc[4];
    #pragma unroll
    for (int i = 0; i < 4; ++i) acc[i] = (facc4){0.f, 0.f, 0.f, 0.f};

    const int sn  = tid & 63;
    const int skg = (tid >> 6) * 8;

    for (int k0 = 0; k0 < 896; k0 += 32) {
        __syncthreads();
        {
            union { u16 s[8]; bfrag8 v; } tw;
            #pragma unroll
            for (int j = 0; j < 8; ++j)
                tw.s[j] = f2bf(wo[(size_t)(k0 + skg + j) * 896 + col0 + sn]);
            *(bfrag8*)(&lds_w[sn * 40 + skg]) = tw.v;
        }
        __syncthreads();

        const bfrag8 a = *(const bfrag8*)(a_in + (size_t)(row0 + lr) * 896 + k0 + quad * 8);
        #pragma unroll
        for (int ct = 0; ct < 4; ++ct) {
            const bfrag8 bfr = *(const bfrag8*)(&lds_w[(ct * 16 + lr) * 40 + quad * 8]);
            acc[ct] = __builtin_amdgcn_mfma_f32_16x16x32_bf16(a, bfr, acc[ct], 0, 0, 0);
        }
    }

    #pragma unroll
    for (int ct = 0; ct < 4; ++ct) {
        const int col = col0 + ct * 16 + lr;
        #pragma unroll
        for (int r = 0; r < 4; ++r) {
            const int row = row0 + quad * 4 + r;
            outp[(size_t)row * 896 + col] = acc[ct][r];
        }
    }
}

// ---------------------------------------------------------------------------
extern "C" void kernel_launch(void* const* d_in, const int* in_sizes, int n_in,
                              void* d_out, int out_size, void* d_ws, size_t ws_size,
                              hipStream_t stream)
{
    const float* x    = (const float*)d_in[0];
    const float* wq   = (const float*)d_in[1];
    const float* bq   = (const float*)d_in[2];
    const float* wk   = (const float*)d_in[3];
    const float* bk   = (const float*)d_in[4];
    const float* wv   = (const float*)d_in[5];
    const float* bv   = (const float*)d_in[6];
    const float* wo   = (const float*)d_in[7];
    const float* cosT = (const float*)d_in[8];
    const float* sinT = (const float*)d_in[9];
    // d_in[10] = mask: exact causal tril(0 / -1e9) — applied inline in attn_kernel.

    // Workspace layout (bf16), ~16.8 MiB total:
    u16* q_ws = (u16*)d_ws;                              // 4096*896
    u16* k_ws = q_ws + (size_t)Mm * 896;                 // 4096*128
    u16* v_t  = k_ws + (size_t)Mm * 128;                 // 2*2*64*2048 (transposed V)
    u16* o_ws = v_t + (size_t)4 * 64 * 2048;             // 4096*896

    qkv_kernel<<<dim3(64, 18), 256, 0, stream>>>(x, wq, bq, wk, bk, wv, bv,
                                                 q_ws, k_ws, v_t);
    rope_kernel<<<dim3(8192), 256, 0, stream>>>(q_ws, k_ws, cosT, sinT);
    attn_kernel<<<dim3(128, 28), 64, 0, stream>>>(q_ws, k_ws, v_t, o_ws);
    oproj_kernel<<<dim3(64, 14), 256, 0, stream>>>(o_ws, wo, (float*)d_out);
}

// Round 6
// 318.957 us; speedup vs baseline: 1.1686x; 1.0385x over previous
//
#include <hip/hip_runtime.h>
#include <hip/hip_bf16.h>
#include <cstdint>
#include <cstddef>

// Problem constants
#define Bb   2
#define Tt   2048
#define Cc   896
#define Hh   14
#define HKVc 2
#define Dd   64
#define Mm   (Bb * Tt)        // 4096 rows

typedef __attribute__((ext_vector_type(8))) short bfrag8;   // 8 bf16 (4 VGPRs)
typedef __attribute__((ext_vector_type(4))) float facc4;    // 4 f32 acc
typedef unsigned short u16;

__device__ __forceinline__ float bf2f(u16 v) {
    union { unsigned int u; float f; } c; c.u = ((unsigned int)v) << 16; return c.f;
}
__device__ __forceinline__ u16 f2bf(float f) {
    union { float f; unsigned int u; } c; c.f = f;
    unsigned int u = c.u;
    return (u16)((u + 0x7fffu + ((u >> 16) & 1u)) >> 16);  // RNE
}
// HW base-2 exp (v_exp_f32). NB: __exp2f does not exist in HIP device code.
__device__ __forceinline__ float ex2(float x) { return __builtin_amdgcn_exp2f(x); }

// ---------------------------------------------------------------------------
// Kernel 1: fused QKV projection GEMM + bias.  Inputs fp32, ws outputs bf16.
// (unchanged from round 4)
// ---------------------------------------------------------------------------
__global__ __launch_bounds__(256)
void qkv_kernel(const float* __restrict__ x,
                const float* __restrict__ wq, const float* __restrict__ bq,
                const float* __restrict__ wk, const float* __restrict__ bk,
                const float* __restrict__ wv, const float* __restrict__ bv,
                u16* __restrict__ q_ws, u16* __restrict__ k_ws, u16* __restrict__ v_t)
{
    __shared__ __align__(16) u16 lds_w[64 * 40];

    const int mt = blockIdx.x;        // 0..63
    const int nt = blockIdx.y;        // 0..17: 14 q-tiles, 2 k-tiles, 2 v-tiles
    const float* W; const float* bias; int ldw, col0;
    if (nt < 14)      { W = wq; bias = bq; ldw = 896; col0 = nt * 64; }
    else if (nt < 16) { W = wk; bias = bk; ldw = 128; col0 = (nt - 14) * 64; }
    else              { W = wv; bias = bv; ldw = 128; col0 = (nt - 16) * 64; }

    const int tid  = threadIdx.x;
    const int lane = tid & 63;
    const int wave = tid >> 6;
    const int lr   = lane & 15;       // A-row / B-col / C-col
    const int quad = lane >> 4;       // k-granule selector
    const int row0 = mt * 64 + wave * 16;

    facc4 acc[4];
    #pragma unroll
    for (int i = 0; i < 4; ++i) acc[i] = (facc4){0.f, 0.f, 0.f, 0.f};

    const int sn  = tid & 63;         // staging: LDS row n
    const int skg = (tid >> 6) * 8;   // staging: k-granule base

    for (int k0 = 0; k0 < 896; k0 += 32) {
        __syncthreads();
        {   // coalesced f32 global loads down a W column group, cvt, one b128 LDS write
            union { u16 s[8]; bfrag8 v; } tw;
            #pragma unroll
            for (int j = 0; j < 8; ++j)
                tw.s[j] = f2bf(W[(size_t)(k0 + skg + j) * ldw + col0 + sn]);
            *(bfrag8*)(&lds_w[sn * 40 + skg]) = tw.v;
        }
        __syncthreads();

        // A-frag: 8 consecutive f32 of an x row -> bf16x8
        const float4* ap = (const float4*)(x + (size_t)(row0 + lr) * 896 + k0 + quad * 8);
        const float4 a0 = ap[0], a1 = ap[1];
        union { u16 s[8]; bfrag8 v; } ta;
        ta.s[0] = f2bf(a0.x); ta.s[1] = f2bf(a0.y); ta.s[2] = f2bf(a0.z); ta.s[3] = f2bf(a0.w);
        ta.s[4] = f2bf(a1.x); ta.s[5] = f2bf(a1.y); ta.s[6] = f2bf(a1.z); ta.s[7] = f2bf(a1.w);

        #pragma unroll
        for (int ct = 0; ct < 4; ++ct) {
            const bfrag8 bfr = *(const bfrag8*)(&lds_w[(ct * 16 + lr) * 40 + quad * 8]);
            acc[ct] = __builtin_amdgcn_mfma_f32_16x16x32_bf16(ta.v, bfr, acc[ct], 0, 0, 0);
        }
    }

    // epilogue: bias + store bf16 (C layout: row = quad*4+r, col = lr)
    const bool is_v = (nt >= 16);
    #pragma unroll
    for (int ct = 0; ct < 4; ++ct) {
        const int col = col0 + ct * 16 + lr;
        const float bb = bias[col];
        #pragma unroll
        for (int r = 0; r < 4; ++r) {
            const int row = row0 + quad * 4 + r;
            const u16 val = f2bf(acc[ct][r] + bb);
            if (is_v) {
                // v_t[((b*2 + kvh)*64 + d) * 2048 + t]
                const int bq_ = row >> 11, t = row & 2047;
                const int kvh = col >> 6, d = col & 63;
                v_t[((size_t)(bq_ * 2 + kvh) * 64 + d) * 2048 + t] = val;
            } else if (nt < 14) {
                q_ws[(size_t)row * 896 + col] = val;
            } else {
                k_ws[(size_t)row * 128 + col] = val;
            }
        }
    }
}

// ---------------------------------------------------------------------------
// Kernel 2: RoPE in-place on bf16 q (B,T,H,D) and k (B,T,HKV,D). (unchanged)
// ---------------------------------------------------------------------------
__global__ __launch_bounds__(256)
void rope_kernel(u16* __restrict__ q_ws, u16* __restrict__ k_ws,
                 const float* __restrict__ cosT, const float* __restrict__ sinT)
{
    const int NQ = Bb * Tt * Hh * 32;
    const int NK = Bb * Tt * HKVc * 32;
    const int idx = blockIdx.x * 256 + threadIdx.x;

    u16* p; int t, d;
    if (idx < NQ) {
        d = idx & 31;
        const int h = (idx >> 5) % Hh;
        t = (idx / (32 * Hh)) % Tt;
        const int b = idx / (32 * Hh * Tt);
        p = q_ws + ((size_t)(b * Tt + t) * Hh + h) * 64;
    } else if (idx < NQ + NK) {
        const int i = idx - NQ;
        d = i & 31;
        const int h = (i >> 5) % HKVc;
        t = (i / (32 * HKVc)) % Tt;
        const int b = i / (32 * HKVc * Tt);
        p = k_ws + ((size_t)(b * Tt + t) * HKVc + h) * 64;
    } else {
        return;
    }
    const float c1 = cosT[t * 64 + d],      s1 = sinT[t * 64 + d];
    const float c2 = cosT[t * 64 + d + 32], s2 = sinT[t * 64 + d + 32];
    const float a  = bf2f(p[d]);
    const float b2 = bf2f(p[d + 32]);
    p[d]      = f2bf(a * c1 - b2 * s1);   // first half: q*c - q[d+32]*s
    p[d + 32] = f2bf(b2 * c2 + a * s2);   // second half: q*c + q[d-32]*s
}

// ---------------------------------------------------------------------------
// Kernel 3: flash attention with KV-SPLIT ACROSS WAVES (flash-decoding style).
// Block = 256 thr (4 waves), all waves share the same 16 Q rows; wave w
// processes KV tiles jt = w, w+4, w+8, ... keeping private (m, l, O) partials.
// One __syncthreads, then in-LDS merge: O = sum_w exp2(m_w - m_fin) O_w.
// Critical path per block: ceil(nkv/4) iterations instead of nkv (round-4's
// 1-wave blocks serialized 32 iters x ~12k cyc in the drain tail).
// Softmax is base-2 (v_exp_f32); scale*log2e folded into Q fragments once.
// ---------------------------------------------------------------------------
__global__ __launch_bounds__(256)
void attn_kernel(const u16* __restrict__ q_ws, const u16* __restrict__ k_ws,
                 const u16* __restrict__ v_t, u16* __restrict__ o_ws)
{
    __shared__ __align__(16) u16  lds_p[4][16 * 72];    // per-wave P relayout
    __shared__ __align__(16) float lds_o[4][16][65];    // per-wave O partials (+1 pad)
    __shared__ __align__(16) float2 lds_ml[4][16];      // per-wave (m, l) per row

    const int qi = 127 - blockIdx.x;      // reversed: long blocks first
    const int bh = blockIdx.y;            // 0..27
    const int b = bh / Hh, h = bh % Hh;
    const int kvh = h / (Hh / HKVc);      // h / 7

    const int tid  = threadIdx.x;
    const int lane = tid & 63;
    const int wave = tid >> 6;            // KV-split index
    const int lr   = lane & 15;
    const int quad = lane >> 4;
    const int m0   = qi * 16;             // q-row base (same for all 4 waves)

    const u16* Qbase = q_ws + (size_t)(b * Tt) * 896 + h * 64;
    const u16* Kbase = k_ws + (size_t)(b * Tt) * 128 + kvh * 64;
    const u16* Vbase = v_t + (size_t)(b * 2 + kvh) * 64 * 2048;

    // Q fragments, pre-scaled by 1/sqrt(D) * log2(e) (base-2 softmax)
    const float QSC = 0.125f * 1.44269504f;
    bfrag8 qf[2];
    #pragma unroll
    for (int ks = 0; ks < 2; ++ks) {
        union { u16 s[8]; bfrag8 v; } tq;
        tq.v = *(const bfrag8*)(Qbase + (size_t)(m0 + lr) * 896 + ks * 32 + quad * 8);
        #pragma unroll
        for (int j = 0; j < 8; ++j) tq.s[j] = f2bf(bf2f(tq.s[j]) * QSC);
        qf[ks] = tq.v;
    }

    float m_r[4], l_r[4];
    #pragma unroll
    for (int r = 0; r < 4; ++r) { m_r[r] = -3e38f; l_r[r] = 0.f; }
    facc4 o_acc[4];
    #pragma unroll
    for (int ct = 0; ct < 4; ++ct) o_acc[ct] = (facc4){0.f, 0.f, 0.f, 0.f};

    const int nkv = (m0 + 16 + 63) >> 6;  // KV-64 tiles covering causal range
    const int diag_jt = nkv - 1;          // only this tile crosses the diagonal

    for (int jt = wave; jt < nkv; jt += 4) {
        const int j0 = jt * 64;

        // batch-issue all K and V fragment loads for this tile
        bfrag8 kf[8], vf[8];
        #pragma unroll
        for (int ct = 0; ct < 4; ++ct)
            #pragma unroll
            for (int ks = 0; ks < 2; ++ks) {
                kf[ct * 2 + ks] = *(const bfrag8*)(
                    Kbase + (size_t)(j0 + ct * 16 + lr) * 128 + ks * 32 + quad * 8);
                vf[ct * 2 + ks] = *(const bfrag8*)(
                    Vbase + (size_t)(ct * 16 + lr) * 2048 + j0 + ks * 32 + quad * 8);
            }

        // S = (Q*qsc) K^T  -> scores already in log2 domain
        facc4 s[4];
        #pragma unroll
        for (int ct = 0; ct < 4; ++ct) {
            s[ct] = (facc4){0.f, 0.f, 0.f, 0.f};
            #pragma unroll
            for (int ks = 0; ks < 2; ++ks)
                s[ct] = __builtin_amdgcn_mfma_f32_16x16x32_bf16(qf[ks], kf[ct * 2 + ks], s[ct], 0, 0, 0);
        }

        // causal mask (wave-uniform branch; only diagonal tile pays)
        if (jt == diag_jt) {
            #pragma unroll
            for (int ct = 0; ct < 4; ++ct) {
                const int j = j0 + ct * 16 + lr;
                #pragma unroll
                for (int r = 0; r < 4; ++r)
                    if (j > (m0 + quad * 4 + r)) s[ct][r] = -3e38f;
            }
        }

        // online softmax (base-2): row max across the quad's 16 lanes
        float alpha[4];
        #pragma unroll
        for (int r = 0; r < 4; ++r) {
            float v = fmaxf(fmaxf(s[0][r], s[1][r]), fmaxf(s[2][r], s[3][r]));
            v = fmaxf(v, __shfl_xor(v, 1));
            v = fmaxf(v, __shfl_xor(v, 2));
            v = fmaxf(v, __shfl_xor(v, 4));
            v = fmaxf(v, __shfl_xor(v, 8));
            const float mn = fmaxf(m_r[r], v);
            alpha[r] = ex2(m_r[r] - mn);
            m_r[r] = mn;
        }

        // P = exp2(s - m); write bf16 P to this wave's LDS region
        float rsum[4] = {0.f, 0.f, 0.f, 0.f};
        #pragma unroll
        for (int ct = 0; ct < 4; ++ct) {
            #pragma unroll
            for (int r = 0; r < 4; ++r) {
                const float p = ex2(s[ct][r] - m_r[r]);
                rsum[r] += p;
                lds_p[wave][(quad * 4 + r) * 72 + ct * 16 + lr] = f2bf(p);
            }
        }
        #pragma unroll
        for (int r = 0; r < 4; ++r) {
            float v = rsum[r];
            v += __shfl_xor(v, 1);
            v += __shfl_xor(v, 2);
            v += __shfl_xor(v, 4);
            v += __shfl_xor(v, 8);
            l_r[r] = l_r[r] * alpha[r] + v;
        }
        #pragma unroll
        for (int ct = 0; ct < 4; ++ct)
            #pragma unroll
            for (int r = 0; r < 4; ++r) o_acc[ct][r] *= alpha[r];

        // O += P @ V  (within-wave LDS ordering; no barrier needed)
        #pragma unroll
        for (int ks = 0; ks < 2; ++ks) {
            const bfrag8 pf = *(const bfrag8*)(&lds_p[wave][lr * 72 + ks * 32 + quad * 8]);
            #pragma unroll
            for (int ct = 0; ct < 4; ++ct)
                o_acc[ct] = __builtin_amdgcn_mfma_f32_16x16x32_bf16(pf, vf[ct * 2 + ks], o_acc[ct], 0, 0, 0);
        }
    }

    // ---- publish partials ----
    #pragma unroll
    for (int ct = 0; ct < 4; ++ct)
        #pragma unroll
        for (int r = 0; r < 4; ++r)
            lds_o[wave][quad * 4 + r][ct * 16 + lr] = o_acc[ct][r];
    if (lr == 0) {
        #pragma unroll
        for (int r = 0; r < 4; ++r)
            lds_ml[wave][quad * 4 + r] = make_float2(m_r[r], l_r[r]);
    }
    __syncthreads();

    // ---- merge: wave w finalizes column tile ct = w ----
    #pragma unroll
    for (int r = 0; r < 4; ++r) {
        const int row = quad * 4 + r;
        const float2 ml0 = lds_ml[0][row], ml1 = lds_ml[1][row];
        const float2 ml2 = lds_ml[2][row], ml3 = lds_ml[3][row];
        const float m_fin = fmaxf(fmaxf(ml0.x, ml1.x), fmaxf(ml2.x, ml3.x));
        const float f0 = ex2(ml0.x - m_fin), f1 = ex2(ml1.x - m_fin);
        const float f2v = ex2(ml2.x - m_fin), f3 = ex2(ml3.x - m_fin);
        const float l_fin = f0 * ml0.y + f1 * ml1.y + f2v * ml2.y + f3 * ml3.y;
        const int col = wave * 16 + lr;
        const float o = f0 * lds_o[0][row][col] + f1 * lds_o[1][row][col]
                      + f2v * lds_o[2][row][col] + f3 * lds_o[3][row][col];
        const int t = m0 + row;
        o_ws[(size_t)(b * Tt + t) * 896 + h * 64 + col] = f2bf(o / l_fin);
    }
}

// ---------------------------------------------------------------------------
// Kernel 4: output projection  o_ws(4096x896 bf16) @ wo(896x896 f32) -> d_out f32
// (unchanged from round 4)
// ---------------------------------------------------------------------------
__global__ __launch_bounds__(256)
void oproj_kernel(const u16* __restrict__ a_in, const float* __restrict__ wo,
                  float* __restrict__ outp)
{
    __shared__ __align__(16) u16 lds_w[64 * 40];

    const int mt = blockIdx.x;        // 0..63
    const int col0 = blockIdx.y * 64; // 0..13 tiles

    const int tid  = threadIdx.x;
    const int lane = tid & 63;
    const int wave = tid >> 6;
    const int lr   = lane & 15;
    const int quad = lane >> 4;
    const int row0 = mt * 64 + wave * 16;

    facc4 acc[4];
    #pragma unroll
    for (int i = 0; i < 4; ++i) acc[i] = (facc4){0.f, 0.f, 0.f, 0.f};

    const int sn  = tid & 63;
    const int skg = (tid >> 6) * 8;

    for (int k0 = 0; k0 < 896; k0 += 32) {
        __syncthreads();
        {
            union { u16 s[8]; bfrag8 v; } tw;
            #pragma unroll
            for (int j = 0; j < 8; ++j)
                tw.s[j] = f2bf(wo[(size_t)(k0 + skg + j) * 896 + col0 + sn]);
            *(bfrag8*)(&lds_w[sn * 40 + skg]) = tw.v;
        }
        __syncthreads();

        const bfrag8 a = *(const bfrag8*)(a_in + (size_t)(row0 + lr) * 896 + k0 + quad * 8);
        #pragma unroll
        for (int ct = 0; ct < 4; ++ct) {
            const bfrag8 bfr = *(const bfrag8*)(&lds_w[(ct * 16 + lr) * 40 + quad * 8]);
            acc[ct] = __builtin_amdgcn_mfma_f32_16x16x32_bf16(a, bfr, acc[ct], 0, 0, 0);
        }
    }

    #pragma unroll
    for (int ct = 0; ct < 4; ++ct) {
        const int col = col0 + ct * 16 + lr;
        #pragma unroll
        for (int r = 0; r < 4; ++r) {
            const int row = row0 + quad * 4 + r;
            outp[(size_t)row * 896 + col] = acc[ct][r];
        }
    }
}

// ---------------------------------------------------------------------------
extern "C" void kernel_launch(void* const* d_in, const int* in_sizes, int n_in,
                              void* d_out, int out_size, void* d_ws, size_t ws_size,
                              hipStream_t stream)
{
    const float* x    = (const float*)d_in[0];
    const float* wq   = (const float*)d_in[1];
    const float* bq   = (const float*)d_in[2];
    const float* wk   = (const float*)d_in[3];
    const float* bk   = (const float*)d_in[4];
    const float* wv   = (const float*)d_in[5];
    const float* bv   = (const float*)d_in[6];
    const float* wo   = (const float*)d_in[7];
    const float* cosT = (const float*)d_in[8];
    const float* sinT = (const float*)d_in[9];
    // d_in[10] = mask: exact causal tril(0 / -1e9) — applied inline in attn_kernel.

    // Workspace layout (bf16), ~16.8 MiB total:
    u16* q_ws = (u16*)d_ws;                              // 4096*896
    u16* k_ws = q_ws + (size_t)Mm * 896;                 // 4096*128
    u16* v_t  = k_ws + (size_t)Mm * 128;                 // 2*2*64*2048 (transposed V)
    u16* o_ws = v_t + (size_t)4 * 64 * 2048;             // 4096*896

    qkv_kernel<<<dim3(64, 18), 256, 0, stream>>>(x, wq, bq, wk, bk, wv, bv,
                                                 q_ws, k_ws, v_t);
    rope_kernel<<<dim3(8192), 256, 0, stream>>>(q_ws, k_ws, cosT, sinT);
    attn_kernel<<<dim3(128, 28), 256, 0, stream>>>(q_ws, k_ws, v_t, o_ws);
    oproj_kernel<<<dim3(64, 14), 256, 0, stream>>>(o_ws, wo, (float*)d_out);
}

// Round 7
// 315.559 us; speedup vs baseline: 1.1812x; 1.0108x over previous
//
#include <hip/hip_runtime.h>
#include <hip/hip_bf16.h>
#include <cstdint>
#include <cstddef>

// Problem constants
#define Bb   2
#define Tt   2048
#define Cc   896
#define Hh   14
#define HKVc 2
#define Mm   (Bb * Tt)        // 4096 rows

typedef __attribute__((ext_vector_type(8))) short bfrag8;   // 8 bf16 (4 VGPRs)
typedef __attribute__((ext_vector_type(4))) float facc4;    // 4 f32 acc
typedef unsigned short u16;
typedef unsigned int   u32;

// Workspace layout (u16 element offsets). Total 5,750,784 u16 = 11.0 MiB.
// o_ws ALIASES q_ws: each attn block reads only its own (16-row x 64-col)
// q tile at start and overwrites exactly that tile at the end -> disjoint.
#define WQ_BF 0          // 896*896
#define WK_BF 802816     // 896*128
#define WV_BF 917504     // 896*128
#define Q_WS  1032192    // 4096*896  (q, then attention output)
#define K_WS  4702208    // 4096*128
#define V_T   5226496    // 2*2*64*2048 transposed V

__device__ __forceinline__ float bf2f(u16 v) {
    union { u32 u; float f; } c; c.u = ((u32)v) << 16; return c.f;
}
__device__ __forceinline__ u16 f2bf(float f) {
    union { float f; u32 u; } c; c.f = f;
    u32 u = c.u;
    return (u16)((u + 0x7fffu + ((u >> 16) & 1u)) >> 16);  // RNE
}
// HW base-2 exp (v_exp_f32). __exp2f does not exist in HIP device code.
__device__ __forceinline__ float ex2(float x) { return __builtin_amdgcn_exp2f(x); }

// ---------------------------------------------------------------------------
// Kernel 0: one-shot f32->bf16 conversion of wq, wk, wv into workspace.
// 258048 float4s total; grid 1008 x 256, 1 float4/thread.
// ---------------------------------------------------------------------------
__global__ __launch_bounds__(256)
void cvt_w_kernel(const float* __restrict__ wq, const float* __restrict__ wk,
                  const float* __restrict__ wv, u16* __restrict__ ws)
{
    const int i = blockIdx.x * 256 + threadIdx.x;
    const float* src; u16* dst; int off;
    if (i < 200704)      { src = wq; dst = ws + WQ_BF; off = i; }
    else if (i < 229376) { src = wk; dst = ws + WK_BF; off = i - 200704; }
    else                 { src = wv; dst = ws + WV_BF; off = i - 229376; }
    const float4 v = ((const float4*)src)[off];
    union { u16 s[4]; unsigned long long q; } o;
    o.s[0] = f2bf(v.x); o.s[1] = f2bf(v.y); o.s[2] = f2bf(v.z); o.s[3] = f2bf(v.w);
    *(unsigned long long*)(dst + (size_t)off * 4) = o.q;
}

// ---------------------------------------------------------------------------
// Kernel 1: QKV projection, 128x128 tile, BK=32, 4 waves in 2x2, 4x4 acc/wave.
// A (x, f32) staged+converted to LDS; B (bf16 weights) staged transposed
// [n][k] stride 40. y: 0..6 = wq col-slices, 7 = wk, 8 = wv (-> v_t scatter).
// ---------------------------------------------------------------------------
__global__ __launch_bounds__(256)
void qkv_kernel(const float* __restrict__ x,
                const u16* __restrict__ wq_bf, const u16* __restrict__ wk_bf,
                const u16* __restrict__ wv_bf,
                const float* __restrict__ bq, const float* __restrict__ bk,
                const float* __restrict__ bv,
                u16* __restrict__ q_ws, u16* __restrict__ k_ws, u16* __restrict__ v_t)
{
    __shared__ __align__(16) u16 As[128 * 40];
    __shared__ __align__(16) u16 Bs[128 * 40];

    const int mt = blockIdx.x;        // 0..31
    const int y  = blockIdx.y;        // 0..8
    const u16* W; const float* bias; int ldw, colg;
    if (y < 7)       { W = wq_bf; bias = bq; ldw = 896; colg = y * 128; }
    else if (y == 7) { W = wk_bf; bias = bk; ldw = 128; colg = 0; }
    else             { W = wv_bf; bias = bv; ldw = 128; colg = 0; }

    const int tid  = threadIdx.x;
    const int lane = tid & 63, wave = tid >> 6;
    const int lr   = lane & 15, quad = lane >> 4;
    const int wm   = wave & 1,  wn   = wave >> 1;
    const int row0 = mt * 128;

    facc4 acc[4][4];
    #pragma unroll
    for (int i = 0; i < 4; ++i)
        #pragma unroll
        for (int j = 0; j < 4; ++j) acc[i][j] = (facc4){0.f, 0.f, 0.f, 0.f};

    const int arow = tid >> 1, aseg = tid & 1;   // A staging role
    const int bn   = tid & 127, bkg = tid >> 7;  // B staging role

    for (int k0 = 0; k0 < 896; k0 += 32) {
        __syncthreads();
        {   // A: 16 f32 -> bf16 -> 2 b128 LDS writes
            const float4* xp = (const float4*)(x + (size_t)(row0 + arow) * 896 + k0 + aseg * 16);
            const float4 v0 = xp[0], v1 = xp[1], v2 = xp[2], v3 = xp[3];
            union { u16 s[16]; bfrag8 v[2]; } t;
            t.s[0]=f2bf(v0.x); t.s[1]=f2bf(v0.y); t.s[2]=f2bf(v0.z); t.s[3]=f2bf(v0.w);
            t.s[4]=f2bf(v1.x); t.s[5]=f2bf(v1.y); t.s[6]=f2bf(v1.z); t.s[7]=f2bf(v1.w);
            t.s[8]=f2bf(v2.x); t.s[9]=f2bf(v2.y); t.s[10]=f2bf(v2.z); t.s[11]=f2bf(v2.w);
            t.s[12]=f2bf(v3.x); t.s[13]=f2bf(v3.y); t.s[14]=f2bf(v3.z); t.s[15]=f2bf(v3.w);
            *(bfrag8*)(&As[arow * 40 + aseg * 16])     = t.v[0];
            *(bfrag8*)(&As[arow * 40 + aseg * 16 + 8]) = t.v[1];
        }
        {   // B: 16 u16 column loads -> transposed [n][k]
            union { u16 s[16]; bfrag8 v[2]; } t;
            #pragma unroll
            for (int j = 0; j < 16; ++j)
                t.s[j] = W[(size_t)(k0 + bkg * 16 + j) * ldw + colg + bn];
            *(bfrag8*)(&Bs[bn * 40 + bkg * 16])     = t.v[0];
            *(bfrag8*)(&Bs[bn * 40 + bkg * 16 + 8]) = t.v[1];
        }
        __syncthreads();

        bfrag8 af[4], bf[4];
        #pragma unroll
        for (int i = 0; i < 4; ++i)
            af[i] = *(const bfrag8*)(&As[(wm * 64 + i * 16 + lr) * 40 + quad * 8]);
        #pragma unroll
        for (int j = 0; j < 4; ++j)
            bf[j] = *(const bfrag8*)(&Bs[(wn * 64 + j * 16 + lr) * 40 + quad * 8]);
        #pragma unroll
        for (int i = 0; i < 4; ++i)
            #pragma unroll
            for (int j = 0; j < 4; ++j)
                acc[i][j] = __builtin_amdgcn_mfma_f32_16x16x32_bf16(af[i], bf[j], acc[i][j], 0, 0, 0);
    }

    // epilogue: bias + route
    #pragma unroll
    for (int i = 0; i < 4; ++i) {
        #pragma unroll
        for (int j = 0; j < 4; ++j) {
            const int cg = colg + wn * 64 + j * 16 + lr;   // col within q(896) or k/v(128)
            const float bb = bias[cg];
            #pragma unroll
            for (int r = 0; r < 4; ++r) {
                const int row = row0 + wm * 64 + i * 16 + quad * 4 + r;
                const float o = acc[i][j][r] + bb;
                if (y < 7)       q_ws[(size_t)row * 896 + cg] = f2bf(o);
                else if (y == 7) k_ws[(size_t)row * 128 + cg] = f2bf(o);
                else {
                    const int bidx = row >> 11, t = row & 2047;
                    const int kvh = cg >> 6, d = cg & 63;
                    v_t[((size_t)(bidx * 2 + kvh) * 64 + d) * 2048 + t] = f2bf(o);
                }
            }
        }
    }
}

// ---------------------------------------------------------------------------
// Kernel 2: RoPE in-place on bf16 q (B,T,H,D) and k (B,T,HKV,D). (unchanged)
// ---------------------------------------------------------------------------
__global__ __launch_bounds__(256)
void rope_kernel(u16* __restrict__ q_ws, u16* __restrict__ k_ws,
                 const float* __restrict__ cosT, const float* __restrict__ sinT)
{
    const int NQ = Bb * Tt * Hh * 32;
    const int NK = Bb * Tt * HKVc * 32;
    const int idx = blockIdx.x * 256 + threadIdx.x;

    u16* p; int t, d;
    if (idx < NQ) {
        d = idx & 31;
        const int h = (idx >> 5) % Hh;
        t = (idx / (32 * Hh)) % Tt;
        const int b = idx / (32 * Hh * Tt);
        p = q_ws + ((size_t)(b * Tt + t) * Hh + h) * 64;
    } else if (idx < NQ + NK) {
        const int i = idx - NQ;
        d = i & 31;
        const int h = (i >> 5) % HKVc;
        t = (i / (32 * HKVc)) % Tt;
        const int b = i / (32 * HKVc * Tt);
        p = k_ws + ((size_t)(b * Tt + t) * HKVc + h) * 64;
    } else {
        return;
    }
    const float c1 = cosT[t * 64 + d],      s1 = sinT[t * 64 + d];
    const float c2 = cosT[t * 64 + d + 32], s2 = sinT[t * 64 + d + 32];
    const float a  = bf2f(p[d]);
    const float b2 = bf2f(p[d + 32]);
    p[d]      = f2bf(a * c1 - b2 * s1);
    p[d + 32] = f2bf(b2 * c2 + a * s2);
}

// ---------------------------------------------------------------------------
// Kernel 3: flash attention, S-TRANSPOSED formulation + KV-split across waves.
// S^T = K Q^T (operand swap, same fragments): each lane then owns ONE Q row
// (q = lane&15) -> softmax = in-register tree + 2 shfls; m/l/alpha scalar.
// PV: O^T = V^T P^T; P relayout via 8 packed-u32 LDS writes + 2 b128 reads.
// 4 waves split KV tiles (jt = wave, wave+4, ...); in-LDS merge at the end.
// o output aliases q_ws (block-disjoint regions).
// ---------------------------------------------------------------------------
__global__ __launch_bounds__(256)
void attn_kernel(const u16* q_ws, const u16* __restrict__ k_ws,
                 const u16* __restrict__ v_t, u16* o_ws)
{
    __shared__ __align__(16) u16   p_s[4][16 * 72];   // per-wave P^T [q][j]
    __shared__ __align__(16) float o_s[4][64][17];    // per-wave O^T [d][q]
    __shared__ __align__(16) float2 ml_s[4][16];      // per-wave (m,l) per q

    const int qi = 127 - blockIdx.x;      // reversed: long blocks first
    const int bh = blockIdx.y;
    const int b = bh / Hh, h = bh % Hh;
    const int kvh = h / (Hh / HKVc);

    const int tid  = threadIdx.x;
    const int lane = tid & 63;
    const int wave = tid >> 6;
    const int lr   = lane & 15;
    const int quad = lane >> 4;
    const int m0   = qi * 16;

    const u16* Qbase = q_ws + (size_t)(b * Tt) * 896 + h * 64;
    const u16* Kbase = k_ws + (size_t)(b * Tt) * 128 + kvh * 64;
    const u16* Vbase = v_t + (size_t)(b * 2 + kvh) * 64 * 2048;

    // Q fragments (B-operand of S^T), pre-scaled by 1/sqrt(D)*log2(e)
    const float QSC = 0.125f * 1.44269504f;
    bfrag8 qf[2];
    #pragma unroll
    for (int ks = 0; ks < 2; ++ks) {
        union { u16 s[8]; bfrag8 v; } tq;
        tq.v = *(const bfrag8*)(Qbase + (size_t)(m0 + lr) * 896 + ks * 32 + quad * 8);
        #pragma unroll
        for (int j = 0; j < 8; ++j) tq.s[j] = f2bf(bf2f(tq.s[j]) * QSC);
        qf[ks] = tq.v;
    }

    float m_v = -3e38f, l_v = 0.f;        // per-lane: this lane's Q row = lr
    facc4 o_acc[4];
    #pragma unroll
    for (int ct = 0; ct < 4; ++ct) o_acc[ct] = (facc4){0.f, 0.f, 0.f, 0.f};

    const int nkv = (m0 + 79) >> 6;
    const int diag_jt = nkv - 1;

    for (int jt = wave; jt < nkv; jt += 4) {
        const int j0 = jt * 64;

        bfrag8 kf[8], vf[8];
        #pragma unroll
        for (int ct = 0; ct < 4; ++ct)
            #pragma unroll
            for (int ks = 0; ks < 2; ++ks) {
                kf[ct * 2 + ks] = *(const bfrag8*)(
                    Kbase + (size_t)(j0 + ct * 16 + lr) * 128 + ks * 32 + quad * 8);
                vf[ct * 2 + ks] = *(const bfrag8*)(
                    Vbase + (size_t)(ct * 16 + lr) * 2048 + j0 + ks * 32 + quad * 8);
            }

        // S^T = K Q^T : st[ct][r] = S[q=m0+lr][j = j0 + ct*16 + quad*4 + r]
        facc4 st[4];
        #pragma unroll
        for (int ct = 0; ct < 4; ++ct) {
            st[ct] = (facc4){0.f, 0.f, 0.f, 0.f};
            #pragma unroll
            for (int ks = 0; ks < 2; ++ks)
                st[ct] = __builtin_amdgcn_mfma_f32_16x16x32_bf16(kf[ct * 2 + ks], qf[ks], st[ct], 0, 0, 0);
        }

        if (jt == diag_jt) {              // causal mask, diagonal tile only
            #pragma unroll
            for (int ct = 0; ct < 4; ++ct) {
                #pragma unroll
                for (int r = 0; r < 4; ++r)
                    if (j0 + ct * 16 + quad * 4 + r > m0 + lr) st[ct][r] = -3e38f;
            }
        }

        // row max: in-register tree over 16, then 2 shfls across quads
        float mx;
        {
            float a0 = fmaxf(fmaxf(st[0][0], st[0][1]), fmaxf(st[0][2], st[0][3]));
            float a1 = fmaxf(fmaxf(st[1][0], st[1][1]), fmaxf(st[1][2], st[1][3]));
            float a2 = fmaxf(fmaxf(st[2][0], st[2][1]), fmaxf(st[2][2], st[2][3]));
            float a3 = fmaxf(fmaxf(st[3][0], st[3][1]), fmaxf(st[3][2], st[3][3]));
            mx = fmaxf(fmaxf(a0, a1), fmaxf(a2, a3));
        }
        mx = fmaxf(mx, __shfl_xor(mx, 16));
        mx = fmaxf(mx, __shfl_xor(mx, 32));
        const float mn = fmaxf(m_v, mx);
        const float alpha = ex2(m_v - mn);
        m_v = mn;

        // P = exp2(S^T - m), row sum in-register + 2 shfls
        float p[4][4];
        float rs = 0.f;
        #pragma unroll
        for (int ct = 0; ct < 4; ++ct)
            #pragma unroll
            for (int r = 0; r < 4; ++r) {
                p[ct][r] = ex2(st[ct][r] - mn);
                rs += p[ct][r];
            }
        rs += __shfl_xor(rs, 16);
        rs += __shfl_xor(rs, 32);
        l_v = l_v * alpha + rs;
        #pragma unroll
        for (int ct = 0; ct < 4; ++ct) o_acc[ct] = o_acc[ct] * alpha;

        // P^T -> LDS [q=lr][j], packed u32 pairs (8 writes)
        u16* pw = &p_s[wave][lr * 72];
        #pragma unroll
        for (int ct = 0; ct < 4; ++ct) {
            const u32 w0 = (u32)f2bf(p[ct][0]) | ((u32)f2bf(p[ct][1]) << 16);
            const u32 w1 = (u32)f2bf(p[ct][2]) | ((u32)f2bf(p[ct][3]) << 16);
            *(u32*)(pw + ct * 16 + quad * 4)     = w0;
            *(u32*)(pw + ct * 16 + quad * 4 + 2) = w1;
        }

        // O^T += V^T P^T
        #pragma unroll
        for (int ks = 0; ks < 2; ++ks) {
            const bfrag8 pf = *(const bfrag8*)(&p_s[wave][lr * 72 + ks * 32 + quad * 8]);
            #pragma unroll
            for (int ct = 0; ct < 4; ++ct)
                o_acc[ct] = __builtin_amdgcn_mfma_f32_16x16x32_bf16(vf[ct * 2 + ks], pf, o_acc[ct], 0, 0, 0);
        }
    }

    // publish partials: O^T [d][q], (m,l) per q
    #pragma unroll
    for (int ct = 0; ct < 4; ++ct)
        #pragma unroll
        for (int r = 0; r < 4; ++r)
            o_s[wave][ct * 16 + quad * 4 + r][lr] = o_acc[ct][r];
    if (lane < 16) ml_s[wave][lane] = make_float2(m_v, l_v);
    __syncthreads();

    // merge: thread (d = tid&63, qg = tid>>6) handles q = qg*4 + rr
    const int d = tid & 63, qg = tid >> 6;
    #pragma unroll
    for (int rr = 0; rr < 4; ++rr) {
        const int q = qg * 4 + rr;
        const float2 a0 = ml_s[0][q], a1 = ml_s[1][q], a2 = ml_s[2][q], a3 = ml_s[3][q];
        const float mf = fmaxf(fmaxf(a0.x, a1.x), fmaxf(a2.x, a3.x));
        const float f0 = ex2(a0.x - mf), f1 = ex2(a1.x - mf);
        const float f2v = ex2(a2.x - mf), f3 = ex2(a3.x - mf);
        const float lf = f0 * a0.y + f1 * a1.y + f2v * a2.y + f3 * a3.y;
        const float o = f0 * o_s[0][d][q] + f1 * o_s[1][d][q]
                      + f2v * o_s[2][d][q] + f3 * o_s[3][d][q];
        o_ws[(size_t)(b * Tt + m0 + q) * 896 + h * 64 + d] = f2bf(o / lf);
    }
}

// ---------------------------------------------------------------------------
// Kernel 4: output projection, 128x128 tile. A = attention out (bf16, in
// q_ws), B = wo (f32, converted during staging), out = d_out f32.
// ---------------------------------------------------------------------------
__global__ __launch_bounds__(256)
void oproj_kernel(const u16* __restrict__ a_bf, const float* __restrict__ wo,
                  float* __restrict__ outp)
{
    __shared__ __align__(16) u16 As[128 * 40];
    __shared__ __align__(16) u16 Bs[128 * 40];

    const int mt   = blockIdx.x;          // 0..31
    const int col0 = blockIdx.y * 128;    // 0..6

    const int tid  = threadIdx.x;
    const int lane = tid & 63, wave = tid >> 6;
    const int lr   = lane & 15, quad = lane >> 4;
    const int wm   = wave & 1,  wn   = wave >> 1;
    const int row0 = mt * 128;

    facc4 acc[4][4];
    #pragma unroll
    for (int i = 0; i < 4; ++i)
        #pragma unroll
        for (int j = 0; j < 4; ++j) acc[i][j] = (facc4){0.f, 0.f, 0.f, 0.f};

    const int arow = tid >> 1, aseg = tid & 1;
    const int bn   = tid & 127, bkg = tid >> 7;

    for (int k0 = 0; k0 < 896; k0 += 32) {
        __syncthreads();
        {   // A: direct bf16 b128 copies
            const bfrag8* ap = (const bfrag8*)(a_bf + (size_t)(row0 + arow) * 896 + k0 + aseg * 16);
            *(bfrag8*)(&As[arow * 40 + aseg * 16])     = ap[0];
            *(bfrag8*)(&As[arow * 40 + aseg * 16 + 8]) = ap[1];
        }
        {   // B: f32 column loads + cvt -> transposed [n][k]
            union { u16 s[16]; bfrag8 v[2]; } t;
            #pragma unroll
            for (int j = 0; j < 16; ++j)
                t.s[j] = f2bf(wo[(size_t)(k0 + bkg * 16 + j) * 896 + col0 + bn]);
            *(bfrag8*)(&Bs[bn * 40 + bkg * 16])     = t.v[0];
            *(bfrag8*)(&Bs[bn * 40 + bkg * 16 + 8]) = t.v[1];
        }
        __syncthreads();

        bfrag8 af[4], bf[4];
        #pragma unroll
        for (int i = 0; i < 4; ++i)
            af[i] = *(const bfrag8*)(&As[(wm * 64 + i * 16 + lr) * 40 + quad * 8]);
        #pragma unroll
        for (int j = 0; j < 4; ++j)
            bf[j] = *(const bfrag8*)(&Bs[(wn * 64 + j * 16 + lr) * 40 + quad * 8]);
        #pragma unroll
        for (int i = 0; i < 4; ++i)
            #pragma unroll
            for (int j = 0; j < 4; ++j)
                acc[i][j] = __builtin_amdgcn_mfma_f32_16x16x32_bf16(af[i], bf[j], acc[i][j], 0, 0, 0);
    }

    #pragma unroll
    for (int i = 0; i < 4; ++i)
        #pragma unroll
        for (int j = 0; j < 4; ++j) {
            const int col = col0 + wn * 64 + j * 16 + lr;
            #pragma unroll
            for (int r = 0; r < 4; ++r) {
                const int row = row0 + wm * 64 + i * 16 + quad * 4 + r;
                outp[(size_t)row * 896 + col] = acc[i][j][r];
            }
        }
}

// ---------------------------------------------------------------------------
extern "C" void kernel_launch(void* const* d_in, const int* in_sizes, int n_in,
                              void* d_out, int out_size, void* d_ws, size_t ws_size,
                              hipStream_t stream)
{
    const float* x    = (const float*)d_in[0];
    const float* wq   = (const float*)d_in[1];
    const float* bq   = (const float*)d_in[2];
    const float* wk   = (const float*)d_in[3];
    const float* bk   = (const float*)d_in[4];
    const float* wv   = (const float*)d_in[5];
    const float* bv   = (const float*)d_in[6];
    const float* wo   = (const float*)d_in[7];
    const float* cosT = (const float*)d_in[8];
    const float* sinT = (const float*)d_in[9];
    // d_in[10] = mask: exact causal tril(0 / -1e9) — applied inline in attn_kernel.

    u16* ws    = (u16*)d_ws;
    u16* wq_bf = ws + WQ_BF;
    u16* wk_bf = ws + WK_BF;
    u16* wv_bf = ws + WV_BF;
    u16* q_ws  = ws + Q_WS;      // doubles as attention output
    u16* k_ws  = ws + K_WS;
    u16* v_t   = ws + V_T;

    cvt_w_kernel<<<dim3(1008), 256, 0, stream>>>(wq, wk, wv, ws);
    qkv_kernel<<<dim3(32, 9), 256, 0, stream>>>(x, wq_bf, wk_bf, wv_bf,
                                                bq, bk, bv, q_ws, k_ws, v_t);
    rope_kernel<<<dim3(8192), 256, 0, stream>>>(q_ws, k_ws, cosT, sinT);
    attn_kernel<<<dim3(128, 28), 256, 0, stream>>>(q_ws, k_ws, v_t, q_ws);
    oproj_kernel<<<dim3(32, 7), 256, 0, stream>>>(q_ws, wo, (float*)d_out);
}

// Round 8
// 245.565 us; speedup vs baseline: 1.5179x; 1.2850x over previous
//
#include <hip/hip_runtime.h>
#include <hip/hip_bf16.h>
#include <cstdint>
#include <cstddef>

// Problem constants
#define Bb   2
#define Tt   2048
#define Cc   896
#define Hh   14
#define HKVc 2
#define Mm   (Bb * Tt)        // 4096 rows

typedef __attribute__((ext_vector_type(8))) short bfrag8;   // 8 bf16 (4 VGPRs)
typedef __attribute__((ext_vector_type(4))) float facc4;    // 4 f32 acc
typedef unsigned short u16;
typedef unsigned int   u32;

// Workspace layout (u16 element offsets). Total 6,553,600 u16 = 12.5 MiB.
// Packed weights: per-128-col-group, per-32-k-step tiles of [n][k] bf16,
// 128x32 = 4096 elems = 8KB contiguous each.
#define WQ_P  0          // 7*28 tiles
#define WK_P  802816     // 28 tiles
#define WV_P  917504     // 28 tiles
#define WO_P  1032192    // 7*28 tiles
#define Q_WS  1835008    // 4096*896 (q, then attention output; block-disjoint alias)
#define K_T   5505024    // [b][kvh][t][d] = 2*2*2048*64
#define V_T2  6029312    // [b][kvh][jt][d][tin] = 2*2*32*64*64

__device__ __forceinline__ float bf2f(u16 v) {
    union { u32 u; float f; } c; c.u = ((u32)v) << 16; return c.f;
}
__device__ __forceinline__ u16 f2bf(float f) {
    union { float f; u32 u; } c; c.f = f;
    u32 u = c.u;
    return (u16)((u + 0x7fffu + ((u >> 16) & 1u)) >> 16);  // RNE
}
// HW base-2 exp (v_exp_f32). __exp2f does not exist in HIP device code.
__device__ __forceinline__ float ex2(float x) { return __builtin_amdgcn_exp2f(x); }

// ---------------------------------------------------------------------------
// Kernel 0: one-shot pack of wq/wk/wv/wo into bf16 MFMA-ready tiles.
// Block = one 128x32 tile; thread gathers 16 f32 down a column (one-shot cost),
// writes 32B contiguous into the packed tile.
// ---------------------------------------------------------------------------
__global__ __launch_bounds__(256)
void pack_w_kernel(const float* __restrict__ wq, const float* __restrict__ wk,
                   const float* __restrict__ wv, const float* __restrict__ wo,
                   u16* __restrict__ ws)
{
    const int bt = blockIdx.x;            // 0..447
    const float* W; u16* dst; int ldw, tile;
    if (bt < 196)      { W = wq; dst = ws + WQ_P; ldw = 896; tile = bt; }
    else if (bt < 224) { W = wk; dst = ws + WK_P; ldw = 128; tile = bt - 196; }
    else if (bt < 252) { W = wv; dst = ws + WV_P; ldw = 128; tile = bt - 224; }
    else               { W = wo; dst = ws + WO_P; ldw = 896; tile = bt - 252; }
    const int nt = tile / 28, kt = tile % 28;

    const int tid = threadIdx.x;
    const int n = tid & 127, kh = tid >> 7;
    const float* src = W + (size_t)(kt * 32 + kh * 16) * ldw + nt * 128 + n;
    union { u16 s[16]; bfrag8 v[2]; } t;
    #pragma unroll
    for (int j = 0; j < 16; ++j) t.s[j] = f2bf(src[(size_t)j * ldw]);
    u16* d = dst + (size_t)tile * 4096 + n * 32 + kh * 16;
    *(bfrag8*)d       = t.v[0];
    *(bfrag8*)(d + 8) = t.v[1];
}

// ---------------------------------------------------------------------------
// Kernel 1: QKV projection, 128x128 tile, BK=32, 4 waves 2x2, 4x4 acc/wave.
// A (x, f32) staged+converted; B from packed tiles (contiguous 8KB copy).
// y: 0..6 = wq col-groups; 7 = wk -> k_t; 8 = wv -> v_t2 (tiled transpose).
// ---------------------------------------------------------------------------
__global__ __launch_bounds__(256)
void qkv_kernel(const float* __restrict__ x, const u16* __restrict__ ws,
                const float* __restrict__ bq, const float* __restrict__ bk,
                const float* __restrict__ bv,
                u16* __restrict__ q_ws, u16* __restrict__ k_t, u16* __restrict__ v_t2)
{
    __shared__ __align__(16) u16 As[128 * 40];
    __shared__ __align__(16) u16 Bs[128 * 40];

    const int mt = blockIdx.x;        // 0..31
    const int y  = blockIdx.y;        // 0..8
    const u16* wp; const float* bias; int colg;
    if (y < 7)       { wp = ws + WQ_P + (size_t)y * 28 * 4096; bias = bq; colg = y * 128; }
    else if (y == 7) { wp = ws + WK_P; bias = bk; colg = 0; }
    else             { wp = ws + WV_P; bias = bv; colg = 0; }

    const int tid  = threadIdx.x;
    const int lane = tid & 63, wave = tid >> 6;
    const int lr   = lane & 15, quad = lane >> 4;
    const int wm   = wave & 1,  wn   = wave >> 1;
    const int row0 = mt * 128;

    facc4 acc[4][4];
    #pragma unroll
    for (int i = 0; i < 4; ++i)
        #pragma unroll
        for (int j = 0; j < 4; ++j) acc[i][j] = (facc4){0.f, 0.f, 0.f, 0.f};

    const int arow = tid >> 1, aseg = tid & 1;   // A staging role

    for (int kt = 0; kt < 28; ++kt) {
        const int k0 = kt * 32;
        __syncthreads();
        {   // A: 16 f32 -> bf16 -> 2 b128 LDS writes
            const float4* xp = (const float4*)(x + (size_t)(row0 + arow) * 896 + k0 + aseg * 16);
            const float4 v0 = xp[0], v1 = xp[1], v2 = xp[2], v3 = xp[3];
            union { u16 s[16]; bfrag8 v[2]; } t;
            t.s[0]=f2bf(v0.x); t.s[1]=f2bf(v0.y); t.s[2]=f2bf(v0.z); t.s[3]=f2bf(v0.w);
            t.s[4]=f2bf(v1.x); t.s[5]=f2bf(v1.y); t.s[6]=f2bf(v1.z); t.s[7]=f2bf(v1.w);
            t.s[8]=f2bf(v2.x); t.s[9]=f2bf(v2.y); t.s[10]=f2bf(v2.z); t.s[11]=f2bf(v2.w);
            t.s[12]=f2bf(v3.x); t.s[13]=f2bf(v3.y); t.s[14]=f2bf(v3.z); t.s[15]=f2bf(v3.w);
            *(bfrag8*)(&As[arow * 40 + aseg * 16])     = t.v[0];
            *(bfrag8*)(&As[arow * 40 + aseg * 16 + 8]) = t.v[1];
        }
        {   // B: contiguous 8KB packed-tile copy, 2 b128/thread
            const u16* src = wp + (size_t)kt * 4096;
            int c = tid;
            #pragma unroll
            for (int u = 0; u < 2; ++u, c += 256)
                *(bfrag8*)(&Bs[(c >> 2) * 40 + (c & 3) * 8]) = *(const bfrag8*)(src + c * 8);
        }
        __syncthreads();

        bfrag8 af[4], bf[4];
        #pragma unroll
        for (int i = 0; i < 4; ++i)
            af[i] = *(const bfrag8*)(&As[(wm * 64 + i * 16 + lr) * 40 + quad * 8]);
        #pragma unroll
        for (int j = 0; j < 4; ++j)
            bf[j] = *(const bfrag8*)(&Bs[(wn * 64 + j * 16 + lr) * 40 + quad * 8]);
        #pragma unroll
        for (int i = 0; i < 4; ++i)
            #pragma unroll
            for (int j = 0; j < 4; ++j)
                acc[i][j] = __builtin_amdgcn_mfma_f32_16x16x32_bf16(af[i], bf[j], acc[i][j], 0, 0, 0);
    }

    // epilogue: bias + route
    #pragma unroll
    for (int i = 0; i < 4; ++i) {
        #pragma unroll
        for (int j = 0; j < 4; ++j) {
            const int cg = colg + wn * 64 + j * 16 + lr;
            const float bb = bias[cg];
            #pragma unroll
            for (int r = 0; r < 4; ++r) {
                const int row = row0 + wm * 64 + i * 16 + quad * 4 + r;
                const u16 val = f2bf(acc[i][j][r] + bb);
                if (y < 7) {
                    q_ws[(size_t)row * 896 + cg] = val;
                } else {
                    const int b = row >> 11, t = row & 2047;
                    const int kvh = cg >> 6, d = cg & 63;
                    if (y == 7)
                        k_t[((size_t)(b * 2 + kvh) * 2048 + t) * 64 + d] = val;
                    else
                        v_t2[((size_t)(b * 2 + kvh) * 32 + (t >> 6)) * 4096 + d * 64 + (t & 63)] = val;
                }
            }
        }
    }
}

// ---------------------------------------------------------------------------
// Kernel 2: RoPE in-place on bf16 q [row][896] and k_t [b][kvh][t][d].
// ---------------------------------------------------------------------------
__global__ __launch_bounds__(256)
void rope_kernel(u16* __restrict__ q_ws, u16* __restrict__ k_t,
                 const float* __restrict__ cosT, const float* __restrict__ sinT)
{
    const int NQ = Bb * Tt * Hh * 32;
    const int NK = Bb * Tt * HKVc * 32;
    const int idx = blockIdx.x * 256 + threadIdx.x;

    u16* p; int t, d;
    if (idx < NQ) {
        d = idx & 31;
        const int h = (idx >> 5) % Hh;
        t = (idx / (32 * Hh)) % Tt;
        const int b = idx / (32 * Hh * Tt);
        p = q_ws + ((size_t)(b * Tt + t)) * 896 + h * 64;
    } else if (idx < NQ + NK) {
        const int i = idx - NQ;
        d = i & 31;
        const int h = (i >> 5) % HKVc;
        t = (i / (32 * HKVc)) % Tt;
        const int b = i / (32 * HKVc * Tt);
        p = k_t + ((size_t)(b * 2 + h) * 2048 + t) * 64;
    } else {
        return;
    }
    const float c1 = cosT[t * 64 + d],      s1 = sinT[t * 64 + d];
    const float c2 = cosT[t * 64 + d + 32], s2 = sinT[t * 64 + d + 32];
    const float a  = bf2f(p[d]);
    const float b2 = bf2f(p[d + 32]);
    p[d]      = f2bf(a * c1 - b2 * s1);
    p[d + 32] = f2bf(b2 * c2 + a * s2);
}

// ---------------------------------------------------------------------------
// Kernel 3: flash attention. Block = 4 waves x one (qt, b, h); wave w owns Q
// rows qt*64 + w*16 ..+15. Per KV-64 tile: cooperative CONTIGUOUS 8KB copies
// of K-tile and V^T-tile into LDS (2 b128/thread each, zero gather), then
// ds_read_b128 fragments. S^T = K Q^T formulation (per-lane scalar softmax,
// q = lane&15, verified R7). P relayout via wave-private LDS. No KV-split,
// no merge; per-wave 1/l normalization in-register. Output aliases q_ws.
// ---------------------------------------------------------------------------
__global__ __launch_bounds__(256)
void attn_kernel(const u16* q_ws, const u16* __restrict__ k_t,
                 const u16* __restrict__ v_t2, u16* o_ws)
{
    __shared__ __align__(16) u16 Ks[64 * 72];     // K-tile [j][d], pad to 72
    __shared__ __align__(16) u16 Vs[64 * 72];     // V^T-tile [d][tin]
    __shared__ __align__(16) u16 Ps[4][16 * 72];  // per-wave P^T; reused as O^T [d][q] s18

    const int qt = 31 - blockIdx.x;       // reversed: long blocks first
    const int bh = blockIdx.y;
    const int b = bh / Hh, h = bh % Hh;
    const int kvh = h / (Hh / HKVc);

    const int tid  = threadIdx.x;
    const int lane = tid & 63;
    const int wave = tid >> 6;
    const int lr   = lane & 15;
    const int quad = lane >> 4;
    const int m0   = qt * 64 + wave * 16; // this wave's Q-row base

    const u16* Kg = k_t + (size_t)(b * 2 + kvh) * 2048 * 64;
    const u16* Vg = v_t2 + (size_t)(b * 2 + kvh) * 32 * 4096;

    // Q fragments (B-operand of S^T), pre-scaled by 1/sqrt(D)*log2(e)
    const float QSC = 0.125f * 1.44269504f;
    bfrag8 qf[2];
    #pragma unroll
    for (int ks = 0; ks < 2; ++ks) {
        union { u16 s[8]; bfrag8 v; } tq;
        tq.v = *(const bfrag8*)(q_ws + (size_t)(b * 2048 + m0 + lr) * 896 + h * 64 + ks * 32 + quad * 8);
        #pragma unroll
        for (int j = 0; j < 8; ++j) tq.s[j] = f2bf(bf2f(tq.s[j]) * QSC);
        qf[ks] = tq.v;
    }

    float m_v = -3e38f, l_v = 0.f;        // per-lane: q = m0 + lr
    facc4 o_acc[4];
    #pragma unroll
    for (int ct = 0; ct < 4; ++ct) o_acc[ct] = (facc4){0.f, 0.f, 0.f, 0.f};

    const int nkv = qt + 1;

    for (int jt = 0; jt < nkv; ++jt) {
        __syncthreads();                  // prior iter's LDS reads complete
        {   // stage K-tile and V^T-tile: fully contiguous, 2+2 b128/thread
            const u16* ksrc = Kg + (size_t)jt * 4096;
            const u16* vsrc = Vg + (size_t)jt * 4096;
            int c = tid;
            #pragma unroll
            for (int u = 0; u < 2; ++u, c += 256) {
                *(bfrag8*)(&Ks[(c >> 3) * 72 + (c & 7) * 8]) = *(const bfrag8*)(ksrc + c * 8);
                *(bfrag8*)(&Vs[(c >> 3) * 72 + (c & 7) * 8]) = *(const bfrag8*)(vsrc + c * 8);
            }
        }
        __syncthreads();

        bfrag8 kf[8], vf[8];
        #pragma unroll
        for (int ct = 0; ct < 4; ++ct)
            #pragma unroll
            for (int ks = 0; ks < 2; ++ks) {
                kf[ct * 2 + ks] = *(const bfrag8*)(&Ks[(ct * 16 + lr) * 72 + ks * 32 + quad * 8]);
                vf[ct * 2 + ks] = *(const bfrag8*)(&Vs[(ct * 16 + lr) * 72 + ks * 32 + quad * 8]);
            }

        // S^T = K Q^T : st[ct][r] = S[q=m0+lr][j = jt*64 + ct*16 + quad*4 + r]
        facc4 st[4];
        #pragma unroll
        for (int ct = 0; ct < 4; ++ct) {
            st[ct] = (facc4){0.f, 0.f, 0.f, 0.f};
            #pragma unroll
            for (int ks = 0; ks < 2; ++ks)
                st[ct] = __builtin_amdgcn_mfma_f32_16x16x32_bf16(kf[ct * 2 + ks], qf[ks], st[ct], 0, 0, 0);
        }

        if (jt == qt) {                   // only the diagonal tile is masked
            const int jb = jt * 64;
            #pragma unroll
            for (int ct = 0; ct < 4; ++ct)
                #pragma unroll
                for (int r = 0; r < 4; ++r)
                    if (jb + ct * 16 + quad * 4 + r > m0 + lr) st[ct][r] = -3e38f;
        }

        // per-lane online softmax: in-register tree + 2 cross-quad shfls
        float mx;
        {
            float a0 = fmaxf(fmaxf(st[0][0], st[0][1]), fmaxf(st[0][2], st[0][3]));
            float a1 = fmaxf(fmaxf(st[1][0], st[1][1]), fmaxf(st[1][2], st[1][3]));
            float a2 = fmaxf(fmaxf(st[2][0], st[2][1]), fmaxf(st[2][2], st[2][3]));
            float a3 = fmaxf(fmaxf(st[3][0], st[3][1]), fmaxf(st[3][2], st[3][3]));
            mx = fmaxf(fmaxf(a0, a1), fmaxf(a2, a3));
        }
        mx = fmaxf(mx, __shfl_xor(mx, 16));
        mx = fmaxf(mx, __shfl_xor(mx, 32));
        const float mn = fmaxf(m_v, mx);
        const float alpha = ex2(m_v - mn);
        m_v = mn;

        float p[4][4];
        float rs = 0.f;
        #pragma unroll
        for (int ct = 0; ct < 4; ++ct)
            #pragma unroll
            for (int r = 0; r < 4; ++r) {
                p[ct][r] = ex2(st[ct][r] - mn);
                rs += p[ct][r];
            }
        rs += __shfl_xor(rs, 16);
        rs += __shfl_xor(rs, 32);
        l_v = l_v * alpha + rs;
        #pragma unroll
        for (int ct = 0; ct < 4; ++ct) o_acc[ct] = o_acc[ct] * alpha;

        // P^T -> wave-private LDS [q=lr][j], packed u32 pairs
        u16* pw = &Ps[wave][lr * 72];
        #pragma unroll
        for (int ct = 0; ct < 4; ++ct) {
            const u32 w0 = (u32)f2bf(p[ct][0]) | ((u32)f2bf(p[ct][1]) << 16);
            const u32 w1 = (u32)f2bf(p[ct][2]) | ((u32)f2bf(p[ct][3]) << 16);
            *(u32*)(pw + ct * 16 + quad * 4)     = w0;
            *(u32*)(pw + ct * 16 + quad * 4 + 2) = w1;
        }

        // O^T += V^T P^T
        #pragma unroll
        for (int ks = 0; ks < 2; ++ks) {
            const bfrag8 pf = *(const bfrag8*)(&Ps[wave][lr * 72 + ks * 32 + quad * 8]);
            #pragma unroll
            for (int ct = 0; ct < 4; ++ct)
                o_acc[ct] = __builtin_amdgcn_mfma_f32_16x16x32_bf16(vf[ct * 2 + ks], pf, o_acc[ct], 0, 0, 0);
        }
    }

    // normalize (l private to lane's q row) and publish O^T [d][q] stride 18
    __syncthreads();                      // all PV reads of Ps done
    const float inv_l = 1.0f / l_v;
    #pragma unroll
    for (int ct = 0; ct < 4; ++ct)
        #pragma unroll
        for (int r = 0; r < 4; ++r)
            Ps[wave][(ct * 16 + quad * 4 + r) * 18 + lr] = f2bf(o_acc[ct][r] * inv_l);
    __syncthreads();

    // coalesced store: thread (d = tid&63, rg = tid>>6) writes 16 rows
    const int d = tid & 63, rg = tid >> 6;
    #pragma unroll
    for (int rr = 0; rr < 16; ++rr) {
        const int rl = rg * 16 + rr;
        const int w = rl >> 4, q = rl & 15;
        o_ws[(size_t)(b * 2048 + qt * 64 + rl) * 896 + h * 64 + d] = Ps[w][d * 18 + q];
    }
}

// ---------------------------------------------------------------------------
// Kernel 4: output projection, 128x128 tile. A = attention out (bf16 in q_ws,
// contiguous b128 staging), B = packed wo tiles, out = d_out f32.
// ---------------------------------------------------------------------------
__global__ __launch_bounds__(256)
void oproj_kernel(const u16* __restrict__ a_bf, const u16* __restrict__ wo_p,
                  float* __restrict__ outp)
{
    __shared__ __align__(16) u16 As[128 * 40];
    __shared__ __align__(16) u16 Bs[128 * 40];

    const int mt = blockIdx.x;            // 0..31
    const int nt = blockIdx.y;            // 0..6

    const int tid  = threadIdx.x;
    const int lane = tid & 63, wave = tid >> 6;
    const int lr   = lane & 15, quad = lane >> 4;
    const int wm   = wave & 1,  wn   = wave >> 1;
    const int row0 = mt * 128;

    facc4 acc[4][4];
    #pragma unroll
    for (int i = 0; i < 4; ++i)
        #pragma unroll
        for (int j = 0; j < 4; ++j) acc[i][j] = (facc4){0.f, 0.f, 0.f, 0.f};

    for (int kt = 0; kt < 28; ++kt) {
        const int k0 = kt * 32;
        __syncthreads();
        {   // A: bf16 rows, 2 b128/thread
            int c = tid;
            #pragma unroll
            for (int u = 0; u < 2; ++u, c += 256)
                *(bfrag8*)(&As[(c >> 2) * 40 + (c & 3) * 8]) =
                    *(const bfrag8*)(a_bf + (size_t)(row0 + (c >> 2)) * 896 + k0 + (c & 3) * 8);
        }
        {   // B: contiguous packed tile copy
            const u16* src = wo_p + ((size_t)nt * 28 + kt) * 4096;
            int c = tid;
            #pragma unroll
            for (int u = 0; u < 2; ++u, c += 256)
                *(bfrag8*)(&Bs[(c >> 2) * 40 + (c & 3) * 8]) = *(const bfrag8*)(src + c * 8);
        }
        __syncthreads();

        bfrag8 af[4], bf[4];
        #pragma unroll
        for (int i = 0; i < 4; ++i)
            af[i] = *(const bfrag8*)(&As[(wm * 64 + i * 16 + lr) * 40 + quad * 8]);
        #pragma unroll
        for (int j = 0; j < 4; ++j)
            bf[j] = *(const bfrag8*)(&Bs[(wn * 64 + j * 16 + lr) * 40 + quad * 8]);
        #pragma unroll
        for (int i = 0; i < 4; ++i)
            #pragma unroll
            for (int j = 0; j < 4; ++j)
                acc[i][j] = __builtin_amdgcn_mfma_f32_16x16x32_bf16(af[i], bf[j], acc[i][j], 0, 0, 0);
    }

    #pragma unroll
    for (int i = 0; i < 4; ++i)
        #pragma unroll
        for (int j = 0; j < 4; ++j) {
            const int col = nt * 128 + wn * 64 + j * 16 + lr;
            #pragma unroll
            for (int r = 0; r < 4; ++r) {
                const int row = row0 + wm * 64 + i * 16 + quad * 4 + r;
                outp[(size_t)row * 896 + col] = acc[i][j][r];
            }
        }
}

// ---------------------------------------------------------------------------
extern "C" void kernel_launch(void* const* d_in, const int* in_sizes, int n_in,
                              void* d_out, int out_size, void* d_ws, size_t ws_size,
                              hipStream_t stream)
{
    const float* x    = (const float*)d_in[0];
    const float* wq   = (const float*)d_in[1];
    const float* bq   = (const float*)d_in[2];
    const float* wk   = (const float*)d_in[3];
    const float* bk   = (const float*)d_in[4];
    const float* wv   = (const float*)d_in[5];
    const float* bv   = (const float*)d_in[6];
    const float* wo   = (const float*)d_in[7];
    const float* cosT = (const float*)d_in[8];
    const float* sinT = (const float*)d_in[9];
    // d_in[10] = mask: exact causal tril(0 / -1e9) — applied inline in attn_kernel.

    u16* ws   = (u16*)d_ws;
    u16* q_ws = ws + Q_WS;       // q, then attention output (block-disjoint alias)
    u16* k_t  = ws + K_T;
    u16* v_t2 = ws + V_T2;

    pack_w_kernel<<<dim3(448), 256, 0, stream>>>(wq, wk, wv, wo, ws);
    qkv_kernel<<<dim3(32, 9), 256, 0, stream>>>(x, ws, bq, bk, bv, q_ws, k_t, v_t2);
    rope_kernel<<<dim3(8192), 256, 0, stream>>>(q_ws, k_t, cosT, sinT);
    attn_kernel<<<dim3(32, 28), 256, 0, stream>>>(q_ws, k_t, v_t2, q_ws);
    oproj_kernel<<<dim3(32, 7), 256, 0, stream>>>(q_ws, ws + WO_P, (float*)d_out);
}

// Round 9
// 201.476 us; speedup vs baseline: 1.8501x; 1.2188x over previous
//
#include <hip/hip_runtime.h>
#include <hip/hip_bf16.h>
#include <cstdint>
#include <cstddef>

// Problem constants
#define Bb   2
#define Tt   2048
#define Cc   896
#define Hh   14
#define HKVc 2
#define Mm   (Bb * Tt)        // 4096 rows

typedef __attribute__((ext_vector_type(8))) short bfrag8;   // 8 bf16 (4 VGPRs)
typedef __attribute__((ext_vector_type(4))) float facc4;    // 4 f32 acc
typedef unsigned short u16;
typedef unsigned int   u32;

// Workspace layout (u16 element offsets). Total 7,012,352 u16 = 14.0 MiB.
// Packed weights: 128(n) x 64(k) bf16 tiles, [n][k], 16KB contiguous each.
#define WQ_P  0          // 7*14 tiles
#define WK_P  802816     // 14 tiles
#define WV_P  917504     // 14 tiles
#define WO_P  1032192    // 7*14 tiles
#define Q_WS  1835008    // 4096*896 (roped q, then merged attention output)
#define K_T   5505024    // [b][kvh][t][d] = 2*2*2048*64 (roped)
#define V_T2  6029312    // [b][kvh][jt][d][tin] = 2*2*32*64*64
#define ML    6553600    // float2 (m,l) per (entry=half*896+bh*32+qt, row) : 1792*64
// Attention O-partials (bf16, 1792 entries x 64row x 64d = 14,680,064 B) live in
// d_out scratch — oproj fully overwrites d_out afterwards.

__device__ __forceinline__ float bf2f(u16 v) {
    union { u32 u; float f; } c; c.u = ((u32)v) << 16; return c.f;
}
__device__ __forceinline__ u16 f2bf(float f) {
    union { float f; u32 u; } c; c.f = f;
    u32 u = c.u;
    return (u16)((u + 0x7fffu + ((u >> 16) & 1u)) >> 16);  // RNE
}
__device__ __forceinline__ u16 f2bf_trunc(float f) {      // cheap truncate (P only)
    union { float f; u32 u; } c; c.f = f;
    return (u16)(c.u >> 16);
}
// HW base-2 exp (v_exp_f32). __exp2f does not exist in HIP device code.
__device__ __forceinline__ float ex2(float x) { return __builtin_amdgcn_exp2f(x); }

// ---------------------------------------------------------------------------
// Kernel 0: one-shot pack of wq/wk/wv/wo into bf16 128x64 [n][k] tiles.
// Block = one tile. Thread (n = tid>>1, kh = tid&1) gathers 32 f32 down a
// column (one-shot cost), writes 64B contiguous.
// ---------------------------------------------------------------------------
__global__ __launch_bounds__(256)
void pack_w_kernel(const float* __restrict__ wq, const float* __restrict__ wk,
                   const float* __restrict__ wv, const float* __restrict__ wo,
                   u16* __restrict__ ws)
{
    const int bt = blockIdx.x;            // 0..223
    const float* W; u16* dst; int ldw, tile;
    if (bt < 98)       { W = wq; dst = ws + WQ_P; ldw = 896; tile = bt; }
    else if (bt < 112) { W = wk; dst = ws + WK_P; ldw = 128; tile = bt - 98; }
    else if (bt < 126) { W = wv; dst = ws + WV_P; ldw = 128; tile = bt - 112; }
    else               { W = wo; dst = ws + WO_P; ldw = 896; tile = bt - 126; }
    const int nt = tile / 14, kt = tile % 14;

    const int tid = threadIdx.x;
    const int n = tid >> 1, kh = tid & 1;
    const float* src = W + (size_t)(kt * 64 + kh * 32) * ldw + nt * 128 + n;
    union { u16 s[32]; bfrag8 v[4]; } t;
    #pragma unroll
    for (int j = 0; j < 32; ++j) t.s[j] = f2bf(src[(size_t)j * ldw]);
    u16* d = dst + (size_t)tile * 8192 + n * 64 + kh * 32;
    #pragma unroll
    for (int u = 0; u < 4; ++u) *(bfrag8*)(d + u * 8) = t.v[u];
}

// ---------------------------------------------------------------------------
// Kernel 1: QKV projection + bias + FUSED ROPE. Tile 64(M) x 128(N), BK=64,
// 4 waves in 2x2 (32x64 quadrant, 2x4 16x16 accs). A (x f32) staged+converted;
// B from packed tiles (contiguous 16KB copy). Each wave's 64-col quadrant is
// exactly one head, so both RoPE pair elements (d, d+32) are in-register.
// y: 0..6 = wq col-groups -> q_ws; 7 = wk -> k_t (roped); 8 = wv -> v_t2.
// ---------------------------------------------------------------------------
__global__ __launch_bounds__(256)
void qkv_kernel(const float* __restrict__ x, const u16* __restrict__ ws,
                const float* __restrict__ bq, const float* __restrict__ bk,
                const float* __restrict__ bv,
                const float* __restrict__ cosT, const float* __restrict__ sinT,
                u16* __restrict__ q_ws, u16* __restrict__ k_t, u16* __restrict__ v_t2)
{
    __shared__ __align__(16) u16 As[64 * 72];
    __shared__ __align__(16) u16 Bs[128 * 72];

    const int mt = blockIdx.x;        // 0..63
    const int y  = blockIdx.y;        // 0..8
    const u16* wp; const float* bias;
    if (y < 7)       { wp = ws + WQ_P + (size_t)y * 14 * 8192; bias = bq; }
    else if (y == 7) { wp = ws + WK_P; bias = bk; }
    else             { wp = ws + WV_P; bias = bv; }

    const int tid  = threadIdx.x;
    const int lane = tid & 63, wave = tid >> 6;
    const int lr   = lane & 15, quad = lane >> 4;
    const int wm   = wave & 1,  wn   = wave >> 1;
    const int row0 = mt * 64;

    facc4 acc[2][4];
    #pragma unroll
    for (int i = 0; i < 2; ++i)
        #pragma unroll
        for (int j = 0; j < 4; ++j) acc[i][j] = (facc4){0.f, 0.f, 0.f, 0.f};

    for (int kt = 0; kt < 14; ++kt) {
        const int k0 = kt * 64;
        __syncthreads();
        {   // A: 64x64 f32 -> bf16, 2 chunks/thread
            int c = tid;
            #pragma unroll
            for (int u = 0; u < 2; ++u, c += 256) {
                const int row = c >> 3, ch = c & 7;
                const float4* xp = (const float4*)(x + (size_t)(row0 + row) * 896 + k0 + ch * 8);
                const float4 v0 = xp[0], v1 = xp[1];
                union { u16 s[8]; bfrag8 v; } t;
                t.s[0]=f2bf(v0.x); t.s[1]=f2bf(v0.y); t.s[2]=f2bf(v0.z); t.s[3]=f2bf(v0.w);
                t.s[4]=f2bf(v1.x); t.s[5]=f2bf(v1.y); t.s[6]=f2bf(v1.z); t.s[7]=f2bf(v1.w);
                *(bfrag8*)(&As[row * 72 + ch * 8]) = t.v;
            }
        }
        {   // B: contiguous 16KB packed-tile copy, 4 b128/thread
            const u16* src = wp + (size_t)kt * 8192;
            int c = tid;
            #pragma unroll
            for (int u = 0; u < 4; ++u, c += 256)
                *(bfrag8*)(&Bs[(c >> 3) * 72 + (c & 7) * 8]) = *(const bfrag8*)(src + c * 8);
        }
        __syncthreads();

        bfrag8 af[2][2], bf[4][2];
        #pragma unroll
        for (int i = 0; i < 2; ++i)
            #pragma unroll
            for (int ks = 0; ks < 2; ++ks)
                af[i][ks] = *(const bfrag8*)(&As[(wm * 32 + i * 16 + lr) * 72 + ks * 32 + quad * 8]);
        #pragma unroll
        for (int j = 0; j < 4; ++j)
            #pragma unroll
            for (int ks = 0; ks < 2; ++ks)
                bf[j][ks] = *(const bfrag8*)(&Bs[(wn * 64 + j * 16 + lr) * 72 + ks * 32 + quad * 8]);
        #pragma unroll
        for (int i = 0; i < 2; ++i)
            #pragma unroll
            for (int j = 0; j < 4; ++j)
                #pragma unroll
                for (int ks = 0; ks < 2; ++ks)
                    acc[i][j] = __builtin_amdgcn_mfma_f32_16x16x32_bf16(af[i][ks], bf[j][ks], acc[i][j], 0, 0, 0);
    }

    // epilogue: bias + rope (q,k) + route. d_j = j*16+lr within the head.
    float bb[4];
    #pragma unroll
    for (int j = 0; j < 4; ++j)
        bb[j] = bias[(y < 7 ? y * 128 : 0) + wn * 64 + j * 16 + lr];

    #pragma unroll
    for (int i = 0; i < 2; ++i) {
        #pragma unroll
        for (int r = 0; r < 4; ++r) {
            const int row = row0 + wm * 32 + i * 16 + quad * 4 + r;
            const int b = row >> 11, t = row & 2047;
            float v0 = acc[i][0][r] + bb[0];
            float v1 = acc[i][1][r] + bb[1];
            float v2 = acc[i][2][r] + bb[2];
            float v3 = acc[i][3][r] + bb[3];
            if (y <= 7) {   // rope for q and k
                const int tb = t * 64 + lr;
                const float c0 = cosT[tb],      s0 = sinT[tb];
                const float c1 = cosT[tb + 16], s1 = sinT[tb + 16];
                const float c2 = cosT[tb + 32], s2 = sinT[tb + 32];
                const float c3 = cosT[tb + 48], s3 = sinT[tb + 48];
                const float n0 = v0 * c0 - v2 * s0;
                const float n1 = v1 * c1 - v3 * s1;
                const float n2 = v2 * c2 + v0 * s2;
                const float n3 = v3 * c3 + v1 * s3;
                v0 = n0; v1 = n1; v2 = n2; v3 = n3;
            }
            const u16 o0 = f2bf(v0), o1 = f2bf(v1), o2 = f2bf(v2), o3 = f2bf(v3);
            if (y < 7) {
                u16* qp = q_ws + (size_t)row * 896 + y * 128 + wn * 64 + lr;
                qp[0] = o0; qp[16] = o1; qp[32] = o2; qp[48] = o3;
            } else if (y == 7) {
                u16* kp = k_t + ((size_t)(b * 2 + wn) * 2048 + t) * 64 + lr;
                kp[0] = o0; kp[16] = o1; kp[32] = o2; kp[48] = o3;
            } else {
                u16* vp = v_t2 + ((size_t)(b * 2 + wn) * 32 + (t >> 6)) * 4096 + lr * 64 + (t & 63);
                vp[0] = o0; vp[16 * 64] = o1; vp[32 * 64] = o2; vp[48 * 64] = o3;
            }
        }
    }
}

// ---------------------------------------------------------------------------
// Kernel 2: flash attention, KV-SPLIT ACROSS 2 BLOCKS per (qt, bh).
// Grid (64, 28): qx = 63-bx; qt = qx>>1, half = qx&1 (long blocks first).
// Block = 4 waves; wave w owns Q rows qt*64 + w*16 ..+15 (same as R8 inner
// loop: contiguous LDS staging of K/V^T tiles, S^T = K Q^T per-lane softmax).
// Each half covers jt in [0,n0) or [n0,nkv); writes raw partials:
// O (bf16) -> d_out scratch, (m,l) f32 -> ws. combine_kernel merges.
// ---------------------------------------------------------------------------
__global__ __launch_bounds__(256)
void attn_kernel(const u16* __restrict__ q_ws, const u16* __restrict__ k_t,
                 const u16* __restrict__ v_t2, u16* __restrict__ pbuf,
                 float2* __restrict__ mlb)
{
    __shared__ __align__(16) u16 Ks[64 * 72];     // K-tile [j][d]
    __shared__ __align__(16) u16 Vs[64 * 72];     // V^T-tile [d][tin]
    __shared__ __align__(16) u16 Ps[4][16 * 72];  // per-wave P^T; reused as O^T

    const int qx = 63 - blockIdx.x;
    const int qt = qx >> 1, half = qx & 1;
    const int bh = blockIdx.y;
    const int b = bh / Hh, h = bh % Hh;
    const int kvh = h / (Hh / HKVc);

    const int tid  = threadIdx.x;
    const int lane = tid & 63;
    const int wave = tid >> 6;
    const int lr   = lane & 15;
    const int quad = lane >> 4;
    const int m0   = qt * 64 + wave * 16;

    const u16* Kg = k_t + (size_t)(b * 2 + kvh) * 2048 * 64;
    const u16* Vg = v_t2 + (size_t)(b * 2 + kvh) * 32 * 4096;

    // Q fragments (B-operand of S^T), pre-scaled by 1/sqrt(D)*log2(e)
    const float QSC = 0.125f * 1.44269504f;
    bfrag8 qf[2];
    #pragma unroll
    for (int ks = 0; ks < 2; ++ks) {
        union { u16 s[8]; bfrag8 v; } tq;
        tq.v = *(const bfrag8*)(q_ws + (size_t)(b * 2048 + m0 + lr) * 896 + h * 64 + ks * 32 + quad * 8);
        #pragma unroll
        for (int j = 0; j < 8; ++j) tq.s[j] = f2bf(bf2f(tq.s[j]) * QSC);
        qf[ks] = tq.v;
    }

    float m_v = -3e38f, l_v = 0.f;        // per-lane: q row = m0 + lr
    facc4 o_acc[4];
    #pragma unroll
    for (int ct = 0; ct < 4; ++ct) o_acc[ct] = (facc4){0.f, 0.f, 0.f, 0.f};

    const int nkv = qt + 1;
    const int n0  = (nkv + 1) >> 1;
    const int jlo = half ? n0 : 0;
    const int jhi = half ? nkv : n0;

    for (int jt = jlo; jt < jhi; ++jt) {
        __syncthreads();
        {   // stage K-tile and V^T-tile: fully contiguous, 2+2 b128/thread
            const u16* ksrc = Kg + (size_t)jt * 4096;
            const u16* vsrc = Vg + (size_t)jt * 4096;
            int c = tid;
            #pragma unroll
            for (int u = 0; u < 2; ++u, c += 256) {
                *(bfrag8*)(&Ks[(c >> 3) * 72 + (c & 7) * 8]) = *(const bfrag8*)(ksrc + c * 8);
                *(bfrag8*)(&Vs[(c >> 3) * 72 + (c & 7) * 8]) = *(const bfrag8*)(vsrc + c * 8);
            }
        }
        __syncthreads();

        bfrag8 kf[8], vf[8];
        #pragma unroll
        for (int ct = 0; ct < 4; ++ct)
            #pragma unroll
            for (int ks = 0; ks < 2; ++ks) {
                kf[ct * 2 + ks] = *(const bfrag8*)(&Ks[(ct * 16 + lr) * 72 + ks * 32 + quad * 8]);
                vf[ct * 2 + ks] = *(const bfrag8*)(&Vs[(ct * 16 + lr) * 72 + ks * 32 + quad * 8]);
            }

        // S^T = K Q^T : st[ct][r] = S[q=m0+lr][j = jt*64 + ct*16 + quad*4 + r]
        facc4 st[4];
        #pragma unroll
        for (int ct = 0; ct < 4; ++ct) {
            st[ct] = (facc4){0.f, 0.f, 0.f, 0.f};
            #pragma unroll
            for (int ks = 0; ks < 2; ++ks)
                st[ct] = __builtin_amdgcn_mfma_f32_16x16x32_bf16(kf[ct * 2 + ks], qf[ks], st[ct], 0, 0, 0);
        }

        if (jt == qt) {                   // only the diagonal tile is masked
            const int jb = jt * 64;
            #pragma unroll
            for (int ct = 0; ct < 4; ++ct)
                #pragma unroll
                for (int r = 0; r < 4; ++r)
                    if (jb + ct * 16 + quad * 4 + r > m0 + lr) st[ct][r] = -3e38f;
        }

        // per-lane online softmax: in-register tree + 2 cross-quad shfls
        float mx;
        {
            float a0 = fmaxf(fmaxf(st[0][0], st[0][1]), fmaxf(st[0][2], st[0][3]));
            float a1 = fmaxf(fmaxf(st[1][0], st[1][1]), fmaxf(st[1][2], st[1][3]));
            float a2 = fmaxf(fmaxf(st[2][0], st[2][1]), fmaxf(st[2][2], st[2][3]));
            float a3 = fmaxf(fmaxf(st[3][0], st[3][1]), fmaxf(st[3][2], st[3][3]));
            mx = fmaxf(fmaxf(a0, a1), fmaxf(a2, a3));
        }
        mx = fmaxf(mx, __shfl_xor(mx, 16));
        mx = fmaxf(mx, __shfl_xor(mx, 32));
        const float mn = fmaxf(m_v, mx);
        const float alpha = ex2(m_v - mn);
        m_v = mn;

        float p[4][4];
        float rs = 0.f;
        #pragma unroll
        for (int ct = 0; ct < 4; ++ct)
            #pragma unroll
            for (int r = 0; r < 4; ++r) {
                p[ct][r] = ex2(st[ct][r] - mn);
                rs += p[ct][r];
            }
        rs += __shfl_xor(rs, 16);
        rs += __shfl_xor(rs, 32);
        l_v = l_v * alpha + rs;
        #pragma unroll
        for (int ct = 0; ct < 4; ++ct) o_acc[ct] = o_acc[ct] * alpha;

        // P^T -> wave-private LDS [q=lr][j], truncating packed u32 pairs
        u16* pw = &Ps[wave][lr * 72];
        #pragma unroll
        for (int ct = 0; ct < 4; ++ct) {
            const u32 w0 = (u32)f2bf_trunc(p[ct][0]) | ((u32)f2bf_trunc(p[ct][1]) << 16);
            const u32 w1 = (u32)f2bf_trunc(p[ct][2]) | ((u32)f2bf_trunc(p[ct][3]) << 16);
            *(u32*)(pw + ct * 16 + quad * 4)     = w0;
            *(u32*)(pw + ct * 16 + quad * 4 + 2) = w1;
        }

        // O^T += V^T P^T
        #pragma unroll
        for (int ks = 0; ks < 2; ++ks) {
            const bfrag8 pf = *(const bfrag8*)(&Ps[wave][lr * 72 + ks * 32 + quad * 8]);
            #pragma unroll
            for (int ct = 0; ct < 4; ++ct)
                o_acc[ct] = __builtin_amdgcn_mfma_f32_16x16x32_bf16(vf[ct * 2 + ks], pf, o_acc[ct], 0, 0, 0);
        }
    }

    // publish raw partials (no 1/l): O^T [d][q] stride 18 in Ps, then store
    const int e = half * 896 + bh * 32 + qt;
    __syncthreads();
    #pragma unroll
    for (int ct = 0; ct < 4; ++ct)
        #pragma unroll
        for (int r = 0; r < 4; ++r)
            Ps[wave][(ct * 16 + quad * 4 + r) * 18 + lr] = f2bf(o_acc[ct][r]);
    if (quad == 0) mlb[(size_t)e * 64 + wave * 16 + lr] = make_float2(m_v, l_v);
    __syncthreads();

    u16* pb = pbuf + (size_t)e * 4096;
    const int d = tid & 63, rg = tid >> 6;
    #pragma unroll
    for (int rr = 0; rr < 16; ++rr) {
        const int rl = rg * 16 + rr;
        pb[rl * 64 + d] = Ps[rl >> 4][d * 18 + (rl & 15)];
    }
}

// ---------------------------------------------------------------------------
// Kernel 3: merge the 2 KV-split partials -> final attention out (bf16, q_ws).
// Grid (32, 28); thread (d = tid&63, rg = tid>>6) handles 16 rows.
// ---------------------------------------------------------------------------
__global__ __launch_bounds__(256)
void combine_kernel(const u16* __restrict__ pbuf, const float2* __restrict__ mlb,
                    u16* __restrict__ o_ws)
{
    const int qt = blockIdx.x, bh = blockIdx.y;
    const int b = bh / Hh, h = bh % Hh;
    const int e0 = bh * 32 + qt, e1 = 896 + bh * 32 + qt;
    const u16* p0 = pbuf + (size_t)e0 * 4096;
    const u16* p1 = pbuf + (size_t)e1 * 4096;

    const int tid = threadIdx.x;
    const int d = tid & 63, rg = tid >> 6;
    #pragma unroll
    for (int rr = 0; rr < 16; ++rr) {
        const int row = rg * 16 + rr;
        const float2 a0 = mlb[(size_t)e0 * 64 + row];
        const float2 a1 = mlb[(size_t)e1 * 64 + row];
        const float mf = fmaxf(a0.x, a1.x);
        const float f0 = ex2(a0.x - mf), f1 = ex2(a1.x - mf);
        const float lf = f0 * a0.y + f1 * a1.y;
        const float o = f0 * bf2f(p0[row * 64 + d]) + f1 * bf2f(p1[row * 64 + d]);
        o_ws[(size_t)(b * 2048 + qt * 64 + row) * 896 + h * 64 + d] = f2bf(o / lf);
    }
}

// ---------------------------------------------------------------------------
// Kernel 4: output projection, 64x128 tile, BK=64. A = attention out (bf16 in
// q_ws, b128 staging), B = packed wo tiles, out = d_out f32 (overwrites the
// partial scratch).
// ---------------------------------------------------------------------------
__global__ __launch_bounds__(256)
void oproj_kernel(const u16* __restrict__ a_bf, const u16* __restrict__ wo_p,
                  float* __restrict__ outp)
{
    __shared__ __align__(16) u16 As[64 * 72];
    __shared__ __align__(16) u16 Bs[128 * 72];

    const int mt = blockIdx.x;            // 0..63
    const int nt = blockIdx.y;            // 0..6

    const int tid  = threadIdx.x;
    const int lane = tid & 63, wave = tid >> 6;
    const int lr   = lane & 15, quad = lane >> 4;
    const int wm   = wave & 1,  wn   = wave >> 1;
    const int row0 = mt * 64;

    facc4 acc[2][4];
    #pragma unroll
    for (int i = 0; i < 2; ++i)
        #pragma unroll
        for (int j = 0; j < 4; ++j) acc[i][j] = (facc4){0.f, 0.f, 0.f, 0.f};

    for (int kt = 0; kt < 14; ++kt) {
        const int k0 = kt * 64;
        __syncthreads();
        {   // A: bf16 rows, 2 b128/thread
            int c = tid;
            #pragma unroll
            for (int u = 0; u < 2; ++u, c += 256)
                *(bfrag8*)(&As[(c >> 3) * 72 + (c & 7) * 8]) =
                    *(const bfrag8*)(a_bf + (size_t)(row0 + (c >> 3)) * 896 + k0 + (c & 7) * 8);
        }
        {   // B: contiguous packed tile copy, 4 b128/thread
            const u16* src = wo_p + ((size_t)nt * 14 + kt) * 8192;
            int c = tid;
            #pragma unroll
            for (int u = 0; u < 4; ++u, c += 256)
                *(bfrag8*)(&Bs[(c >> 3) * 72 + (c & 7) * 8]) = *(const bfrag8*)(src + c * 8);
        }
        __syncthreads();

        bfrag8 af[2][2], bf[4][2];
        #pragma unroll
        for (int i = 0; i < 2; ++i)
            #pragma unroll
            for (int ks = 0; ks < 2; ++ks)
                af[i][ks] = *(const bfrag8*)(&As[(wm * 32 + i * 16 + lr) * 72 + ks * 32 + quad * 8]);
        #pragma unroll
        for (int j = 0; j < 4; ++j)
            #pragma unroll
            for (int ks = 0; ks < 2; ++ks)
                bf[j][ks] = *(const bfrag8*)(&Bs[(wn * 64 + j * 16 + lr) * 72 + ks * 32 + quad * 8]);
        #pragma unroll
        for (int i = 0; i < 2; ++i)
            #pragma unroll
            for (int j = 0; j < 4; ++j)
                #pragma unroll
                for (int ks = 0; ks < 2; ++ks)
                    acc[i][j] = __builtin_amdgcn_mfma_f32_16x16x32_bf16(af[i][ks], bf[j][ks], acc[i][j], 0, 0, 0);
    }

    #pragma unroll
    for (int i = 0; i < 2; ++i)
        #pragma unroll
        for (int j = 0; j < 4; ++j) {
            const int col = nt * 128 + wn * 64 + j * 16 + lr;
            #pragma unroll
            for (int r = 0; r < 4; ++r) {
                const int row = row0 + wm * 32 + i * 16 + quad * 4 + r;
                outp[(size_t)row * 896 + col] = acc[i][j][r];
            }
        }
}

// ---------------------------------------------------------------------------
extern "C" void kernel_launch(void* const* d_in, const int* in_sizes, int n_in,
                              void* d_out, int out_size, void* d_ws, size_t ws_size,
                              hipStream_t stream)
{
    const float* x    = (const float*)d_in[0];
    const float* wq   = (const float*)d_in[1];
    const float* bq   = (const float*)d_in[2];
    const float* wk   = (const float*)d_in[3];
    const float* bk   = (const float*)d_in[4];
    const float* wv   = (const float*)d_in[5];
    const float* bv   = (const float*)d_in[6];
    const float* wo   = (const float*)d_in[7];
    const float* cosT = (const float*)d_in[8];
    const float* sinT = (const float*)d_in[9];
    // d_in[10] = mask: exact causal tril(0 / -1e9) — applied inline in attn_kernel.

    u16* ws   = (u16*)d_ws;
    u16* q_ws = ws + Q_WS;
    u16* k_t  = ws + K_T;
    u16* v_t2 = ws + V_T2;
    float2* mlb = (float2*)(ws + ML);
    u16* pbuf = (u16*)d_out;     // O-partial scratch; oproj overwrites d_out

    pack_w_kernel<<<dim3(224), 256, 0, stream>>>(wq, wk, wv, wo, ws);
    qkv_kernel<<<dim3(64, 9), 256, 0, stream>>>(x, ws, bq, bk, bv, cosT, sinT,
                                                q_ws, k_t, v_t2);
    attn_kernel<<<dim3(64, 28), 256, 0, stream>>>(q_ws, k_t, v_t2, pbuf, mlb);
    combine_kernel<<<dim3(32, 28), 256, 0, stream>>>(pbuf, mlb, q_ws);
    oproj_kernel<<<dim3(64, 7), 256, 0, stream>>>(q_ws, ws + WO_P, (float*)d_out);
}

// Round 10
// 196.816 us; speedup vs baseline: 1.8939x; 1.0237x over previous
//
#include <hip/hip_runtime.h>
#include <hip/hip_bf16.h>
#include <cstdint>
#include <cstddef>

// Problem constants
#define Bb   2
#define Tt   2048
#define Cc   896
#define Hh   14
#define HKVc 2
#define Mm   (Bb * Tt)        // 4096 rows

typedef __attribute__((ext_vector_type(8))) short bfrag8;   // 8 bf16 (4 VGPRs)
typedef __attribute__((ext_vector_type(4))) float facc4;    // 4 f32 acc
typedef unsigned short u16;
typedef unsigned int   u32;

// Workspace layout (u16 element offsets). Total 7,012,352 u16 = 14.0 MiB.
// All tiled buffers use 64-col tiles with granule-XOR swizzle: the 8-elem
// granule g of row r is stored at g^(r&7). Staging copies stay contiguous;
// LDS fragment reads become conflict-free (2-way max, free per m136).
#define WQ_P  0          // 7*14 tiles of 128x64
#define WK_P  802816     // 14 tiles
#define WV_P  917504     // 14 tiles
#define WO_P  1032192    // 7*14 tiles
#define Q_WS  1835008    // 4096*896: roped q (row-major), later swizzled-tiled attn-out
#define K_T   5505024    // [b][kvh][jt][t&63][d-swizzled] = 2*2*32*4096
#define V_T2  6029312    // [b][kvh][jt][d][tin-swizzled] = 2*2*32*4096
#define ML    6553600    // float2 (m,l): 1792 entries x 64 rows
// d_out scratch timeline: x_bf (swizzled tiles, 7.3MB) during qkv ->
// attn O-partials (14.68MB) -> final f32 output by oproj.

__device__ __forceinline__ float bf2f(u16 v) {
    union { u32 u; float f; } c; c.u = ((u32)v) << 16; return c.f;
}
__device__ __forceinline__ u16 f2bf(float f) {
    union { float f; u32 u; } c; c.f = f;
    u32 u = c.u;
    return (u16)((u + 0x7fffu + ((u >> 16) & 1u)) >> 16);  // RNE
}
__device__ __forceinline__ u16 f2bf_trunc(float f) {      // cheap truncate (P only)
    union { float f; u32 u; } c; c.f = f;
    return (u16)(c.u >> 16);
}
// HW base-2 exp (v_exp_f32). __exp2f does not exist in HIP device code.
__device__ __forceinline__ float ex2(float x) { return __builtin_amdgcn_exp2f(x); }

// ---------------------------------------------------------------------------
// Kernel 0a: x (f32) -> x_bf swizzled 64x64 tiles [mt][kt][row][g^row&7] in
// d_out scratch. One block per tile; 2 chunks of 8 f32 per thread.
// ---------------------------------------------------------------------------
__global__ __launch_bounds__(256)
void cvt_x_kernel(const float* __restrict__ x, u16* __restrict__ x_bf)
{
    const int mt = blockIdx.x, kt = blockIdx.y;
    u16* tile = x_bf + ((size_t)mt * 14 + kt) * 4096;
    int c = threadIdx.x;
    #pragma unroll
    for (int u = 0; u < 2; ++u, c += 256) {
        const int row = c >> 3, g = c & 7;
        const float4* xp = (const float4*)(x + (size_t)(mt * 64 + row) * 896 + kt * 64 + g * 8);
        const float4 v0 = xp[0], v1 = xp[1];
        union { u16 s[8]; bfrag8 v; } t;
        t.s[0]=f2bf(v0.x); t.s[1]=f2bf(v0.y); t.s[2]=f2bf(v0.z); t.s[3]=f2bf(v0.w);
        t.s[4]=f2bf(v1.x); t.s[5]=f2bf(v1.y); t.s[6]=f2bf(v1.z); t.s[7]=f2bf(v1.w);
        *(bfrag8*)(tile + row * 64 + ((g ^ (row & 7)) * 8)) = t.v;
    }
}

// ---------------------------------------------------------------------------
// Kernel 0b: pack wq/wk/wv/wo into bf16 128x64 [n][k-swizzled] tiles.
// ---------------------------------------------------------------------------
__global__ __launch_bounds__(256)
void pack_w_kernel(const float* __restrict__ wq, const float* __restrict__ wk,
                   const float* __restrict__ wv, const float* __restrict__ wo,
                   u16* __restrict__ ws)
{
    const int bt = blockIdx.x;            // 0..223
    const float* W; u16* dst; int ldw, tile;
    if (bt < 98)       { W = wq; dst = ws + WQ_P; ldw = 896; tile = bt; }
    else if (bt < 112) { W = wk; dst = ws + WK_P; ldw = 128; tile = bt - 98; }
    else if (bt < 126) { W = wv; dst = ws + WV_P; ldw = 128; tile = bt - 112; }
    else               { W = wo; dst = ws + WO_P; ldw = 896; tile = bt - 126; }
    const int nt = tile / 14, kt = tile % 14;

    const int tid = threadIdx.x;
    const int n = tid >> 1, kh = tid & 1;
    const float* src = W + (size_t)(kt * 64 + kh * 32) * ldw + nt * 128 + n;
    union { u16 s[32]; bfrag8 v[4]; } t;
    #pragma unroll
    for (int j = 0; j < 32; ++j) t.s[j] = f2bf(src[(size_t)j * ldw]);
    u16* d = dst + (size_t)tile * 8192 + n * 64;
    #pragma unroll
    for (int u = 0; u < 4; ++u)
        *(bfrag8*)(d + ((kh * 4 + u) ^ (n & 7)) * 8) = t.v[u];
}

// ---------------------------------------------------------------------------
// Kernel 1: QKV projection + bias + fused RoPE. 64(M) x 128(N), BK=64.
// A from swizzled x_bf tiles (pure copy), B from packed tiles (pure copy).
// y: 0..6 = wq col-groups -> q_ws (row-major); 7 = wk -> k_t (swizzled tiles,
// roped); 8 = wv -> v_t2 (swizzled transposed tiles).
// ---------------------------------------------------------------------------
__global__ __launch_bounds__(256)
void qkv_kernel(const u16* __restrict__ x_bf, const u16* __restrict__ ws,
                const float* __restrict__ bq, const float* __restrict__ bk,
                const float* __restrict__ bv,
                const float* __restrict__ cosT, const float* __restrict__ sinT,
                u16* __restrict__ q_ws, u16* __restrict__ k_t, u16* __restrict__ v_t2)
{
    __shared__ __align__(16) u16 As[64 * 64];
    __shared__ __align__(16) u16 Bs[128 * 64];

    const int mt = blockIdx.x;        // 0..63
    const int y  = blockIdx.y;        // 0..8
    const u16* wp; const float* bias;
    if (y < 7)       { wp = ws + WQ_P + (size_t)y * 14 * 8192; bias = bq; }
    else if (y == 7) { wp = ws + WK_P; bias = bk; }
    else             { wp = ws + WV_P; bias = bv; }

    const int tid  = threadIdx.x;
    const int lane = tid & 63, wave = tid >> 6;
    const int lr   = lane & 15, quad = lane >> 4;
    const int wm   = wave & 1,  wn   = wave >> 1;
    const int lx   = lr & 7;          // swizzle key for fragment rows

    facc4 acc[2][4];
    #pragma unroll
    for (int i = 0; i < 2; ++i)
        #pragma unroll
        for (int j = 0; j < 4; ++j) acc[i][j] = (facc4){0.f, 0.f, 0.f, 0.f};

    for (int kt = 0; kt < 14; ++kt) {
        __syncthreads();
        {   // A: contiguous swizzled-tile copy, 2 b128/thread
            const u16* src = x_bf + ((size_t)mt * 14 + kt) * 4096;
            *(bfrag8*)(&As[tid * 8])        = *(const bfrag8*)(src + tid * 8);
            *(bfrag8*)(&As[2048 + tid * 8]) = *(const bfrag8*)(src + 2048 + tid * 8);
        }
        {   // B: contiguous 16KB packed-tile copy, 4 b128/thread
            const u16* src = wp + (size_t)kt * 8192;
            int c = tid;
            #pragma unroll
            for (int u = 0; u < 4; ++u, c += 256)
                *(bfrag8*)(&Bs[c * 8]) = *(const bfrag8*)(src + c * 8);
        }
        __syncthreads();

        bfrag8 af[2][2], bf[4][2];
        #pragma unroll
        for (int i = 0; i < 2; ++i)
            #pragma unroll
            for (int ks = 0; ks < 2; ++ks)
                af[i][ks] = *(const bfrag8*)(&As[(wm * 32 + i * 16 + lr) * 64 + ((ks * 4 + quad) ^ lx) * 8]);
        #pragma unroll
        for (int j = 0; j < 4; ++j)
            #pragma unroll
            for (int ks = 0; ks < 2; ++ks)
                bf[j][ks] = *(const bfrag8*)(&Bs[(wn * 64 + j * 16 + lr) * 64 + ((ks * 4 + quad) ^ lx) * 8]);
        #pragma unroll
        for (int i = 0; i < 2; ++i)
            #pragma unroll
            for (int j = 0; j < 4; ++j)
                #pragma unroll
                for (int ks = 0; ks < 2; ++ks)
                    acc[i][j] = __builtin_amdgcn_mfma_f32_16x16x32_bf16(af[i][ks], bf[j][ks], acc[i][j], 0, 0, 0);
    }

    // epilogue: bias + rope (q,k) + route
    float bb[4];
    #pragma unroll
    for (int j = 0; j < 4; ++j)
        bb[j] = bias[(y < 7 ? y * 128 : 0) + wn * 64 + j * 16 + lr];

    #pragma unroll
    for (int i = 0; i < 2; ++i) {
        #pragma unroll
        for (int r = 0; r < 4; ++r) {
            const int row = mt * 64 + wm * 32 + i * 16 + quad * 4 + r;
            const int b = row >> 11, t = row & 2047;
            float v0 = acc[i][0][r] + bb[0];
            float v1 = acc[i][1][r] + bb[1];
            float v2 = acc[i][2][r] + bb[2];
            float v3 = acc[i][3][r] + bb[3];
            if (y <= 7) {   // rope for q and k (pairs d, d+32 in-register)
                const int tb = t * 64 + lr;
                const float c0 = cosT[tb],      s0 = sinT[tb];
                const float c1 = cosT[tb + 16], s1 = sinT[tb + 16];
                const float c2 = cosT[tb + 32], s2 = sinT[tb + 32];
                const float c3 = cosT[tb + 48], s3 = sinT[tb + 48];
                const float n0 = v0 * c0 - v2 * s0;
                const float n1 = v1 * c1 - v3 * s1;
                const float n2 = v2 * c2 + v0 * s2;
                const float n3 = v3 * c3 + v1 * s3;
                v0 = n0; v1 = n1; v2 = n2; v3 = n3;
            }
            const u16 o0 = f2bf(v0), o1 = f2bf(v1), o2 = f2bf(v2), o3 = f2bf(v3);
            if (y < 7) {
                u16* qp = q_ws + (size_t)row * 896 + y * 128 + wn * 64 + lr;
                qp[0] = o0; qp[16] = o1; qp[32] = o2; qp[48] = o3;
            } else if (y == 7) {
                // k_t swizzled tile: [row=t&63][g=(d>>3)^(t&7)], d = j*16+lr
                u16* kp = k_t + ((size_t)(b * 2 + wn) * 32 + (t >> 6)) * 4096
                              + (t & 63) * 64 + (lr & 7);
                const int tx = t & 7, g0 = lr >> 3;
                kp[((g0    ) ^ tx) * 8] = o0;
                kp[((g0 + 2) ^ tx) * 8] = o1;
                kp[((g0 + 4) ^ tx) * 8] = o2;
                kp[((g0 + 6) ^ tx) * 8] = o3;
            } else {
                // v_t2 swizzled tile: [d][g=((t&63)>>3)^(d&7)], d&7 = lr&7
                u16* vp = v_t2 + ((size_t)(b * 2 + wn) * 32 + (t >> 6)) * 4096
                               + ((((t & 63) >> 3) ^ (lr & 7)) * 8) + (t & 7);
                vp[(size_t)(lr     ) * 64] = o0;
                vp[(size_t)(lr + 16) * 64] = o1;
                vp[(size_t)(lr + 32) * 64] = o2;
                vp[(size_t)(lr + 48) * 64] = o3;
            }
        }
    }
}

// ---------------------------------------------------------------------------
// Kernel 2: flash attention, KV-split x2 across blocks, swizzled LDS.
// Grid (64, 28): qx = 63-bx; qt = qx>>1, half = qx&1. Block = 4 waves; wave w
// owns Q rows qt*64 + w*16..+15. K/V tiles staged by contiguous 8KB copies
// (pre-swizzled in memory); fragment reads conflict-free via XOR swizzle.
// Raw partials: O (bf16) -> d_out scratch, (m,l) -> ws.
// ---------------------------------------------------------------------------
__global__ __launch_bounds__(256)
void attn_kernel(const u16* __restrict__ q_ws, const u16* __restrict__ k_t,
                 const u16* __restrict__ v_t2, u16* __restrict__ pbuf,
                 float2* __restrict__ mlb)
{
    __shared__ __align__(16) u16 Ks[64 * 64];     // [j][d-swizzled]
    __shared__ __align__(16) u16 Vs[64 * 64];     // [d][tin-swizzled]
    __shared__ __align__(16) u16 Ps[4][16 * 64];  // per-wave P^T [q][j-swizzled]; reused as O^T [d][q]

    const int qx = 63 - blockIdx.x;
    const int qt = qx >> 1, half = qx & 1;
    const int bh = blockIdx.y;
    const int b = bh / Hh, h = bh % Hh;
    const int kvh = h / (Hh / HKVc);

    const int tid  = threadIdx.x;
    const int lane = tid & 63;
    const int wave = tid >> 6;
    const int lr   = lane & 15;
    const int quad = lane >> 4;
    const int lx   = lr & 7;
    const int m0   = qt * 64 + wave * 16;

    const u16* Kg = k_t + (size_t)(b * 2 + kvh) * 32 * 4096;
    const u16* Vg = v_t2 + (size_t)(b * 2 + kvh) * 32 * 4096;

    // Q fragments (B-operand of S^T), pre-scaled by 1/sqrt(D)*log2(e)
    const float QSC = 0.125f * 1.44269504f;
    bfrag8 qf[2];
    #pragma unroll
    for (int ks = 0; ks < 2; ++ks) {
        union { u16 s[8]; bfrag8 v; } tq;
        tq.v = *(const bfrag8*)(q_ws + (size_t)(b * 2048 + m0 + lr) * 896 + h * 64 + ks * 32 + quad * 8);
        #pragma unroll
        for (int j = 0; j < 8; ++j) tq.s[j] = f2bf(bf2f(tq.s[j]) * QSC);
        qf[ks] = tq.v;
    }

    float m_v = -3e38f, l_v = 0.f;        // per-lane: q row = m0 + lr
    facc4 o_acc[4];
    #pragma unroll
    for (int ct = 0; ct < 4; ++ct) o_acc[ct] = (facc4){0.f, 0.f, 0.f, 0.f};

    const int nkv = qt + 1;
    const int n0  = (nkv + 1) >> 1;
    const int jlo = half ? n0 : 0;
    const int jhi = half ? nkv : n0;

    for (int jt = jlo; jt < jhi; ++jt) {
        __syncthreads();
        {   // stage K and V^T tiles: fully contiguous, 2+2 b128/thread
            const u16* ksrc = Kg + (size_t)jt * 4096;
            const u16* vsrc = Vg + (size_t)jt * 4096;
            int c = tid;
            #pragma unroll
            for (int u = 0; u < 2; ++u, c += 256) {
                *(bfrag8*)(&Ks[c * 8]) = *(const bfrag8*)(ksrc + c * 8);
                *(bfrag8*)(&Vs[c * 8]) = *(const bfrag8*)(vsrc + c * 8);
            }
        }
        __syncthreads();

        bfrag8 kf[8], vf[8];
        #pragma unroll
        for (int ct = 0; ct < 4; ++ct)
            #pragma unroll
            for (int ks = 0; ks < 2; ++ks) {
                kf[ct * 2 + ks] = *(const bfrag8*)(&Ks[(ct * 16 + lr) * 64 + ((ks * 4 + quad) ^ lx) * 8]);
                vf[ct * 2 + ks] = *(const bfrag8*)(&Vs[(ct * 16 + lr) * 64 + ((ks * 4 + quad) ^ lx) * 8]);
            }

        // S^T = K Q^T : st[ct][r] = S[q=m0+lr][j = jt*64 + ct*16 + quad*4 + r]
        facc4 st[4];
        #pragma unroll
        for (int ct = 0; ct < 4; ++ct) {
            st[ct] = (facc4){0.f, 0.f, 0.f, 0.f};
            #pragma unroll
            for (int ks = 0; ks < 2; ++ks)
                st[ct] = __builtin_amdgcn_mfma_f32_16x16x32_bf16(kf[ct * 2 + ks], qf[ks], st[ct], 0, 0, 0);
        }

        if (jt == qt) {                   // only the diagonal tile is masked
            const int jb = jt * 64;
            #pragma unroll
            for (int ct = 0; ct < 4; ++ct)
                #pragma unroll
                for (int r = 0; r < 4; ++r)
                    if (jb + ct * 16 + quad * 4 + r > m0 + lr) st[ct][r] = -3e38f;
        }

        // per-lane online softmax: in-register tree + 2 cross-quad shfls
        float mx;
        {
            float a0 = fmaxf(fmaxf(st[0][0], st[0][1]), fmaxf(st[0][2], st[0][3]));
            float a1 = fmaxf(fmaxf(st[1][0], st[1][1]), fmaxf(st[1][2], st[1][3]));
            float a2 = fmaxf(fmaxf(st[2][0], st[2][1]), fmaxf(st[2][2], st[2][3]));
            float a3 = fmaxf(fmaxf(st[3][0], st[3][1]), fmaxf(st[3][2], st[3][3]));
            mx = fmaxf(fmaxf(a0, a1), fmaxf(a2, a3));
        }
        mx = fmaxf(mx, __shfl_xor(mx, 16));
        mx = fmaxf(mx, __shfl_xor(mx, 32));
        const float mn = fmaxf(m_v, mx);
        const float alpha = ex2(m_v - mn);
        m_v = mn;

        float p[4][4];
        float rs = 0.f;
        #pragma unroll
        for (int ct = 0; ct < 4; ++ct)
            #pragma unroll
            for (int r = 0; r < 4; ++r) {
                p[ct][r] = ex2(st[ct][r] - mn);
                rs += p[ct][r];
            }
        rs += __shfl_xor(rs, 16);
        rs += __shfl_xor(rs, 32);
        l_v = l_v * alpha + rs;
        #pragma unroll
        for (int ct = 0; ct < 4; ++ct) o_acc[ct] = o_acc[ct] * alpha;

        // P^T -> wave-private swizzled LDS [q=lr][j], packed u32 pairs
        u16* pw = &Ps[wave][lr * 64];
        #pragma unroll
        for (int ct = 0; ct < 4; ++ct) {
            const u32 w0 = (u32)f2bf_trunc(p[ct][0]) | ((u32)f2bf_trunc(p[ct][1]) << 16);
            const u32 w1 = (u32)f2bf_trunc(p[ct][2]) | ((u32)f2bf_trunc(p[ct][3]) << 16);
            const int gp = ((ct * 2 + (quad >> 1)) ^ lx) * 8 + (quad & 1) * 4;
            *(u32*)(pw + gp)     = w0;
            *(u32*)(pw + gp + 2) = w1;
        }

        // O^T += V^T P^T
        #pragma unroll
        for (int ks = 0; ks < 2; ++ks) {
            const bfrag8 pf = *(const bfrag8*)(&Ps[wave][lr * 64 + ((ks * 4 + quad) ^ lx) * 8]);
            #pragma unroll
            for (int ct = 0; ct < 4; ++ct)
                o_acc[ct] = __builtin_amdgcn_mfma_f32_16x16x32_bf16(vf[ct * 2 + ks], pf, o_acc[ct], 0, 0, 0);
        }
    }

    // publish raw partials: O^T [d][q] into Ps (wave-private reuse), then store
    const int e = half * 896 + bh * 32 + qt;
    __syncthreads();
    #pragma unroll
    for (int ct = 0; ct < 4; ++ct)
        #pragma unroll
        for (int r = 0; r < 4; ++r)
            Ps[wave][(ct * 16 + quad * 4 + r) * 16 + lr] = f2bf(o_acc[ct][r]);
    if (quad == 0) mlb[(size_t)e * 64 + wave * 16 + lr] = make_float2(m_v, l_v);
    __syncthreads();

    u16* pb = pbuf + (size_t)e * 4096;
    const int d = tid & 63, rg = tid >> 6;
    #pragma unroll
    for (int rr = 0; rr < 16; ++rr) {
        const int rl = rg * 16 + rr;
        pb[rl * 64 + d] = Ps[rl >> 4][d * 16 + (rl & 15)];
    }
}

// ---------------------------------------------------------------------------
// Kernel 3: merge the 2 KV-split partials -> attention out as SWIZZLED 64x64
// tiles [mt][ct=h][row][g^row&7] in the q_ws region (q is dead now).
// ---------------------------------------------------------------------------
__global__ __launch_bounds__(256)
void combine_kernel(const u16* __restrict__ pbuf, const float2* __restrict__ mlb,
                    u16* __restrict__ aout)
{
    const int qt = blockIdx.x, bh = blockIdx.y;
    const int b = bh / Hh, h = bh % Hh;
    const int e0 = bh * 32 + qt, e1 = 896 + bh * 32 + qt;
    const u16* p0 = pbuf + (size_t)e0 * 4096;
    const u16* p1 = pbuf + (size_t)e1 * 4096;

    const int tid = threadIdx.x;
    const int d = tid & 63, rg = tid >> 6;
    #pragma unroll
    for (int rr = 0; rr < 16; ++rr) {
        const int row = rg * 16 + rr;                  // row within 64-tile
        const float2 a0 = mlb[(size_t)e0 * 64 + row];
        const float2 a1 = mlb[(size_t)e1 * 64 + row];
        const float mf = fmaxf(a0.x, a1.x);
        const float f0 = ex2(a0.x - mf), f1 = ex2(a1.x - mf);
        const float lf = f0 * a0.y + f1 * a1.y;
        const float o = f0 * bf2f(p0[row * 64 + d]) + f1 * bf2f(p1[row * 64 + d]);
        const int gmt = (b * 2048 + qt * 64) >> 6;     // global row-tile
        aout[((size_t)gmt * 14 + h) * 4096 + row * 64
             + (((d >> 3) ^ (row & 7)) * 8) + (d & 7)] = f2bf(o / lf);
    }
}

// ---------------------------------------------------------------------------
// Kernel 4: output projection, 64x128, BK=64. A = swizzled attn-out tiles
// (pure copy), B = packed wo tiles (pure copy), out = d_out f32.
// ---------------------------------------------------------------------------
__global__ __launch_bounds__(256)
void oproj_kernel(const u16* __restrict__ a_t, const u16* __restrict__ wo_p,
                  float* __restrict__ outp)
{
    __shared__ __align__(16) u16 As[64 * 64];
    __shared__ __align__(16) u16 Bs[128 * 64];

    const int mt = blockIdx.x;            // 0..63
    const int nt = blockIdx.y;            // 0..6

    const int tid  = threadIdx.x;
    const int lane = tid & 63, wave = tid >> 6;
    const int lr   = lane & 15, quad = lane >> 4;
    const int wm   = wave & 1,  wn   = wave >> 1;
    const int lx   = lr & 7;

    facc4 acc[2][4];
    #pragma unroll
    for (int i = 0; i < 2; ++i)
        #pragma unroll
        for (int j = 0; j < 4; ++j) acc[i][j] = (facc4){0.f, 0.f, 0.f, 0.f};

    for (int kt = 0; kt < 14; ++kt) {
        __syncthreads();
        {   // A: contiguous swizzled-tile copy
            const u16* src = a_t + ((size_t)mt * 14 + kt) * 4096;
            *(bfrag8*)(&As[tid * 8])        = *(const bfrag8*)(src + tid * 8);
            *(bfrag8*)(&As[2048 + tid * 8]) = *(const bfrag8*)(src + 2048 + tid * 8);
        }
        {   // B: contiguous packed tile copy
            const u16* src = wo_p + ((size_t)nt * 14 + kt) * 8192;
            int c = tid;
            #pragma unroll
            for (int u = 0; u < 4; ++u, c += 256)
                *(bfrag8*)(&Bs[c * 8]) = *(const bfrag8*)(src + c * 8);
        }
        __syncthreads();

        bfrag8 af[2][2], bf[4][2];
        #pragma unroll
        for (int i = 0; i < 2; ++i)
            #pragma unroll
            for (int ks = 0; ks < 2; ++ks)
                af[i][ks] = *(const bfrag8*)(&As[(wm * 32 + i * 16 + lr) * 64 + ((ks * 4 + quad) ^ lx) * 8]);
        #pragma unroll
        for (int j = 0; j < 4; ++j)
            #pragma unroll
            for (int ks = 0; ks < 2; ++ks)
                bf[j][ks] = *(const bfrag8*)(&Bs[(wn * 64 + j * 16 + lr) * 64 + ((ks * 4 + quad) ^ lx) * 8]);
        #pragma unroll
        for (int i = 0; i < 2; ++i)
            #pragma unroll
            for (int j = 0; j < 4; ++j)
                #pragma unroll
                for (int ks = 0; ks < 2; ++ks)
                    acc[i][j] = __builtin_amdgcn_mfma_f32_16x16x32_bf16(af[i][ks], bf[j][ks], acc[i][j], 0, 0, 0);
    }

    #pragma unroll
    for (int i = 0; i < 2; ++i)
        #pragma unroll
        for (int j = 0; j < 4; ++j) {
            const int col = nt * 128 + wn * 64 + j * 16 + lr;
            #pragma unroll
            for (int r = 0; r < 4; ++r) {
                const int row = mt * 64 + wm * 32 + i * 16 + quad * 4 + r;
                outp[(size_t)row * 896 + col] = acc[i][j][r];
            }
        }
}

// ---------------------------------------------------------------------------
extern "C" void kernel_launch(void* const* d_in, const int* in_sizes, int n_in,
                              void* d_out, int out_size, void* d_ws, size_t ws_size,
                              hipStream_t stream)
{
    const float* x    = (const float*)d_in[0];
    const float* wq   = (const float*)d_in[1];
    const float* bq   = (const float*)d_in[2];
    const float* wk   = (const float*)d_in[3];
    const float* bk   = (const float*)d_in[4];
    const float* wv   = (const float*)d_in[5];
    const float* bv   = (const float*)d_in[6];
    const float* wo   = (const float*)d_in[7];
    const float* cosT = (const float*)d_in[8];
    const float* sinT = (const float*)d_in[9];
    // d_in[10] = mask: exact causal tril(0 / -1e9) — applied inline in attn_kernel.

    u16* ws   = (u16*)d_ws;
    u16* q_ws = ws + Q_WS;       // q rows, then swizzled attn-out tiles
    u16* k_t  = ws + K_T;
    u16* v_t2 = ws + V_T2;
    float2* mlb = (float2*)(ws + ML);
    u16* scratch = (u16*)d_out;  // x_bf during qkv, then O-partials, then f32 out

    cvt_x_kernel<<<dim3(64, 14), 256, 0, stream>>>(x, scratch);
    pack_w_kernel<<<dim3(224), 256, 0, stream>>>(wq, wk, wv, wo, ws);
    qkv_kernel<<<dim3(64, 9), 256, 0, stream>>>(scratch, ws, bq, bk, bv, cosT, sinT,
                                                q_ws, k_t, v_t2);
    attn_kernel<<<dim3(64, 28), 256, 0, stream>>>(q_ws, k_t, v_t2, scratch, mlb);
    combine_kernel<<<dim3(32, 28), 256, 0, stream>>>(scratch, mlb, q_ws);
    oproj_kernel<<<dim3(64, 7), 256, 0, stream>>>(q_ws, ws + WO_P, (float*)d_out);
}

// Round 11
// 190.561 us; speedup vs baseline: 1.9560x; 1.0328x over previous
//
#include <hip/hip_runtime.h>
#include <hip/hip_bf16.h>
#include <cstdint>
#include <cstddef>

// Problem constants
#define Bb   2
#define Tt   2048
#define Cc   896
#define Hh   14
#define HKVc 2
#define Mm   (Bb * Tt)        // 4096 rows

typedef __attribute__((ext_vector_type(8))) short bfrag8;   // 8 bf16 (4 VGPRs)
typedef __attribute__((ext_vector_type(4))) float facc4;    // 4 f32 acc
typedef unsigned short u16;
typedef unsigned int   u32;

// Workspace layout (u16 element offsets). All tiled buffers use 64-col tiles
// with granule-XOR swizzle (granule g of row r stored at g^(r&7)): staging is
// a contiguous copy, LDS fragment reads are conflict-free.
#define WQ_P  0          // 7*14 tiles of 128x64
#define WK_P  802816     // 14 tiles
#define WV_P  917504     // 14 tiles
#define WO_P  1032192    // 7*14 tiles
#define Q_WS  1835008    // 4096*896: roped q (row-major), later swizzled attn-out tiles
#define K_T   5505024    // [b][kvh][jt][t&63][d-swizzled] = 2*2*32*4096
#define V_T2  6029312    // [b][kvh][jt][d][tin-swizzled] = 2*2*32*4096
#define ML    6553600    // float2 (m,l): 1792 entries x 64 rows
// d_out scratch timeline: x_bf (swizzled tiles, 7.3MB) during qkv ->
// attn O-partials (14.68MB) -> final f32 output by oproj.

__device__ __forceinline__ float bf2f(u16 v) {
    union { u32 u; float f; } c; c.u = ((u32)v) << 16; return c.f;
}
__device__ __forceinline__ u16 f2bf(float f) {
    union { float f; u32 u; } c; c.f = f;
    u32 u = c.u;
    return (u16)((u + 0x7fffu + ((u >> 16) & 1u)) >> 16);  // RNE
}
__device__ __forceinline__ u16 f2bf_trunc(float f) {      // cheap truncate (P only)
    union { float f; u32 u; } c; c.f = f;
    return (u16)(c.u >> 16);
}
// HW base-2 exp (v_exp_f32). __exp2f does not exist in HIP device code.
__device__ __forceinline__ float ex2(float x) { return __builtin_amdgcn_exp2f(x); }

// Async global->LDS DMA, 16B/lane. lds base must be wave-uniform; HW writes
// lane i's data at lds_base + i*16 (m97/m104). g already includes lane*16B.
__device__ __forceinline__ void gld_lds16(u16* lds_uniform, const u16* g_per_lane) {
    __builtin_amdgcn_global_load_lds(
        (const __attribute__((address_space(1))) u32*)g_per_lane,
        (__attribute__((address_space(3))) u32*)lds_uniform, 16, 0, 0);
}

// ---------------------------------------------------------------------------
// Kernel 0a: x (f32) -> x_bf swizzled 64x64 tiles in d_out scratch.
// ---------------------------------------------------------------------------
__global__ __launch_bounds__(256)
void cvt_x_kernel(const float* __restrict__ x, u16* __restrict__ x_bf)
{
    const int mt = blockIdx.x, kt = blockIdx.y;
    u16* tile = x_bf + ((size_t)mt * 14 + kt) * 4096;
    int c = threadIdx.x;
    #pragma unroll
    for (int u = 0; u < 2; ++u, c += 256) {
        const int row = c >> 3, g = c & 7;
        const float4* xp = (const float4*)(x + (size_t)(mt * 64 + row) * 896 + kt * 64 + g * 8);
        const float4 v0 = xp[0], v1 = xp[1];
        union { u16 s[8]; bfrag8 v; } t;
        t.s[0]=f2bf(v0.x); t.s[1]=f2bf(v0.y); t.s[2]=f2bf(v0.z); t.s[3]=f2bf(v0.w);
        t.s[4]=f2bf(v1.x); t.s[5]=f2bf(v1.y); t.s[6]=f2bf(v1.z); t.s[7]=f2bf(v1.w);
        *(bfrag8*)(tile + row * 64 + ((g ^ (row & 7)) * 8)) = t.v;
    }
}

// ---------------------------------------------------------------------------
// Kernel 0b: pack weights into bf16 128x64 [n][k-swizzled] tiles.
// COALESCED: phase 1 reads W rows (contiguous f32), cvt -> LDS [kk][n];
// phase 2 reads LDS transposed, writes 64B contiguous per thread.
// (R10 version gathered 32 strided f32/thread -> ~117MB of line traffic.)
// ---------------------------------------------------------------------------
__global__ __launch_bounds__(256)
void pack_w_kernel(const float* __restrict__ wq, const float* __restrict__ wk,
                   const float* __restrict__ wv, const float* __restrict__ wo,
                   u16* __restrict__ ws)
{
    __shared__ u16 T[64 * 136];           // [kk][n], pad 8

    const int bt = blockIdx.x;            // 0..223
    const float* W; u16* dst; int ldw, tile;
    if (bt < 98)       { W = wq; dst = ws + WQ_P; ldw = 896; tile = bt; }
    else if (bt < 112) { W = wk; dst = ws + WK_P; ldw = 128; tile = bt - 98; }
    else if (bt < 126) { W = wv; dst = ws + WV_P; ldw = 128; tile = bt - 112; }
    else               { W = wo; dst = ws + WO_P; ldw = 896; tile = bt - 126; }
    const int nt = tile / 14, kt = tile % 14;

    const int tid = threadIdx.x;
    {   // phase 1: thread reads 32 contiguous f32 of row kk
        const int kk = tid >> 2, nc = (tid & 3) * 32;
        const float* src = W + (size_t)(kt * 64 + kk) * ldw + nt * 128 + nc;
        union { u16 s[32]; bfrag8 v[4]; } t;
        #pragma unroll
        for (int j = 0; j < 8; ++j) {
            const float4 v = ((const float4*)src)[j];
            t.s[j*4+0]=f2bf(v.x); t.s[j*4+1]=f2bf(v.y); t.s[j*4+2]=f2bf(v.z); t.s[j*4+3]=f2bf(v.w);
        }
        #pragma unroll
        for (int u = 0; u < 4; ++u)
            *(bfrag8*)(&T[kk * 136 + nc + u * 8]) = t.v[u];
    }
    __syncthreads();
    {   // phase 2: thread assembles column n, kh half, writes 64B contiguous
        const int n = tid >> 1, kh = tid & 1;
        union { u16 s[32]; bfrag8 v[4]; } t;
        #pragma unroll
        for (int j = 0; j < 32; ++j) t.s[j] = T[(kh * 32 + j) * 136 + n];
        u16* d = dst + (size_t)tile * 8192 + n * 64;
        #pragma unroll
        for (int u = 0; u < 4; ++u)
            *(bfrag8*)(d + ((kh * 4 + u) ^ (n & 7)) * 8) = t.v[u];
    }
}

// ---------------------------------------------------------------------------
// Kernel 1: QKV projection + bias + fused RoPE. 64(M) x 128(N), BK=64.
// A and B staged by global_load_lds DMA (contiguous pre-swizzled tiles).
// y: 0..6 = wq col-groups -> q_ws; 7 = wk -> k_t (roped); 8 = wv -> v_t2.
// ---------------------------------------------------------------------------
__global__ __launch_bounds__(256)
void qkv_kernel(const u16* __restrict__ x_bf, const u16* __restrict__ ws,
                const float* __restrict__ bq, const float* __restrict__ bk,
                const float* __restrict__ bv,
                const float* __restrict__ cosT, const float* __restrict__ sinT,
                u16* __restrict__ q_ws, u16* __restrict__ k_t, u16* __restrict__ v_t2)
{
    __shared__ __align__(16) u16 As[64 * 64];
    __shared__ __align__(16) u16 Bs[128 * 64];

    const int mt = blockIdx.x;        // 0..63
    const int y  = blockIdx.y;        // 0..8
    const u16* wp; const float* bias;
    if (y < 7)       { wp = ws + WQ_P + (size_t)y * 14 * 8192; bias = bq; }
    else if (y == 7) { wp = ws + WK_P; bias = bk; }
    else             { wp = ws + WV_P; bias = bv; }

    const int tid  = threadIdx.x;
    const int lane = tid & 63, wave = tid >> 6;
    const int lr   = lane & 15, quad = lane >> 4;
    const int wm   = wave & 1,  wn   = wave >> 1;
    const int lx   = lr & 7;

    facc4 acc[2][4];
    #pragma unroll
    for (int i = 0; i < 2; ++i)
        #pragma unroll
        for (int j = 0; j < 4; ++j) acc[i][j] = (facc4){0.f, 0.f, 0.f, 0.f};

    for (int kt = 0; kt < 14; ++kt) {
        __syncthreads();
        {   // A: 8KB DMA (2 chunks/wave), B: 16KB DMA (4 chunks/wave)
            const u16* asrc = x_bf + ((size_t)mt * 14 + kt) * 4096;
            const u16* bsrc = wp + (size_t)kt * 8192;
            #pragma unroll
            for (int u = 0; u < 2; ++u) {
                const int ch = wave * 2 + u;
                gld_lds16(&As[ch * 512], asrc + ch * 512 + lane * 8);
            }
            #pragma unroll
            for (int u = 0; u < 4; ++u) {
                const int ch = wave * 4 + u;
                gld_lds16(&Bs[ch * 512], bsrc + ch * 512 + lane * 8);
            }
        }
        __syncthreads();

        bfrag8 af[2][2], bf[4][2];
        #pragma unroll
        for (int i = 0; i < 2; ++i)
            #pragma unroll
            for (int ks = 0; ks < 2; ++ks)
                af[i][ks] = *(const bfrag8*)(&As[(wm * 32 + i * 16 + lr) * 64 + ((ks * 4 + quad) ^ lx) * 8]);
        #pragma unroll
        for (int j = 0; j < 4; ++j)
            #pragma unroll
            for (int ks = 0; ks < 2; ++ks)
                bf[j][ks] = *(const bfrag8*)(&Bs[(wn * 64 + j * 16 + lr) * 64 + ((ks * 4 + quad) ^ lx) * 8]);
        #pragma unroll
        for (int i = 0; i < 2; ++i)
            #pragma unroll
            for (int j = 0; j < 4; ++j)
                #pragma unroll
                for (int ks = 0; ks < 2; ++ks)
                    acc[i][j] = __builtin_amdgcn_mfma_f32_16x16x32_bf16(af[i][ks], bf[j][ks], acc[i][j], 0, 0, 0);
    }

    // epilogue: bias + rope (q,k) + route
    float bb[4];
    #pragma unroll
    for (int j = 0; j < 4; ++j)
        bb[j] = bias[(y < 7 ? y * 128 : 0) + wn * 64 + j * 16 + lr];

    #pragma unroll
    for (int i = 0; i < 2; ++i) {
        #pragma unroll
        for (int r = 0; r < 4; ++r) {
            const int row = mt * 64 + wm * 32 + i * 16 + quad * 4 + r;
            const int b = row >> 11, t = row & 2047;
            float v0 = acc[i][0][r] + bb[0];
            float v1 = acc[i][1][r] + bb[1];
            float v2 = acc[i][2][r] + bb[2];
            float v3 = acc[i][3][r] + bb[3];
            if (y <= 7) {   // rope (pairs d, d+32 in-register)
                const int tb = t * 64 + lr;
                const float c0 = cosT[tb],      s0 = sinT[tb];
                const float c1 = cosT[tb + 16], s1 = sinT[tb + 16];
                const float c2 = cosT[tb + 32], s2 = sinT[tb + 32];
                const float c3 = cosT[tb + 48], s3 = sinT[tb + 48];
                const float n0 = v0 * c0 - v2 * s0;
                const float n1 = v1 * c1 - v3 * s1;
                const float n2 = v2 * c2 + v0 * s2;
                const float n3 = v3 * c3 + v1 * s3;
                v0 = n0; v1 = n1; v2 = n2; v3 = n3;
            }
            const u16 o0 = f2bf(v0), o1 = f2bf(v1), o2 = f2bf(v2), o3 = f2bf(v3);
            if (y < 7) {
                u16* qp = q_ws + (size_t)row * 896 + y * 128 + wn * 64 + lr;
                qp[0] = o0; qp[16] = o1; qp[32] = o2; qp[48] = o3;
            } else if (y == 7) {
                u16* kp = k_t + ((size_t)(b * 2 + wn) * 32 + (t >> 6)) * 4096
                              + (t & 63) * 64 + (lr & 7);
                const int tx = t & 7, g0 = lr >> 3;
                kp[((g0    ) ^ tx) * 8] = o0;
                kp[((g0 + 2) ^ tx) * 8] = o1;
                kp[((g0 + 4) ^ tx) * 8] = o2;
                kp[((g0 + 6) ^ tx) * 8] = o3;
            } else {
                u16* vp = v_t2 + ((size_t)(b * 2 + wn) * 32 + (t >> 6)) * 4096
                               + ((((t & 63) >> 3) ^ (lr & 7)) * 8) + (t & 7);
                vp[(size_t)(lr     ) * 64] = o0;
                vp[(size_t)(lr + 16) * 64] = o1;
                vp[(size_t)(lr + 32) * 64] = o2;
                vp[(size_t)(lr + 48) * 64] = o3;
            }
        }
    }
}

// ---------------------------------------------------------------------------
// Kernel 2: flash attention, KV-split x2 across blocks, swizzled LDS, DMA
// K/V staging. Grid (64, 28). Raw partials -> d_out scratch + ml -> ws.
// ---------------------------------------------------------------------------
__global__ __launch_bounds__(256)
void attn_kernel(const u16* __restrict__ q_ws, const u16* __restrict__ k_t,
                 const u16* __restrict__ v_t2, u16* __restrict__ pbuf,
                 float2* __restrict__ mlb)
{
    __shared__ __align__(16) u16 Ks[64 * 64];     // [j][d-swizzled]
    __shared__ __align__(16) u16 Vs[64 * 64];     // [d][tin-swizzled]
    __shared__ __align__(16) u16 Ps[4][16 * 64];  // per-wave P^T; reused as O^T

    const int qx = 63 - blockIdx.x;
    const int qt = qx >> 1, half = qx & 1;
    const int bh = blockIdx.y;
    const int b = bh / Hh, h = bh % Hh;
    const int kvh = h / (Hh / HKVc);

    const int tid  = threadIdx.x;
    const int lane = tid & 63;
    const int wave = tid >> 6;
    const int lr   = lane & 15;
    const int quad = lane >> 4;
    const int lx   = lr & 7;
    const int m0   = qt * 64 + wave * 16;

    const u16* Kg = k_t + (size_t)(b * 2 + kvh) * 32 * 4096;
    const u16* Vg = v_t2 + (size_t)(b * 2 + kvh) * 32 * 4096;

    // Q fragments (B-operand of S^T), pre-scaled by 1/sqrt(D)*log2(e)
    const float QSC = 0.125f * 1.44269504f;
    bfrag8 qf[2];
    #pragma unroll
    for (int ks = 0; ks < 2; ++ks) {
        union { u16 s[8]; bfrag8 v; } tq;
        tq.v = *(const bfrag8*)(q_ws + (size_t)(b * 2048 + m0 + lr) * 896 + h * 64 + ks * 32 + quad * 8);
        #pragma unroll
        for (int j = 0; j < 8; ++j) tq.s[j] = f2bf(bf2f(tq.s[j]) * QSC);
        qf[ks] = tq.v;
    }

    float m_v = -3e38f, l_v = 0.f;        // per-lane: q row = m0 + lr
    facc4 o_acc[4];
    #pragma unroll
    for (int ct = 0; ct < 4; ++ct) o_acc[ct] = (facc4){0.f, 0.f, 0.f, 0.f};

    const int nkv = qt + 1;
    const int n0  = (nkv + 1) >> 1;
    const int jlo = half ? n0 : 0;
    const int jhi = half ? nkv : n0;

    for (int jt = jlo; jt < jhi; ++jt) {
        __syncthreads();
        {   // K and V tiles: 8KB DMA each (2 chunks/wave each)
            const u16* ksrc = Kg + (size_t)jt * 4096;
            const u16* vsrc = Vg + (size_t)jt * 4096;
            #pragma unroll
            for (int u = 0; u < 2; ++u) {
                const int ch = wave * 2 + u;
                gld_lds16(&Ks[ch * 512], ksrc + ch * 512 + lane * 8);
                gld_lds16(&Vs[ch * 512], vsrc + ch * 512 + lane * 8);
            }
        }
        __syncthreads();

        bfrag8 kf[8], vf[8];
        #pragma unroll
        for (int ct = 0; ct < 4; ++ct)
            #pragma unroll
            for (int ks = 0; ks < 2; ++ks) {
                kf[ct * 2 + ks] = *(const bfrag8*)(&Ks[(ct * 16 + lr) * 64 + ((ks * 4 + quad) ^ lx) * 8]);
                vf[ct * 2 + ks] = *(const bfrag8*)(&Vs[(ct * 16 + lr) * 64 + ((ks * 4 + quad) ^ lx) * 8]);
            }

        // S^T = K Q^T : st[ct][r] = S[q=m0+lr][j = jt*64 + ct*16 + quad*4 + r]
        facc4 st[4];
        #pragma unroll
        for (int ct = 0; ct < 4; ++ct) {
            st[ct] = (facc4){0.f, 0.f, 0.f, 0.f};
            #pragma unroll
            for (int ks = 0; ks < 2; ++ks)
                st[ct] = __builtin_amdgcn_mfma_f32_16x16x32_bf16(kf[ct * 2 + ks], qf[ks], st[ct], 0, 0, 0);
        }

        if (jt == qt) {                   // only the diagonal tile is masked
            const int jb = jt * 64;
            #pragma unroll
            for (int ct = 0; ct < 4; ++ct)
                #pragma unroll
                for (int r = 0; r < 4; ++r)
                    if (jb + ct * 16 + quad * 4 + r > m0 + lr) st[ct][r] = -3e38f;
        }

        // per-lane online softmax: in-register tree + 2 cross-quad shfls
        float mx;
        {
            float a0 = fmaxf(fmaxf(st[0][0], st[0][1]), fmaxf(st[0][2], st[0][3]));
            float a1 = fmaxf(fmaxf(st[1][0], st[1][1]), fmaxf(st[1][2], st[1][3]));
            float a2 = fmaxf(fmaxf(st[2][0], st[2][1]), fmaxf(st[2][2], st[2][3]));
            float a3 = fmaxf(fmaxf(st[3][0], st[3][1]), fmaxf(st[3][2], st[3][3]));
            mx = fmaxf(fmaxf(a0, a1), fmaxf(a2, a3));
        }
        mx = fmaxf(mx, __shfl_xor(mx, 16));
        mx = fmaxf(mx, __shfl_xor(mx, 32));
        const float mn = fmaxf(m_v, mx);
        const float alpha = ex2(m_v - mn);
        m_v = mn;

        float p[4][4];
        float rs = 0.f;
        #pragma unroll
        for (int ct = 0; ct < 4; ++ct)
            #pragma unroll
            for (int r = 0; r < 4; ++r) {
                p[ct][r] = ex2(st[ct][r] - mn);
                rs += p[ct][r];
            }
        rs += __shfl_xor(rs, 16);
        rs += __shfl_xor(rs, 32);
        l_v = l_v * alpha + rs;
        #pragma unroll
        for (int ct = 0; ct < 4; ++ct) o_acc[ct] = o_acc[ct] * alpha;

        // P^T -> wave-private swizzled LDS [q=lr][j], packed u32 pairs
        u16* pw = &Ps[wave][lr * 64];
        #pragma unroll
        for (int ct = 0; ct < 4; ++ct) {
            const u32 w0 = (u32)f2bf_trunc(p[ct][0]) | ((u32)f2bf_trunc(p[ct][1]) << 16);
            const u32 w1 = (u32)f2bf_trunc(p[ct][2]) | ((u32)f2bf_trunc(p[ct][3]) << 16);
            const int gp = ((ct * 2 + (quad >> 1)) ^ lx) * 8 + (quad & 1) * 4;
            *(u32*)(pw + gp)     = w0;
            *(u32*)(pw + gp + 2) = w1;
        }

        // O^T += V^T P^T
        #pragma unroll
        for (int ks = 0; ks < 2; ++ks) {
            const bfrag8 pf = *(const bfrag8*)(&Ps[wave][lr * 64 + ((ks * 4 + quad) ^ lx) * 8]);
            #pragma unroll
            for (int ct = 0; ct < 4; ++ct)
                o_acc[ct] = __builtin_amdgcn_mfma_f32_16x16x32_bf16(vf[ct * 2 + ks], pf, o_acc[ct], 0, 0, 0);
        }
    }

    // publish raw partials: O^T [d][q] into Ps (wave-private reuse), then store
    const int e = half * 896 + bh * 32 + qt;
    __syncthreads();
    #pragma unroll
    for (int ct = 0; ct < 4; ++ct)
        #pragma unroll
        for (int r = 0; r < 4; ++r)
            Ps[wave][(ct * 16 + quad * 4 + r) * 16 + lr] = f2bf(o_acc[ct][r]);
    if (quad == 0) mlb[(size_t)e * 64 + wave * 16 + lr] = make_float2(m_v, l_v);
    __syncthreads();

    u16* pb = pbuf + (size_t)e * 4096;
    const int d = tid & 63, rg = tid >> 6;
    #pragma unroll
    for (int rr = 0; rr < 16; ++rr) {
        const int rl = rg * 16 + rr;
        pb[rl * 64 + d] = Ps[rl >> 4][d * 16 + (rl & 15)];
    }
}

// ---------------------------------------------------------------------------
// Kernel 3: merge the 2 KV-split partials -> swizzled attn-out tiles in q_ws.
// Vectorized: bfrag8 loads/stores (R10 was scalar u16).
// ---------------------------------------------------------------------------
__global__ __launch_bounds__(256)
void combine_kernel(const u16* __restrict__ pbuf, const float2* __restrict__ mlb,
                    u16* __restrict__ aout)
{
    const int qt = blockIdx.x, bh = blockIdx.y;
    const int b = bh / Hh, h = bh % Hh;
    const int e0 = bh * 32 + qt, e1 = 896 + bh * 32 + qt;
    const u16* p0 = pbuf + (size_t)e0 * 4096;
    const u16* p1 = pbuf + (size_t)e1 * 4096;
    u16* tile = aout + ((size_t)(b * 32 + qt) * 14 + h) * 4096;

    int c = threadIdx.x;
    #pragma unroll
    for (int u = 0; u < 2; ++u, c += 256) {
        const int row = c >> 3, g = c & 7;
        const float2 a0 = mlb[(size_t)e0 * 64 + row];
        const float2 a1 = mlb[(size_t)e1 * 64 + row];
        const float mf = fmaxf(a0.x, a1.x);
        const float f0 = ex2(a0.x - mf), f1 = ex2(a1.x - mf);
        const float inv = 1.0f / (f0 * a0.y + f1 * a1.y);
        union { u16 s[8]; bfrag8 v; } t0, t1, o;
        t0.v = *(const bfrag8*)(p0 + row * 64 + g * 8);
        t1.v = *(const bfrag8*)(p1 + row * 64 + g * 8);
        #pragma unroll
        for (int j = 0; j < 8; ++j)
            o.s[j] = f2bf((f0 * bf2f(t0.s[j]) + f1 * bf2f(t1.s[j])) * inv);
        *(bfrag8*)(tile + row * 64 + ((g ^ (row & 7)) * 8)) = o.v;
    }
}

// ---------------------------------------------------------------------------
// Kernel 4: output projection, 64x128, BK=64, DMA staging. A = swizzled
// attn-out tiles, B = packed wo tiles, out = d_out f32.
// ---------------------------------------------------------------------------
__global__ __launch_bounds__(256)
void oproj_kernel(const u16* __restrict__ a_t, const u16* __restrict__ wo_p,
                  float* __restrict__ outp)
{
    __shared__ __align__(16) u16 As[64 * 64];
    __shared__ __align__(16) u16 Bs[128 * 64];

    const int mt = blockIdx.x;            // 0..63
    const int nt = blockIdx.y;            // 0..6

    const int tid  = threadIdx.x;
    const int lane = tid & 63, wave = tid >> 6;
    const int lr   = lane & 15, quad = lane >> 4;
    const int wm   = wave & 1,  wn   = wave >> 1;
    const int lx   = lr & 7;

    facc4 acc[2][4];
    #pragma unroll
    for (int i = 0; i < 2; ++i)
        #pragma unroll
        for (int j = 0; j < 4; ++j) acc[i][j] = (facc4){0.f, 0.f, 0.f, 0.f};

    for (int kt = 0; kt < 14; ++kt) {
        __syncthreads();
        {
            const u16* asrc = a_t + ((size_t)mt * 14 + kt) * 4096;
            const u16* bsrc = wo_p + ((size_t)nt * 14 + kt) * 8192;
            #pragma unroll
            for (int u = 0; u < 2; ++u) {
                const int ch = wave * 2 + u;
                gld_lds16(&As[ch * 512], asrc + ch * 512 + lane * 8);
            }
            #pragma unroll
            for (int u = 0; u < 4; ++u) {
                const int ch = wave * 4 + u;
                gld_lds16(&Bs[ch * 512], bsrc + ch * 512 + lane * 8);
            }
        }
        __syncthreads();

        bfrag8 af[2][2], bf[4][2];
        #pragma unroll
        for (int i = 0; i < 2; ++i)
            #pragma unroll
            for (int ks = 0; ks < 2; ++ks)
                af[i][ks] = *(const bfrag8*)(&As[(wm * 32 + i * 16 + lr) * 64 + ((ks * 4 + quad) ^ lx) * 8]);
        #pragma unroll
        for (int j = 0; j < 4; ++j)
            #pragma unroll
            for (int ks = 0; ks < 2; ++ks)
                bf[j][ks] = *(const bfrag8*)(&Bs[(wn * 64 + j * 16 + lr) * 64 + ((ks * 4 + quad) ^ lx) * 8]);
        #pragma unroll
        for (int i = 0; i < 2; ++i)
            #pragma unroll
            for (int j = 0; j < 4; ++j)
                #pragma unroll
                for (int ks = 0; ks < 2; ++ks)
                    acc[i][j] = __builtin_amdgcn_mfma_f32_16x16x32_bf16(af[i][ks], bf[j][ks], acc[i][j], 0, 0, 0);
    }

    #pragma unroll
    for (int i = 0; i < 2; ++i)
        #pragma unroll
        for (int j = 0; j < 4; ++j) {
            const int col = nt * 128 + wn * 64 + j * 16 + lr;
            #pragma unroll
            for (int r = 0; r < 4; ++r) {
                const int row = mt * 64 + wm * 32 + i * 16 + quad * 4 + r;
                outp[(size_t)row * 896 + col] = acc[i][j][r];
            }
        }
}

// ---------------------------------------------------------------------------
extern "C" void kernel_launch(void* const* d_in, const int* in_sizes, int n_in,
                              void* d_out, int out_size, void* d_ws, size_t ws_size,
                              hipStream_t stream)
{
    const float* x    = (const float*)d_in[0];
    const float* wq   = (const float*)d_in[1];
    const float* bq   = (const float*)d_in[2];
    const float* wk   = (const float*)d_in[3];
    const float* bk   = (const float*)d_in[4];
    const float* wv   = (const float*)d_in[5];
    const float* bv   = (const float*)d_in[6];
    const float* wo   = (const float*)d_in[7];
    const float* cosT = (const float*)d_in[8];
    const float* sinT = (const float*)d_in[9];
    // d_in[10] = mask: exact causal tril(0 / -1e9) — applied inline in attn_kernel.

    u16* ws   = (u16*)d_ws;
    u16* q_ws = ws + Q_WS;       // q rows, then swizzled attn-out tiles
    u16* k_t  = ws + K_T;
    u16* v_t2 = ws + V_T2;
    float2* mlb = (float2*)(ws + ML);
    u16* scratch = (u16*)d_out;  // x_bf during qkv, then O-partials, then f32 out

    cvt_x_kernel<<<dim3(64, 14), 256, 0, stream>>>(x, scratch);
    pack_w_kernel<<<dim3(224), 256, 0, stream>>>(wq, wk, wv, wo, ws);
    qkv_kernel<<<dim3(64, 9), 256, 0, stream>>>(scratch, ws, bq, bk, bv, cosT, sinT,
                                                q_ws, k_t, v_t2);
    attn_kernel<<<dim3(64, 28), 256, 0, stream>>>(q_ws, k_t, v_t2, scratch, mlb);
    combine_kernel<<<dim3(32, 28), 256, 0, stream>>>(scratch, mlb, q_ws);
    oproj_kernel<<<dim3(64, 7), 256, 0, stream>>>(q_ws, ws + WO_P, (float*)d_out);
}

// Round 12
// 184.619 us; speedup vs baseline: 2.0190x; 1.0322x over previous
//
#include <hip/hip_runtime.h>
#include <hip/hip_bf16.h>
#include <cstdint>
#include <cstddef>

// Problem constants
#define Bb   2
#define Tt   2048
#define Cc   896
#define Hh   14
#define HKVc 2
#define Mm   (Bb * Tt)        // 4096 rows

typedef __attribute__((ext_vector_type(8))) short bfrag8;   // 8 bf16 (4 VGPRs)
typedef __attribute__((ext_vector_type(4))) float facc4;    // 4 f32 acc
typedef unsigned short u16;
typedef unsigned int   u32;

// Workspace layout (u16 element offsets). All tiled buffers use 64-col tiles
// with granule-XOR swizzle (granule g of row r stored at g^(r&7)).
#define WQ_P  0          // 7*14 tiles of 128x64
#define WK_P  802816     // 14 tiles
#define WV_P  917504     // 14 tiles
#define WO_P  1032192    // 7*14 tiles
#define Q_WS  1835008    // 4096*896: roped q (row-major), later swizzled attn-out tiles
#define K_T   5505024    // [b][kvh][jt][t&63][d-swizzled] = 2*2*32*4096
#define V_T2  6029312    // [b][kvh][jt][d][tin-swizzled] = 2*2*32*4096
#define ML    6553600    // float2 (m,l): 1792 entries x 64 rows
// d_out scratch timeline: x_bf (swizzled tiles) -> attn O-partials -> f32 out.

__device__ __forceinline__ float bf2f(u16 v) {
    union { u32 u; float f; } c; c.u = ((u32)v) << 16; return c.f;
}
__device__ __forceinline__ u16 f2bf(float f) {
    union { float f; u32 u; } c; c.f = f;
    u32 u = c.u;
    return (u16)((u + 0x7fffu + ((u >> 16) & 1u)) >> 16);  // RNE
}
__device__ __forceinline__ u16 f2bf_trunc(float f) {      // cheap truncate (P only)
    union { float f; u32 u; } c; c.f = f;
    return (u16)(c.u >> 16);
}
// HW base-2 exp (v_exp_f32). __exp2f does not exist in HIP device code.
__device__ __forceinline__ float ex2(float x) { return __builtin_amdgcn_exp2f(x); }

// Async global->LDS DMA, 16B/lane; lds base wave-uniform, lane i -> base+i*16.
__device__ __forceinline__ void gld_lds16(u16* lds_uniform, const u16* g_per_lane) {
    __builtin_amdgcn_global_load_lds(
        (const __attribute__((address_space(1))) u32*)g_per_lane,
        (__attribute__((address_space(3))) u32*)lds_uniform, 16, 0, 0);
}

// ---------------------------------------------------------------------------
// Kernel 0a: x (f32) -> x_bf swizzled 64x64 tiles in d_out scratch.
// ---------------------------------------------------------------------------
__global__ __launch_bounds__(256)
void cvt_x_kernel(const float* __restrict__ x, u16* __restrict__ x_bf)
{
    const int mt = blockIdx.x, kt = blockIdx.y;
    u16* tile = x_bf + ((size_t)mt * 14 + kt) * 4096;
    int c = threadIdx.x;
    #pragma unroll
    for (int u = 0; u < 2; ++u, c += 256) {
        const int row = c >> 3, g = c & 7;
        const float4* xp = (const float4*)(x + (size_t)(mt * 64 + row) * 896 + kt * 64 + g * 8);
        const float4 v0 = xp[0], v1 = xp[1];
        union { u16 s[8]; bfrag8 v; } t;
        t.s[0]=f2bf(v0.x); t.s[1]=f2bf(v0.y); t.s[2]=f2bf(v0.z); t.s[3]=f2bf(v0.w);
        t.s[4]=f2bf(v1.x); t.s[5]=f2bf(v1.y); t.s[6]=f2bf(v1.z); t.s[7]=f2bf(v1.w);
        *(bfrag8*)(tile + row * 64 + ((g ^ (row & 7)) * 8)) = t.v;
    }
}

// ---------------------------------------------------------------------------
// Kernel 0b: pack weights into bf16 128x64 [n][k-swizzled] tiles (coalesced
// read + LDS transpose).
// ---------------------------------------------------------------------------
__global__ __launch_bounds__(256)
void pack_w_kernel(const float* __restrict__ wq, const float* __restrict__ wk,
                   const float* __restrict__ wv, const float* __restrict__ wo,
                   u16* __restrict__ ws)
{
    __shared__ u16 T[64 * 136];           // [kk][n], pad 8

    const int bt = blockIdx.x;            // 0..223
    const float* W; u16* dst; int ldw, tile;
    if (bt < 98)       { W = wq; dst = ws + WQ_P; ldw = 896; tile = bt; }
    else if (bt < 112) { W = wk; dst = ws + WK_P; ldw = 128; tile = bt - 98; }
    else if (bt < 126) { W = wv; dst = ws + WV_P; ldw = 128; tile = bt - 112; }
    else               { W = wo; dst = ws + WO_P; ldw = 896; tile = bt - 126; }
    const int nt = tile / 14, kt = tile % 14;

    const int tid = threadIdx.x;
    {   // phase 1: thread reads 32 contiguous f32 of row kk
        const int kk = tid >> 2, nc = (tid & 3) * 32;
        const float* src = W + (size_t)(kt * 64 + kk) * ldw + nt * 128 + nc;
        union { u16 s[32]; bfrag8 v[4]; } t;
        #pragma unroll
        for (int j = 0; j < 8; ++j) {
            const float4 v = ((const float4*)src)[j];
            t.s[j*4+0]=f2bf(v.x); t.s[j*4+1]=f2bf(v.y); t.s[j*4+2]=f2bf(v.z); t.s[j*4+3]=f2bf(v.w);
        }
        #pragma unroll
        for (int u = 0; u < 4; ++u)
            *(bfrag8*)(&T[kk * 136 + nc + u * 8]) = t.v[u];
    }
    __syncthreads();
    {   // phase 2: thread assembles column n, kh half, writes 64B contiguous
        const int n = tid >> 1, kh = tid & 1;
        union { u16 s[32]; bfrag8 v[4]; } t;
        #pragma unroll
        for (int j = 0; j < 32; ++j) t.s[j] = T[(kh * 32 + j) * 136 + n];
        u16* d = dst + (size_t)tile * 8192 + n * 64;
        #pragma unroll
        for (int u = 0; u < 4; ++u)
            *(bfrag8*)(d + ((kh * 4 + u) ^ (n & 7)) * 8) = t.v[u];
    }
}

// ---------------------------------------------------------------------------
// Kernel 1: QKV projection + bias + fused RoPE. 64(M) x 128(N), BK=64, DMA
// staging. y: 0..6 = wq -> q_ws; 7 = wk -> k_t (roped); 8 = wv -> v_t2.
// ---------------------------------------------------------------------------
__global__ __launch_bounds__(256)
void qkv_kernel(const u16* __restrict__ x_bf, const u16* __restrict__ ws,
                const float* __restrict__ bq, const float* __restrict__ bk,
                const float* __restrict__ bv,
                const float* __restrict__ cosT, const float* __restrict__ sinT,
                u16* __restrict__ q_ws, u16* __restrict__ k_t, u16* __restrict__ v_t2)
{
    __shared__ __align__(16) u16 As[64 * 64];
    __shared__ __align__(16) u16 Bs[128 * 64];

    const int mt = blockIdx.x;        // 0..63
    const int y  = blockIdx.y;        // 0..8
    const u16* wp; const float* bias;
    if (y < 7)       { wp = ws + WQ_P + (size_t)y * 14 * 8192; bias = bq; }
    else if (y == 7) { wp = ws + WK_P; bias = bk; }
    else             { wp = ws + WV_P; bias = bv; }

    const int tid  = threadIdx.x;
    const int lane = tid & 63, wave = tid >> 6;
    const int lr   = lane & 15, quad = lane >> 4;
    const int wm   = wave & 1,  wn   = wave >> 1;
    const int lx   = lr & 7;

    facc4 acc[2][4];
    #pragma unroll
    for (int i = 0; i < 2; ++i)
        #pragma unroll
        for (int j = 0; j < 4; ++j) acc[i][j] = (facc4){0.f, 0.f, 0.f, 0.f};

    for (int kt = 0; kt < 14; ++kt) {
        __syncthreads();
        {
            const u16* asrc = x_bf + ((size_t)mt * 14 + kt) * 4096;
            const u16* bsrc = wp + (size_t)kt * 8192;
            #pragma unroll
            for (int u = 0; u < 2; ++u) {
                const int ch = wave * 2 + u;
                gld_lds16(&As[ch * 512], asrc + ch * 512 + lane * 8);
            }
            #pragma unroll
            for (int u = 0; u < 4; ++u) {
                const int ch = wave * 4 + u;
                gld_lds16(&Bs[ch * 512], bsrc + ch * 512 + lane * 8);
            }
        }
        __syncthreads();

        bfrag8 af[2][2], bf[4][2];
        #pragma unroll
        for (int i = 0; i < 2; ++i)
            #pragma unroll
            for (int ks = 0; ks < 2; ++ks)
                af[i][ks] = *(const bfrag8*)(&As[(wm * 32 + i * 16 + lr) * 64 + ((ks * 4 + quad) ^ lx) * 8]);
        #pragma unroll
        for (int j = 0; j < 4; ++j)
            #pragma unroll
            for (int ks = 0; ks < 2; ++ks)
                bf[j][ks] = *(const bfrag8*)(&Bs[(wn * 64 + j * 16 + lr) * 64 + ((ks * 4 + quad) ^ lx) * 8]);
        #pragma unroll
        for (int i = 0; i < 2; ++i)
            #pragma unroll
            for (int j = 0; j < 4; ++j)
                #pragma unroll
                for (int ks = 0; ks < 2; ++ks)
                    acc[i][j] = __builtin_amdgcn_mfma_f32_16x16x32_bf16(af[i][ks], bf[j][ks], acc[i][j], 0, 0, 0);
    }

    // epilogue: bias + rope (q,k) + route
    float bb[4];
    #pragma unroll
    for (int j = 0; j < 4; ++j)
        bb[j] = bias[(y < 7 ? y * 128 : 0) + wn * 64 + j * 16 + lr];

    #pragma unroll
    for (int i = 0; i < 2; ++i) {
        #pragma unroll
        for (int r = 0; r < 4; ++r) {
            const int row = mt * 64 + wm * 32 + i * 16 + quad * 4 + r;
            const int b = row >> 11, t = row & 2047;
            float v0 = acc[i][0][r] + bb[0];
            float v1 = acc[i][1][r] + bb[1];
            float v2 = acc[i][2][r] + bb[2];
            float v3 = acc[i][3][r] + bb[3];
            if (y <= 7) {   // rope (pairs d, d+32 in-register)
                const int tb = t * 64 + lr;
                const float c0 = cosT[tb],      s0 = sinT[tb];
                const float c1 = cosT[tb + 16], s1 = sinT[tb + 16];
                const float c2 = cosT[tb + 32], s2 = sinT[tb + 32];
                const float c3 = cosT[tb + 48], s3 = sinT[tb + 48];
                const float n0 = v0 * c0 - v2 * s0;
                const float n1 = v1 * c1 - v3 * s1;
                const float n2 = v2 * c2 + v0 * s2;
                const float n3 = v3 * c3 + v1 * s3;
                v0 = n0; v1 = n1; v2 = n2; v3 = n3;
            }
            const u16 o0 = f2bf(v0), o1 = f2bf(v1), o2 = f2bf(v2), o3 = f2bf(v3);
            if (y < 7) {
                u16* qp = q_ws + (size_t)row * 896 + y * 128 + wn * 64 + lr;
                qp[0] = o0; qp[16] = o1; qp[32] = o2; qp[48] = o3;
            } else if (y == 7) {
                u16* kp = k_t + ((size_t)(b * 2 + wn) * 32 + (t >> 6)) * 4096
                              + (t & 63) * 64 + (lr & 7);
                const int tx = t & 7, g0 = lr >> 3;
                kp[((g0    ) ^ tx) * 8] = o0;
                kp[((g0 + 2) ^ tx) * 8] = o1;
                kp[((g0 + 4) ^ tx) * 8] = o2;
                kp[((g0 + 6) ^ tx) * 8] = o3;
            } else {
                u16* vp = v_t2 + ((size_t)(b * 2 + wn) * 32 + (t >> 6)) * 4096
                               + ((((t & 63) >> 3) ^ (lr & 7)) * 8) + (t & 7);
                vp[(size_t)(lr     ) * 64] = o0;
                vp[(size_t)(lr + 16) * 64] = o1;
                vp[(size_t)(lr + 32) * 64] = o2;
                vp[(size_t)(lr + 48) * 64] = o3;
            }
        }
    }
}

// ---------------------------------------------------------------------------
// Kernel 2: flash attention — PAIRED Q-TILES for uniform block workloads.
// Grid (32, 28): pp = bx>>1 in [0,16), half = bx&1. Block handles qa = pp and
// qb = 31-pp, iterating KV tiles jt ≡ half (mod 2) (parity split => same
// staging serves both Q-tiles; every (qt, jt) covered exactly once).
// All blocks do ⌈(32-pp)/2⌉ staging iters + ~16.5 compute units: UNIFORM.
// Partials (entry e = half*896 + bh*32 + qt) unchanged -> combine_kernel.
// ---------------------------------------------------------------------------
__global__ __launch_bounds__(256)
void attn_kernel(const u16* __restrict__ q_ws, const u16* __restrict__ k_t,
                 const u16* __restrict__ v_t2, u16* __restrict__ pbuf,
                 float2* __restrict__ mlb)
{
    __shared__ __align__(16) u16 Ks[64 * 64];     // [j][d-swizzled]
    __shared__ __align__(16) u16 Vs[64 * 64];     // [d][tin-swizzled]
    __shared__ __align__(16) u16 Ps[4][16 * 64];  // per-wave P^T; reused as O^T

    const int pp = blockIdx.x >> 1, half = blockIdx.x & 1;
    const int qa = pp, qb = 31 - pp;
    const int bh = blockIdx.y;
    const int b = bh / Hh, h = bh % Hh;
    const int kvh = h / (Hh / HKVc);

    const int tid  = threadIdx.x;
    const int lane = tid & 63;
    const int wave = tid >> 6;
    const int lr   = lane & 15;
    const int quad = lane >> 4;
    const int lx   = lr & 7;

    const u16* Kg = k_t + (size_t)(b * 2 + kvh) * 32 * 4096;
    const u16* Vg = v_t2 + (size_t)(b * 2 + kvh) * 32 * 4096;

    // Q fragments for both tiles, pre-scaled by 1/sqrt(D)*log2(e)
    const float QSC = 0.125f * 1.44269504f;
    bfrag8 qfa[2], qfb[2];
    #pragma unroll
    for (int ks = 0; ks < 2; ++ks) {
        union { u16 s[8]; bfrag8 v; } ta, tb2;
        ta.v = *(const bfrag8*)(q_ws + (size_t)(b * 2048 + qa * 64 + wave * 16 + lr) * 896 + h * 64 + ks * 32 + quad * 8);
        tb2.v = *(const bfrag8*)(q_ws + (size_t)(b * 2048 + qb * 64 + wave * 16 + lr) * 896 + h * 64 + ks * 32 + quad * 8);
        #pragma unroll
        for (int j = 0; j < 8; ++j) { ta.s[j] = f2bf(bf2f(ta.s[j]) * QSC); tb2.s[j] = f2bf(bf2f(tb2.s[j]) * QSC); }
        qfa[ks] = ta.v; qfb[ks] = tb2.v;
    }

    float m_a = -3e38f, l_a = 0.f, m_b = -3e38f, l_b = 0.f;
    facc4 oa[4], ob[4];
    #pragma unroll
    for (int ct = 0; ct < 4; ++ct) {
        oa[ct] = (facc4){0.f, 0.f, 0.f, 0.f};
        ob[ct] = (facc4){0.f, 0.f, 0.f, 0.f};
    }

    const int nkva = qa + 1, nkvb = qb + 1;

    for (int jt = half; jt < nkvb; jt += 2) {
        __syncthreads();
        {   // K and V tiles: 8KB DMA each
            const u16* ksrc = Kg + (size_t)jt * 4096;
            const u16* vsrc = Vg + (size_t)jt * 4096;
            #pragma unroll
            for (int u = 0; u < 2; ++u) {
                const int ch = wave * 2 + u;
                gld_lds16(&Ks[ch * 512], ksrc + ch * 512 + lane * 8);
                gld_lds16(&Vs[ch * 512], vsrc + ch * 512 + lane * 8);
            }
        }
        __syncthreads();

        bfrag8 kf[8], vf[8];
        #pragma unroll
        for (int ct = 0; ct < 4; ++ct)
            #pragma unroll
            for (int ks = 0; ks < 2; ++ks) {
                kf[ct * 2 + ks] = *(const bfrag8*)(&Ks[(ct * 16 + lr) * 64 + ((ks * 4 + quad) ^ lx) * 8]);
                vf[ct * 2 + ks] = *(const bfrag8*)(&Vs[(ct * 16 + lr) * 64 + ((ks * 4 + quad) ^ lx) * 8]);
            }

        const bool do_a = (jt < nkva);    // block-uniform

        // ---- qb (always active) ----
        {
            const int m0 = qb * 64 + wave * 16;
            facc4 st[4];
            #pragma unroll
            for (int ct = 0; ct < 4; ++ct) {
                st[ct] = (facc4){0.f, 0.f, 0.f, 0.f};
                #pragma unroll
                for (int ks = 0; ks < 2; ++ks)
                    st[ct] = __builtin_amdgcn_mfma_f32_16x16x32_bf16(kf[ct * 2 + ks], qfb[ks], st[ct], 0, 0, 0);
            }
            if (jt == qb) {
                const int jb = jt * 64;
                #pragma unroll
                for (int ct = 0; ct < 4; ++ct)
                    #pragma unroll
                    for (int r = 0; r < 4; ++r)
                        if (jb + ct * 16 + quad * 4 + r > m0 + lr) st[ct][r] = -3e38f;
            }
            float mx;
            {
                float a0 = fmaxf(fmaxf(st[0][0], st[0][1]), fmaxf(st[0][2], st[0][3]));
                float a1 = fmaxf(fmaxf(st[1][0], st[1][1]), fmaxf(st[1][2], st[1][3]));
                float a2 = fmaxf(fmaxf(st[2][0], st[2][1]), fmaxf(st[2][2], st[2][3]));
                float a3 = fmaxf(fmaxf(st[3][0], st[3][1]), fmaxf(st[3][2], st[3][3]));
                mx = fmaxf(fmaxf(a0, a1), fmaxf(a2, a3));
            }
            mx = fmaxf(mx, __shfl_xor(mx, 16));
            mx = fmaxf(mx, __shfl_xor(mx, 32));
            const float mn = fmaxf(m_b, mx);
            const float alpha = ex2(m_b - mn);
            m_b = mn;
            float p[4][4]; float rs = 0.f;
            #pragma unroll
            for (int ct = 0; ct < 4; ++ct)
                #pragma unroll
                for (int r = 0; r < 4; ++r) { p[ct][r] = ex2(st[ct][r] - mn); rs += p[ct][r]; }
            rs += __shfl_xor(rs, 16);
            rs += __shfl_xor(rs, 32);
            l_b = l_b * alpha + rs;
            #pragma unroll
            for (int ct = 0; ct < 4; ++ct) ob[ct] = ob[ct] * alpha;
            u16* pw = &Ps[wave][lr * 64];
            #pragma unroll
            for (int ct = 0; ct < 4; ++ct) {
                const u32 w0 = (u32)f2bf_trunc(p[ct][0]) | ((u32)f2bf_trunc(p[ct][1]) << 16);
                const u32 w1 = (u32)f2bf_trunc(p[ct][2]) | ((u32)f2bf_trunc(p[ct][3]) << 16);
                const int gp = ((ct * 2 + (quad >> 1)) ^ lx) * 8 + (quad & 1) * 4;
                *(u32*)(pw + gp)     = w0;
                *(u32*)(pw + gp + 2) = w1;
            }
            #pragma unroll
            for (int ks = 0; ks < 2; ++ks) {
                const bfrag8 pf = *(const bfrag8*)(&Ps[wave][lr * 64 + ((ks * 4 + quad) ^ lx) * 8]);
                #pragma unroll
                for (int ct = 0; ct < 4; ++ct)
                    ob[ct] = __builtin_amdgcn_mfma_f32_16x16x32_bf16(vf[ct * 2 + ks], pf, ob[ct], 0, 0, 0);
            }
        }

        // ---- qa (active while jt < nkva) ----
        if (do_a) {
            const int m0 = qa * 64 + wave * 16;
            facc4 st[4];
            #pragma unroll
            for (int ct = 0; ct < 4; ++ct) {
                st[ct] = (facc4){0.f, 0.f, 0.f, 0.f};
                #pragma unroll
                for (int ks = 0; ks < 2; ++ks)
                    st[ct] = __builtin_amdgcn_mfma_f32_16x16x32_bf16(kf[ct * 2 + ks], qfa[ks], st[ct], 0, 0, 0);
            }
            if (jt == qa) {
                const int jb = jt * 64;
                #pragma unroll
                for (int ct = 0; ct < 4; ++ct)
                    #pragma unroll
                    for (int r = 0; r < 4; ++r)
                        if (jb + ct * 16 + quad * 4 + r > m0 + lr) st[ct][r] = -3e38f;
            }
            float mx;
            {
                float a0 = fmaxf(fmaxf(st[0][0], st[0][1]), fmaxf(st[0][2], st[0][3]));
                float a1 = fmaxf(fmaxf(st[1][0], st[1][1]), fmaxf(st[1][2], st[1][3]));
                float a2 = fmaxf(fmaxf(st[2][0], st[2][1]), fmaxf(st[2][2], st[2][3]));
                float a3 = fmaxf(fmaxf(st[3][0], st[3][1]), fmaxf(st[3][2], st[3][3]));
                mx = fmaxf(fmaxf(a0, a1), fmaxf(a2, a3));
            }
            mx = fmaxf(mx, __shfl_xor(mx, 16));
            mx = fmaxf(mx, __shfl_xor(mx, 32));
            const float mn = fmaxf(m_a, mx);
            const float alpha = ex2(m_a - mn);
            m_a = mn;
            float p[4][4]; float rs = 0.f;
            #pragma unroll
            for (int ct = 0; ct < 4; ++ct)
                #pragma unroll
                for (int r = 0; r < 4; ++r) { p[ct][r] = ex2(st[ct][r] - mn); rs += p[ct][r]; }
            rs += __shfl_xor(rs, 16);
            rs += __shfl_xor(rs, 32);
            l_a = l_a * alpha + rs;
            #pragma unroll
            for (int ct = 0; ct < 4; ++ct) oa[ct] = oa[ct] * alpha;
            u16* pw = &Ps[wave][lr * 64];
            #pragma unroll
            for (int ct = 0; ct < 4; ++ct) {
                const u32 w0 = (u32)f2bf_trunc(p[ct][0]) | ((u32)f2bf_trunc(p[ct][1]) << 16);
                const u32 w1 = (u32)f2bf_trunc(p[ct][2]) | ((u32)f2bf_trunc(p[ct][3]) << 16);
                const int gp = ((ct * 2 + (quad >> 1)) ^ lx) * 8 + (quad & 1) * 4;
                *(u32*)(pw + gp)     = w0;
                *(u32*)(pw + gp + 2) = w1;
            }
            #pragma unroll
            for (int ks = 0; ks < 2; ++ks) {
                const bfrag8 pf = *(const bfrag8*)(&Ps[wave][lr * 64 + ((ks * 4 + quad) ^ lx) * 8]);
                #pragma unroll
                for (int ct = 0; ct < 4; ++ct)
                    oa[ct] = __builtin_amdgcn_mfma_f32_16x16x32_bf16(vf[ct * 2 + ks], pf, oa[ct], 0, 0, 0);
            }
        }
    }

    // ---- publish both partial entries (qa then qb) ----
    #pragma unroll
    for (int ph = 0; ph < 2; ++ph) {
        const int qt = ph ? qb : qa;
        const int e = half * 896 + bh * 32 + qt;
        __syncthreads();                  // prior Ps readers done
        #pragma unroll
        for (int ct = 0; ct < 4; ++ct)
            #pragma unroll
            for (int r = 0; r < 4; ++r)
                Ps[wave][(ct * 16 + quad * 4 + r) * 16 + lr] =
                    f2bf(ph ? ob[ct][r] : oa[ct][r]);
        if (quad == 0)
            mlb[(size_t)e * 64 + wave * 16 + lr] =
                ph ? make_float2(m_b, l_b) : make_float2(m_a, l_a);
        __syncthreads();
        u16* pb = pbuf + (size_t)e * 4096;
        const int d = tid & 63, rg = tid >> 6;
        #pragma unroll
        for (int rr = 0; rr < 16; ++rr) {
            const int rl = rg * 16 + rr;
            pb[rl * 64 + d] = Ps[rl >> 4][d * 16 + (rl & 15)];
        }
    }
}

// ---------------------------------------------------------------------------
// Kernel 3: merge the 2 KV-split partials -> swizzled attn-out tiles in q_ws.
// ---------------------------------------------------------------------------
__global__ __launch_bounds__(256)
void combine_kernel(const u16* __restrict__ pbuf, const float2* __restrict__ mlb,
                    u16* __restrict__ aout)
{
    const int qt = blockIdx.x, bh = blockIdx.y;
    const int b = bh / Hh, h = bh % Hh;
    const int e0 = bh * 32 + qt, e1 = 896 + bh * 32 + qt;
    const u16* p0 = pbuf + (size_t)e0 * 4096;
    const u16* p1 = pbuf + (size_t)e1 * 4096;
    u16* tile = aout + ((size_t)(b * 32 + qt) * 14 + h) * 4096;

    int c = threadIdx.x;
    #pragma unroll
    for (int u = 0; u < 2; ++u, c += 256) {
        const int row = c >> 3, g = c & 7;
        const float2 a0 = mlb[(size_t)e0 * 64 + row];
        const float2 a1 = mlb[(size_t)e1 * 64 + row];
        const float mf = fmaxf(a0.x, a1.x);
        const float f0 = ex2(a0.x - mf), f1 = ex2(a1.x - mf);
        const float inv = 1.0f / (f0 * a0.y + f1 * a1.y);
        union { u16 s[8]; bfrag8 v; } t0, t1, o;
        t0.v = *(const bfrag8*)(p0 + row * 64 + g * 8);
        t1.v = *(const bfrag8*)(p1 + row * 64 + g * 8);
        #pragma unroll
        for (int j = 0; j < 8; ++j)
            o.s[j] = f2bf((f0 * bf2f(t0.s[j]) + f1 * bf2f(t1.s[j])) * inv);
        *(bfrag8*)(tile + row * 64 + ((g ^ (row & 7)) * 8)) = o.v;
    }
}

// ---------------------------------------------------------------------------
// Kernel 4: output projection, 64x128, BK=64, DMA staging.
// ---------------------------------------------------------------------------
__global__ __launch_bounds__(256)
void oproj_kernel(const u16* __restrict__ a_t, const u16* __restrict__ wo_p,
                  float* __restrict__ outp)
{
    __shared__ __align__(16) u16 As[64 * 64];
    __shared__ __align__(16) u16 Bs[128 * 64];

    const int mt = blockIdx.x;            // 0..63
    const int nt = blockIdx.y;            // 0..6

    const int tid  = threadIdx.x;
    const int lane = tid & 63, wave = tid >> 6;
    const int lr   = lane & 15, quad = lane >> 4;
    const int wm   = wave & 1,  wn   = wave >> 1;
    const int lx   = lr & 7;

    facc4 acc[2][4];
    #pragma unroll
    for (int i = 0; i < 2; ++i)
        #pragma unroll
        for (int j = 0; j < 4; ++j) acc[i][j] = (facc4){0.f, 0.f, 0.f, 0.f};

    for (int kt = 0; kt < 14; ++kt) {
        __syncthreads();
        {
            const u16* asrc = a_t + ((size_t)mt * 14 + kt) * 4096;
            const u16* bsrc = wo_p + ((size_t)nt * 14 + kt) * 8192;
            #pragma unroll
            for (int u = 0; u < 2; ++u) {
                const int ch = wave * 2 + u;
                gld_lds16(&As[ch * 512], asrc + ch * 512 + lane * 8);
            }
            #pragma unroll
            for (int u = 0; u < 4; ++u) {
                const int ch = wave * 4 + u;
                gld_lds16(&Bs[ch * 512], bsrc + ch * 512 + lane * 8);
            }
        }
        __syncthreads();

        bfrag8 af[2][2], bf[4][2];
        #pragma unroll
        for (int i = 0; i < 2; ++i)
            #pragma unroll
            for (int ks = 0; ks < 2; ++ks)
                af[i][ks] = *(const bfrag8*)(&As[(wm * 32 + i * 16 + lr) * 64 + ((ks * 4 + quad) ^ lx) * 8]);
        #pragma unroll
        for (int j = 0; j < 4; ++j)
            #pragma unroll
            for (int ks = 0; ks < 2; ++ks)
                bf[j][ks] = *(const bfrag8*)(&Bs[(wn * 64 + j * 16 + lr) * 64 + ((ks * 4 + quad) ^ lx) * 8]);
        #pragma unroll
        for (int i = 0; i < 2; ++i)
            #pragma unroll
            for (int j = 0; j < 4; ++j)
                #pragma unroll
                for (int ks = 0; ks < 2; ++ks)
                    acc[i][j] = __builtin_amdgcn_mfma_f32_16x16x32_bf16(af[i][ks], bf[j][ks], acc[i][j], 0, 0, 0);
    }

    #pragma unroll
    for (int i = 0; i < 2; ++i)
        #pragma unroll
        for (int j = 0; j < 4; ++j) {
            const int col = nt * 128 + wn * 64 + j * 16 + lr;
            #pragma unroll
            for (int r = 0; r < 4; ++r) {
                const int row = mt * 64 + wm * 32 + i * 16 + quad * 4 + r;
                outp[(size_t)row * 896 + col] = acc[i][j][r];
            }
        }
}

// ---------------------------------------------------------------------------
extern "C" void kernel_launch(void* const* d_in, const int* in_sizes, int n_in,
                              void* d_out, int out_size, void* d_ws, size_t ws_size,
                              hipStream_t stream)
{
    const float* x    = (const float*)d_in[0];
    const float* wq   = (const float*)d_in[1];
    const float* bq   = (const float*)d_in[2];
    const float* wk   = (const float*)d_in[3];
    const float* bk   = (const float*)d_in[4];
    const float* wv   = (const float*)d_in[5];
    const float* bv   = (const float*)d_in[6];
    const float* wo   = (const float*)d_in[7];
    const float* cosT = (const float*)d_in[8];
    const float* sinT = (const float*)d_in[9];
    // d_in[10] = mask: exact causal tril(0 / -1e9) — applied inline in attn_kernel.

    u16* ws   = (u16*)d_ws;
    u16* q_ws = ws + Q_WS;       // q rows, then swizzled attn-out tiles
    u16* k_t  = ws + K_T;
    u16* v_t2 = ws + V_T2;
    float2* mlb = (float2*)(ws + ML);
    u16* scratch = (u16*)d_out;  // x_bf during qkv, then O-partials, then f32 out

    cvt_x_kernel<<<dim3(64, 14), 256, 0, stream>>>(x, scratch);
    pack_w_kernel<<<dim3(224), 256, 0, stream>>>(wq, wk, wv, wo, ws);
    qkv_kernel<<<dim3(64, 9), 256, 0, stream>>>(scratch, ws, bq, bk, bv, cosT, sinT,
                                                q_ws, k_t, v_t2);
    attn_kernel<<<dim3(32, 28), 256, 0, stream>>>(q_ws, k_t, v_t2, scratch, mlb);
    combine_kernel<<<dim3(32, 28), 256, 0, stream>>>(scratch, mlb, q_ws);
    oproj_kernel<<<dim3(64, 7), 256, 0, stream>>>(q_ws, ws + WO_P, (float*)d_out);
}